// Round 1
// baseline (5850.350 us; speedup 1.0000x reference)
//
#include <hip/hip_runtime.h>
#include <hip/hip_bf16.h>

#define B_ 4
#define S_ 4096
#define D_ 768
#define H_ 12
#define DH_ 64
#define G_ 64
#define C_ 256
#define FF_ 3072

// ---------------------------------------------------------------------------
// Generic fp32 tiled GEMM: C = op(A@W [+bias]) [+C]
// flags: 1 = add bias, 2 = relu, 4 = accumulate into C
// A: M x K (lda), W: K x N (ldw), C: M x N (ldc). M%64==0, N%64==0, K%16==0.
// ---------------------------------------------------------------------------
__global__ __launch_bounds__(256) void gemm_kernel(
    const float* __restrict__ A, const float* __restrict__ W,
    const float* __restrict__ bias, float* __restrict__ C,
    int M, int N, int K, int lda, int ldw, int ldc, int flags)
{
    __shared__ float As[16][65];
    __shared__ float Ws[16][65];
    const int t = threadIdx.x;
    const int tx = t & 15, ty = t >> 4;
    const int bm = blockIdx.y * 64, bn = blockIdx.x * 64;

    float acc[4][4] = {};

    for (int k0 = 0; k0 < K; k0 += 16) {
#pragma unroll
        for (int i = 0; i < 4; ++i) {
            int lin = t + i * 256;
            int m = lin >> 4, kk = lin & 15;
            As[kk][m] = A[(size_t)(bm + m) * lda + (k0 + kk)];
        }
#pragma unroll
        for (int i = 0; i < 4; ++i) {
            int lin = t + i * 256;
            int n = lin & 63, kk = lin >> 6;
            Ws[kk][n] = W[(size_t)(k0 + kk) * ldw + (bn + n)];
        }
        __syncthreads();
#pragma unroll
        for (int kk = 0; kk < 16; ++kk) {
            float ra[4], rb[4];
#pragma unroll
            for (int i = 0; i < 4; ++i) ra[i] = As[kk][ty * 4 + i];
#pragma unroll
            for (int i = 0; i < 4; ++i) rb[i] = Ws[kk][tx * 4 + i];
#pragma unroll
            for (int i = 0; i < 4; ++i)
#pragma unroll
                for (int j = 0; j < 4; ++j)
                    acc[i][j] += ra[i] * rb[j];
        }
        __syncthreads();
    }

#pragma unroll
    for (int i = 0; i < 4; ++i) {
        int m = bm + ty * 4 + i;
#pragma unroll
        for (int j = 0; j < 4; ++j) {
            int n = bn + tx * 4 + j;
            float v = acc[i][j];
            if (flags & 1) v += bias[n];
            if (flags & 2) v = fmaxf(v, 0.0f);
            float* p = &C[(size_t)m * ldc + n];
            if (flags & 4) v += *p;
            *p = v;
        }
    }
}

// ---------------------------------------------------------------------------
// Gather selected K/V source rows: Psel[b*128+i] = prev[b, sel(b,i), :]
// sel(b,i) = i for i<64 else rand_idx[b, i-64]
// ---------------------------------------------------------------------------
__global__ void gather_kernel(const float* __restrict__ prev,
                              const int* __restrict__ rand_idx,
                              float* __restrict__ Psel, int* __restrict__ sel)
{
    int j = blockIdx.x;               // 0 .. B*128-1
    int b = j >> 7, i = j & 127;
    int sv = (i < 64) ? i : rand_idx[b * G_ + (i - 64)];
    if (threadIdx.x == 0) sel[j] = sv;
    const float* src = prev + ((size_t)(b * S_ + sv)) * D_;
    float* dst = Psel + (size_t)j * D_;
    for (int d = threadIdx.x; d < D_; d += blockDim.x) dst[d] = src[d];
}

// ---------------------------------------------------------------------------
// Sparse attention: one wave per (b,s,h); 128 keys; masked softmax; PV.
// ---------------------------------------------------------------------------
__global__ __launch_bounds__(256) void attn_kernel(
    const float* __restrict__ q, const float* __restrict__ ksel,
    const float* __restrict__ vsel, const int* __restrict__ sel,
    float* __restrict__ out)
{
    const int wid = blockIdx.x * 4 + (threadIdx.x >> 6);
    const int lane = threadIdx.x & 63;
    const int h = wid % H_;
    const int s = (wid / H_) % S_;
    const int b = wid / (H_ * S_);
    const float scale = 0.125f;  // 1/sqrt(64)

    float qv = q[((size_t)(b * S_ + s)) * D_ + h * 64 + lane];

    const float* k0p = ksel + ((size_t)(b * 128 + lane)) * D_ + h * 64;
    const float* k1p = k0p + (size_t)64 * D_;
    float acc0 = 0.f, acc1 = 0.f;
#pragma unroll
    for (int d = 0; d < 64; ++d) {
        float qd = __shfl(qv, d, 64);
        acc0 += qd * k0p[d];
        acc1 += qd * k1p[d];
    }
    int sel0 = sel[b * 128 + lane];
    int sel1 = sel[b * 128 + 64 + lane];
    float s0 = (sel0 <= s) ? acc0 * scale : -1e9f;
    float s1 = (sel1 <= s) ? acc1 * scale : -1e9f;

    float m = fmaxf(s0, s1);
#pragma unroll
    for (int off = 32; off; off >>= 1) m = fmaxf(m, __shfl_xor(m, off, 64));
    float e0 = __expf(s0 - m), e1 = __expf(s1 - m);
    float z = e0 + e1;
#pragma unroll
    for (int off = 32; off; off >>= 1) z += __shfl_xor(z, off, 64);
    float inv = 1.0f / z;
    float a0 = e0 * inv, a1 = e1 * inv;

    const float* vbase = vsel + ((size_t)(b * 128)) * D_ + h * 64 + lane;
    float o = 0.f;
#pragma unroll
    for (int kk = 0; kk < 64; ++kk) {
        float a = __shfl(a0, kk, 64);
        o += a * vbase[(size_t)kk * D_];
    }
#pragma unroll
    for (int kk = 0; kk < 64; ++kk) {
        float a = __shfl(a1, kk, 64);
        o += a * vbase[(size_t)(64 + kk) * D_];
    }
    out[((size_t)(b * S_ + s)) * D_ + h * 64 + lane] = o;
}

// ---------------------------------------------------------------------------
// out[row] = LN(xa[row] + xb[row]) * g + beta   (row length 768, block 256)
// ---------------------------------------------------------------------------
__global__ __launch_bounds__(256) void addln_kernel(
    const float* __restrict__ xa, const float* __restrict__ xb,
    const float* __restrict__ g, const float* __restrict__ beta,
    float* __restrict__ out)
{
    const int row = blockIdx.x;
    const float* pa = xa + (size_t)row * D_;
    const float* pb = xb + (size_t)row * D_;
    float v[3];
    float sum = 0.f;
#pragma unroll
    for (int i = 0; i < 3; ++i) {
        int d = threadIdx.x + i * 256;
        v[i] = pa[d] + pb[d];
        sum += v[i];
    }
#pragma unroll
    for (int off = 32; off; off >>= 1) sum += __shfl_xor(sum, off, 64);
    __shared__ float r1[4], r2[4];
    int wv = threadIdx.x >> 6, ln = threadIdx.x & 63;
    if (ln == 0) r1[wv] = sum;
    __syncthreads();
    float mean = (r1[0] + r1[1] + r1[2] + r1[3]) * (1.0f / 768.0f);
    float sq = 0.f;
#pragma unroll
    for (int i = 0; i < 3; ++i) { v[i] -= mean; sq += v[i] * v[i]; }
#pragma unroll
    for (int off = 32; off; off >>= 1) sq += __shfl_xor(sq, off, 64);
    if (ln == 0) r2[wv] = sq;
    __syncthreads();
    float var = (r2[0] + r2[1] + r2[2] + r2[3]) * (1.0f / 768.0f);
    float rs = rsqrtf(var + 1e-5f);
    float* po = out + (size_t)row * D_;
#pragma unroll
    for (int i = 0; i < 3; ++i) {
        int d = threadIdx.x + i * 256;
        po[d] = v[i] * rs * g[d] + beta[d];
    }
}

// ---------------------------------------------------------------------------
// Class-attention precompute:
// U[d,h]   = sum_j Wqc[d, h*64+j] * Wkc[h*64+j]        (768 x 12)
// ab[h]    = sum_j bqc[h*64+j]    * Wkc[h*64+j]
// Wmix[h,n]= sum_j Wvc[h*64+j]    * Woc[h*64+j, n]     (12 x 768)
// bias2[n] = boc[n] + sum_d bvc[d]*Woc[d,n]
// ---------------------------------------------------------------------------
__global__ void precompute_U(const float* __restrict__ Wqc,
                             const float* __restrict__ Wkc,
                             const float* __restrict__ bqc,
                             float* __restrict__ U, float* __restrict__ ab)
{
    int idx = blockIdx.x * blockDim.x + threadIdx.x;  // 768*12
    if (idx < D_ * H_) {
        int d = idx / H_, h = idx % H_;
        float acc = 0.f;
        for (int j = 0; j < 64; ++j)
            acc += Wqc[(size_t)d * D_ + h * 64 + j] * Wkc[h * 64 + j];
        U[idx] = acc;
    }
    if (idx < H_) {
        float acc = 0.f;
        for (int j = 0; j < 64; ++j) acc += bqc[idx * 64 + j] * Wkc[idx * 64 + j];
        ab[idx] = acc;
    }
}

__global__ void precompute_mix(const float* __restrict__ Wvc,
                               const float* __restrict__ Woc,
                               const float* __restrict__ bvc,
                               const float* __restrict__ boc,
                               float* __restrict__ Wmix, float* __restrict__ bias2)
{
    int idx = blockIdx.x * blockDim.x + threadIdx.x;  // 12*768
    if (idx < H_ * D_) {
        int h = idx / D_, n = idx % D_;
        float acc = 0.f;
        for (int j = 0; j < 64; ++j)
            acc += Wvc[h * 64 + j] * Woc[(size_t)(h * 64 + j) * D_ + n];
        Wmix[idx] = acc;
    }
    if (idx < D_) {
        float acc = boc[idx];
        for (int d = 0; d < D_; ++d) acc += bvc[d] * Woc[(size_t)d * D_ + idx];
        bias2[idx] = acc;
    }
}

// alpha[row,h] = scale * ( x1[row] . U[:,h] + ab[h] )
__global__ __launch_bounds__(256) void alpha_kernel(
    const float* __restrict__ x1, const float* __restrict__ U,
    const float* __restrict__ ab, float* __restrict__ alpha)
{
    const int row = blockIdx.x;
    __shared__ float xs[D_];
    for (int d = threadIdx.x; d < D_; d += 256) xs[d] = x1[(size_t)row * D_ + d];
    __syncthreads();
    __shared__ float red[H_][16];
    int h = threadIdx.x >> 4, i = threadIdx.x & 15;
    if (h < H_) {
        float acc = 0.f;
        for (int j = i; j < D_; j += 16) acc += xs[j] * U[j * H_ + h];
        red[h][i] = acc;
    }
    __syncthreads();
    if (threadIdx.x < H_) {
        float acc = 0.f;
        for (int k = 0; k < 16; ++k) acc += red[threadIdx.x][k];
        alpha[(size_t)row * H_ + threadIdx.x] = 0.125f * (acc + ab[threadIdx.x]);
    }
}

// mu[row,h] = sum_c softmax_c(alpha[row,h]*cv[b,c]) * cv[b,c]; one wave/row
__global__ __launch_bounds__(256) void mu_kernel(
    const float* __restrict__ alpha, const float* __restrict__ cvec,
    float* __restrict__ mu)
{
    const int wid = blockIdx.x * 4 + (threadIdx.x >> 6);  // = b*S + s
    const int lane = threadIdx.x & 63;
    const int b = wid / S_;
    float cvv[4];
#pragma unroll
    for (int i = 0; i < 4; ++i) cvv[i] = cvec[b * C_ + lane * 4 + i];
    for (int h = 0; h < H_; ++h) {
        float a = alpha[(size_t)wid * H_ + h];
        float sc[4];
        float m = -1e30f;
#pragma unroll
        for (int i = 0; i < 4; ++i) { sc[i] = a * cvv[i]; m = fmaxf(m, sc[i]); }
#pragma unroll
        for (int off = 32; off; off >>= 1) m = fmaxf(m, __shfl_xor(m, off, 64));
        float z = 0.f, ms = 0.f;
#pragma unroll
        for (int i = 0; i < 4; ++i) {
            float e = __expf(sc[i] - m);
            z += e; ms += e * cvv[i];
        }
#pragma unroll
        for (int off = 32; off; off >>= 1) {
            z += __shfl_xor(z, off, 64);
            ms += __shfl_xor(ms, off, 64);
        }
        mu[(size_t)wid * H_ + h] = ms / z;
    }
}

// oc[row,n] = bias2[n] + sum_h mu[row,h]*Wmix[h,n]
__global__ __launch_bounds__(256) void oc_kernel(
    const float* __restrict__ mu, const float* __restrict__ Wmix,
    const float* __restrict__ bias2, float* __restrict__ oc)
{
    const int row = blockIdx.x;
    __shared__ float ms[H_];
    if (threadIdx.x < H_) ms[threadIdx.x] = mu[(size_t)row * H_ + threadIdx.x];
    __syncthreads();
    for (int n = threadIdx.x; n < D_; n += 256) {
        float acc = bias2[n];
#pragma unroll
        for (int h = 0; h < H_; ++h) acc += ms[h] * Wmix[h * D_ + n];
        oc[(size_t)row * D_ + n] = acc;
    }
}

// ---------------------------------------------------------------------------
extern "C" void kernel_launch(void* const* d_in, const int* in_sizes, int n_in,
                              void* d_out, int out_size, void* d_ws, size_t ws_size,
                              hipStream_t stream) {
    const float* cur   = (const float*)d_in[0];
    const float* prev  = (const float*)d_in[1];
    const float* cvec  = (const float*)d_in[2];
    const int*   ridx  = (const int*)d_in[3];
    const float* Wq  = (const float*)d_in[4];
    const float* bq  = (const float*)d_in[5];
    const float* Wk  = (const float*)d_in[6];
    const float* bk  = (const float*)d_in[7];
    const float* Wv  = (const float*)d_in[8];
    const float* bv  = (const float*)d_in[9];
    const float* Wo  = (const float*)d_in[10];
    const float* bo  = (const float*)d_in[11];
    const float* g1  = (const float*)d_in[12];
    const float* b1  = (const float*)d_in[13];
    const float* Wqc = (const float*)d_in[14];
    const float* bqc = (const float*)d_in[15];
    const float* Wkc = (const float*)d_in[16];
    const float* bkc = (const float*)d_in[17];  (void)bkc; // cancels in softmax
    const float* Wvc = (const float*)d_in[18];
    const float* bvc = (const float*)d_in[19];
    const float* Woc = (const float*)d_in[20];
    const float* boc = (const float*)d_in[21];
    const float* g2  = (const float*)d_in[22];
    const float* b2  = (const float*)d_in[23];
    const float* W1  = (const float*)d_in[24];
    const float* bf1 = (const float*)d_in[25];
    const float* W2  = (const float*)d_in[26];
    const float* bf2 = (const float*)d_in[27];
    const float* g3  = (const float*)d_in[28];
    const float* b3  = (const float*)d_in[29];
    float* outp = (float*)d_out;

    const size_t NBSD = (size_t)B_ * S_ * D_;       // 12,582,912
    const size_t NSEL = (size_t)B_ * 128 * D_;      // 393,216
    float* bufA  = (float*)d_ws;
    float* bufB  = bufA + NBSD;
    float* Psel  = bufB + NBSD;
    float* kselp = Psel + NSEL;
    float* vselp = kselp + NSEL;
    float* Ub    = vselp + NSEL;                    // 768*12
    float* abv   = Ub + (size_t)D_ * H_;            // 12 (pad 16)
    float* Wmix  = abv + 16;                        // 12*768
    float* bias2 = Wmix + (size_t)H_ * D_;          // 768
    float* alphab= bias2 + D_;                      // 16384*12
    float* mub   = alphab + (size_t)B_ * S_ * H_;   // 16384*12
    int*   selb  = (int*)(mub + (size_t)B_ * S_ * H_);  // 512 ints
    (void)ws_size; (void)in_sizes; (void)n_in; (void)out_size;

    const int M = B_ * S_;   // 16384

    // 1) gather selected rows + sel indices
    gather_kernel<<<B_ * 128, 256, 0, stream>>>(prev, ridx, Psel, selb);

    // 2) ksel / vsel projections (512 x 768 each)
    {
        dim3 g(D_ / 64, (B_ * 128) / 64);
        gemm_kernel<<<g, 256, 0, stream>>>(Psel, Wk, bk, kselp, B_ * 128, D_, D_, D_, D_, D_, 1);
        gemm_kernel<<<g, 256, 0, stream>>>(Psel, Wv, bv, vselp, B_ * 128, D_, D_, D_, D_, D_, 1);
    }

    // 3) q projection -> bufA
    {
        dim3 g(D_ / 64, M / 64);
        gemm_kernel<<<g, 256, 0, stream>>>(cur, Wq, bq, bufA, M, D_, D_, D_, D_, D_, 1);
    }

    // 4) sparse attention -> bufB
    attn_kernel<<<(B_ * S_ * H_) / 4, 256, 0, stream>>>(bufA, kselp, vselp, selb, bufB);

    // 5) output projection -> d_out (temp)
    {
        dim3 g(D_ / 64, M / 64);
        gemm_kernel<<<g, 256, 0, stream>>>(bufB, Wo, bo, outp, M, D_, D_, D_, D_, D_, 1);
    }

    // 6) x1 = LN(cur + o) -> bufA
    addln_kernel<<<M, 256, 0, stream>>>(cur, outp, g1, b1, bufA);

    // 7) class-attention precompute
    precompute_U<<<(D_ * H_ + 255) / 256, 256, 0, stream>>>(Wqc, Wkc, bqc, Ub, abv);
    precompute_mix<<<(H_ * D_ + 255) / 256, 256, 0, stream>>>(Wvc, Woc, bvc, boc, Wmix, bias2);

    // 8) alpha, mu, oc
    alpha_kernel<<<M, 256, 0, stream>>>(bufA, Ub, abv, alphab);
    mu_kernel<<<M / 4, 256, 0, stream>>>(alphab, cvec, mub);
    oc_kernel<<<M, 256, 0, stream>>>(mub, Wmix, bias2, bufB);

    // 9) x2 = LN(x1 + oc) -> d_out
    addln_kernel<<<M, 256, 0, stream>>>(bufA, bufB, g2, b2, outp);

    // 10) FF in 4 column-chunks of 768: hmid -> bufA, ff accum -> bufB
    for (int c = 0; c < 4; ++c) {
        dim3 g(D_ / 64, M / 64);
        gemm_kernel<<<g, 256, 0, stream>>>(outp, W1 + (size_t)c * D_, bf1 + (size_t)c * D_,
                                           bufA, M, D_, D_, D_, FF_, D_, 1 | 2);
        gemm_kernel<<<g, 256, 0, stream>>>(bufA, W2 + (size_t)c * D_ * D_, bf2,
                                           bufB, M, D_, D_, D_, D_, D_, (c == 0) ? 1 : 4);
    }

    // 11) out = LN(x2 + ff), in-place on d_out
    addln_kernel<<<M, 256, 0, stream>>>(outp, bufB, g3, b3, outp);
}

// Round 2
// 2263.192 us; speedup vs baseline: 2.5850x; 2.5850x over previous
//
#include <hip/hip_runtime.h>
#include <hip/hip_bf16.h>

#define B_ 4
#define S_ 4096
#define D_ 768
#define H_ 12
#define DH_ 64
#define G_ 64
#define C_ 256
#define FF_ 3072

typedef __attribute__((ext_vector_type(8))) short bf16x8;
typedef __attribute__((ext_vector_type(4))) float f32x4;

// ---------------------------------------------------------------------------
// bf16 MFMA GEMM: C = op(A @ B [+bias]) [+C]
// A: M x K row-major bf16 (lda elems). Bt: N x K row-major bf16 (B transposed,
// ldbt elems). Output: fp32 Cf or bf16 Cb, ldc = N.
// flags: 1=bias, 2=relu, 4=accumulate into Cf, 8=store bf16 to Cb
// M%128==0, N%128==0, K%32==0.
// ---------------------------------------------------------------------------
__global__ __launch_bounds__(256) void gemm_mfma(
    const __hip_bfloat16* __restrict__ A, const __hip_bfloat16* __restrict__ Bt,
    const float* __restrict__ bias, float* __restrict__ Cf,
    __hip_bfloat16* __restrict__ Cb,
    int M, int N, int K, int lda, int ldbt, int flags)
{
    const int t = threadIdx.x;
    const int lane = t & 63;
    const int wave = t >> 6;
    const int wr = wave >> 1, wc = wave & 1;     // 2x2 wave grid, 64x64 each
    const int qd = lane >> 4, r = lane & 15;
    const int bm = blockIdx.y * 128, bn = blockIdx.x * 128;

    // padded stride 40 elems (80 B) keeps ds_read_b128 ~2-way (free)
    __shared__ __hip_bfloat16 As[128 * 40];
    __shared__ __hip_bfloat16 Bs[128 * 40];

    f32x4 acc[4][4] = {};

    const int ar0 = t >> 2;            // 0..63
    const int ac0 = (t & 3) * 8;       // 0,8,16,24
    const __hip_bfloat16* Ap = A + (size_t)(bm + ar0) * lda + ac0;
    const __hip_bfloat16* Bp = Bt + (size_t)(bn + ar0) * ldbt + ac0;

    for (int k0 = 0; k0 < K; k0 += 32) {
        uint4 a0 = *(const uint4*)(Ap + k0);
        uint4 a1 = *(const uint4*)(Ap + (size_t)64 * lda + k0);
        uint4 b0 = *(const uint4*)(Bp + k0);
        uint4 b1 = *(const uint4*)(Bp + (size_t)64 * ldbt + k0);
        __syncthreads();
        *(uint4*)&As[ar0 * 40 + ac0] = a0;
        *(uint4*)&As[(ar0 + 64) * 40 + ac0] = a1;
        *(uint4*)&Bs[ar0 * 40 + ac0] = b0;
        *(uint4*)&Bs[(ar0 + 64) * 40 + ac0] = b1;
        __syncthreads();

        bf16x8 afr[4], bfr[4];
#pragma unroll
        for (int m = 0; m < 4; ++m)
            afr[m] = *(const bf16x8*)&As[(wr * 64 + m * 16 + r) * 40 + qd * 8];
#pragma unroll
        for (int n = 0; n < 4; ++n)
            bfr[n] = *(const bf16x8*)&Bs[(wc * 64 + n * 16 + r) * 40 + qd * 8];
#pragma unroll
        for (int m = 0; m < 4; ++m)
#pragma unroll
            for (int n = 0; n < 4; ++n)
                acc[m][n] = __builtin_amdgcn_mfma_f32_16x16x32_bf16(
                    afr[m], bfr[n], acc[m][n], 0, 0, 0);
    }

#pragma unroll
    for (int m = 0; m < 4; ++m) {
        int row0 = bm + wr * 64 + m * 16 + qd * 4;
#pragma unroll
        for (int n = 0; n < 4; ++n) {
            int col = bn + wc * 64 + n * 16 + r;
            float bv = (flags & 1) ? bias[col] : 0.0f;
#pragma unroll
            for (int i = 0; i < 4; ++i) {
                float v = acc[m][n][i] + bv;
                if (flags & 2) v = fmaxf(v, 0.0f);
                size_t off = (size_t)(row0 + i) * N + col;
                if (flags & 4) v += Cf[off];
                if (flags & 8) Cb[off] = __float2bfloat16(v);
                else           Cf[off] = v;
            }
        }
    }
}

// ---------------------------------------------------------------------------
// fp32 tiled GEMM (small inputs only): C = A@W + bias
// ---------------------------------------------------------------------------
__global__ __launch_bounds__(256) void gemm_kernel(
    const float* __restrict__ A, const float* __restrict__ W,
    const float* __restrict__ bias, float* __restrict__ C,
    int M, int N, int K, int lda, int ldw, int ldc, int flags)
{
    __shared__ float As[16][65];
    __shared__ float Ws[16][65];
    const int t = threadIdx.x;
    const int tx = t & 15, ty = t >> 4;
    const int bm = blockIdx.y * 64, bn = blockIdx.x * 64;
    float acc[4][4] = {};
    for (int k0 = 0; k0 < K; k0 += 16) {
#pragma unroll
        for (int i = 0; i < 4; ++i) {
            int lin = t + i * 256;
            int m = lin >> 4, kk = lin & 15;
            As[kk][m] = A[(size_t)(bm + m) * lda + (k0 + kk)];
        }
#pragma unroll
        for (int i = 0; i < 4; ++i) {
            int lin = t + i * 256;
            int n = lin & 63, kk = lin >> 6;
            Ws[kk][n] = W[(size_t)(k0 + kk) * ldw + (bn + n)];
        }
        __syncthreads();
#pragma unroll
        for (int kk = 0; kk < 16; ++kk) {
            float ra[4], rb[4];
#pragma unroll
            for (int i = 0; i < 4; ++i) ra[i] = As[kk][ty * 4 + i];
#pragma unroll
            for (int i = 0; i < 4; ++i) rb[i] = Ws[kk][tx * 4 + i];
#pragma unroll
            for (int i = 0; i < 4; ++i)
#pragma unroll
                for (int j = 0; j < 4; ++j)
                    acc[i][j] += ra[i] * rb[j];
        }
        __syncthreads();
    }
#pragma unroll
    for (int i = 0; i < 4; ++i) {
        int m = bm + ty * 4 + i;
#pragma unroll
        for (int j = 0; j < 4; ++j) {
            int n = bn + tx * 4 + j;
            float v = acc[i][j];
            if (flags & 1) v += bias[n];
            C[(size_t)m * ldc + n] = v;
        }
    }
}

// ---------------------------------------------------------------------------
// fp32 -> bf16 copy-convert
// ---------------------------------------------------------------------------
__global__ __launch_bounds__(256) void conv_bf16(const float* __restrict__ in,
                                                 __hip_bfloat16* __restrict__ out,
                                                 int n8)
{
    int i = blockIdx.x * 256 + threadIdx.x;
    if (i >= n8) return;
    const float4* p = (const float4*)(in + (size_t)i * 8);
    float4 v0 = p[0], v1 = p[1];
    __hip_bfloat16 o[8] = {
        __float2bfloat16(v0.x), __float2bfloat16(v0.y),
        __float2bfloat16(v0.z), __float2bfloat16(v0.w),
        __float2bfloat16(v1.x), __float2bfloat16(v1.y),
        __float2bfloat16(v1.z), __float2bfloat16(v1.w)};
    *(uint4*)(out + (size_t)i * 8) = *(const uint4*)o;
}

// ---------------------------------------------------------------------------
// W [K x N] fp32 -> Wt [N x K] bf16 (32x32 tiles)
// ---------------------------------------------------------------------------
__global__ __launch_bounds__(256) void transp_bf16(const float* __restrict__ W,
                                                   __hip_bfloat16* __restrict__ Wt,
                                                   int K, int N)
{
    __shared__ float s[32][33];
    int n0 = blockIdx.x * 32, k0 = blockIdx.y * 32;
    int tx = threadIdx.x & 31, ty = threadIdx.x >> 5;  // ty 0..7
#pragma unroll
    for (int i = 0; i < 4; ++i)
        s[ty + i * 8][tx] = W[(size_t)(k0 + ty + i * 8) * N + n0 + tx];
    __syncthreads();
#pragma unroll
    for (int i = 0; i < 4; ++i)
        Wt[(size_t)(n0 + ty + i * 8) * K + k0 + tx] =
            __float2bfloat16(s[tx][ty + i * 8]);
}

// ---------------------------------------------------------------------------
// Gather selected K/V source rows
// ---------------------------------------------------------------------------
__global__ void gather_kernel(const float* __restrict__ prev,
                              const int* __restrict__ rand_idx,
                              float* __restrict__ Psel, int* __restrict__ sel)
{
    int j = blockIdx.x;
    int b = j >> 7, i = j & 127;
    int sv = (i < 64) ? i : rand_idx[b * G_ + (i - 64)];
    if (threadIdx.x == 0) sel[j] = sv;
    const float* src = prev + ((size_t)(b * S_ + sv)) * D_;
    float* dst = Psel + (size_t)j * D_;
    for (int d = threadIdx.x; d < D_; d += blockDim.x) dst[d] = src[d];
}

// ---------------------------------------------------------------------------
// Sparse attention v2: block per (b,h,s-chunk); K/V staged in LDS.
// grid: (S/256, B*H). out is bf16.
// ---------------------------------------------------------------------------
__global__ __launch_bounds__(256) void attn2_kernel(
    const float* __restrict__ q, const float* __restrict__ ksel,
    const float* __restrict__ vsel, const int* __restrict__ sel,
    __hip_bfloat16* __restrict__ out)
{
    const int bh = blockIdx.y;
    const int b = bh / H_, h = bh % H_;
    const int s0 = blockIdx.x * 256;
    const int t = threadIdx.x;

    __shared__ float KsT[64][129];   // K^T: [d][key]
    __shared__ float Vs[128][68];    // V:   [key][d]
    __shared__ int ssel[128];

    {
        int kk = t >> 1, half = t & 1;
        const float* kp = ksel + (size_t)(b * 128 + kk) * D_ + h * 64 + half * 32;
        const float* vp = vsel + (size_t)(b * 128 + kk) * D_ + h * 64 + half * 32;
#pragma unroll
        for (int j = 0; j < 8; ++j) {
            float4 kv = *(const float4*)(kp + j * 4);
            float4 vv = *(const float4*)(vp + j * 4);
            int d = half * 32 + j * 4;
            KsT[d + 0][kk] = kv.x; KsT[d + 1][kk] = kv.y;
            KsT[d + 2][kk] = kv.z; KsT[d + 3][kk] = kv.w;
            *(float4*)&Vs[kk][d] = vv;
        }
        if (t < 128) ssel[t] = sel[b * 128 + t];
    }
    __syncthreads();

    const int wv = t >> 6, lane = t & 63;
    const int sel0 = ssel[lane], sel1 = ssel[64 + lane];
    const float scale = 0.125f;

    for (int si = wv; si < 256; si += 4) {
        int s = s0 + si;
        float qv = q[((size_t)(b * S_ + s)) * D_ + h * 64 + lane];

        float acc0 = 0.f, acc1 = 0.f;
#pragma unroll
        for (int d = 0; d < 64; ++d) {
            float qdv = __shfl(qv, d, 64);
            acc0 += qdv * KsT[d][lane];
            acc1 += qdv * KsT[d][64 + lane];
        }
        float sc0 = (sel0 <= s) ? acc0 * scale : -1e9f;
        float sc1 = (sel1 <= s) ? acc1 * scale : -1e9f;

        float m = fmaxf(sc0, sc1);
#pragma unroll
        for (int off = 32; off; off >>= 1) m = fmaxf(m, __shfl_xor(m, off, 64));
        float e0 = __expf(sc0 - m), e1 = __expf(sc1 - m);
        float z = e0 + e1;
#pragma unroll
        for (int off = 32; off; off >>= 1) z += __shfl_xor(z, off, 64);
        float inv = 1.0f / z;
        float a0 = e0 * inv, a1 = e1 * inv;

        float o = 0.f;
#pragma unroll
        for (int kk = 0; kk < 64; ++kk) {
            o += __shfl(a0, kk, 64) * Vs[kk][lane];
            o += __shfl(a1, kk, 64) * Vs[64 + kk][lane];
        }
        out[((size_t)(b * S_ + s)) * D_ + h * 64 + lane] = __float2bfloat16(o);
    }
}

// ---------------------------------------------------------------------------
// out[row] = LN(xa[row] + xb[row]) * g + beta ; optional bf16 copy of result
// ---------------------------------------------------------------------------
__global__ __launch_bounds__(256) void addln_kernel(
    const float* __restrict__ xa, const float* __restrict__ xb,
    const float* __restrict__ g, const float* __restrict__ beta,
    float* __restrict__ out, __hip_bfloat16* __restrict__ outb)
{
    const int row = blockIdx.x;
    const float* pa = xa + (size_t)row * D_;
    const float* pb = xb + (size_t)row * D_;
    float v[3];
    float sum = 0.f;
#pragma unroll
    for (int i = 0; i < 3; ++i) {
        int d = threadIdx.x + i * 256;
        v[i] = pa[d] + pb[d];
        sum += v[i];
    }
#pragma unroll
    for (int off = 32; off; off >>= 1) sum += __shfl_xor(sum, off, 64);
    __shared__ float r1[4], r2[4];
    int wv = threadIdx.x >> 6, ln = threadIdx.x & 63;
    if (ln == 0) r1[wv] = sum;
    __syncthreads();
    float mean = (r1[0] + r1[1] + r1[2] + r1[3]) * (1.0f / 768.0f);
    float sq = 0.f;
#pragma unroll
    for (int i = 0; i < 3; ++i) { v[i] -= mean; sq += v[i] * v[i]; }
#pragma unroll
    for (int off = 32; off; off >>= 1) sq += __shfl_xor(sq, off, 64);
    if (ln == 0) r2[wv] = sq;
    __syncthreads();
    float var = (r2[0] + r2[1] + r2[2] + r2[3]) * (1.0f / 768.0f);
    float rs = rsqrtf(var + 1e-5f);
    float* po = out + (size_t)row * D_;
#pragma unroll
    for (int i = 0; i < 3; ++i) {
        int d = threadIdx.x + i * 256;
        float val = v[i] * rs * g[d] + beta[d];
        po[d] = val;
        if (outb) outb[(size_t)row * D_ + d] = __float2bfloat16(val);
    }
}

// ---------------------------------------------------------------------------
// Class-attention precompute (rank-1 K/V collapse)
// ---------------------------------------------------------------------------
__global__ void precompute_U(const float* __restrict__ Wqc,
                             const float* __restrict__ Wkc,
                             const float* __restrict__ bqc,
                             float* __restrict__ U, float* __restrict__ ab)
{
    int idx = blockIdx.x * blockDim.x + threadIdx.x;
    if (idx < D_ * H_) {
        int d = idx / H_, h = idx % H_;
        float acc = 0.f;
        for (int j = 0; j < 64; ++j)
            acc += Wqc[(size_t)d * D_ + h * 64 + j] * Wkc[h * 64 + j];
        U[idx] = acc;
    }
    if (idx < H_) {
        float acc = 0.f;
        for (int j = 0; j < 64; ++j) acc += bqc[idx * 64 + j] * Wkc[idx * 64 + j];
        ab[idx] = acc;
    }
}

__global__ void precompute_mix(const float* __restrict__ Wvc,
                               const float* __restrict__ Woc,
                               const float* __restrict__ bvc,
                               const float* __restrict__ boc,
                               float* __restrict__ Wmix, float* __restrict__ bias2)
{
    int idx = blockIdx.x * blockDim.x + threadIdx.x;
    if (idx < H_ * D_) {
        int h = idx / D_, n = idx % D_;
        float acc = 0.f;
        for (int j = 0; j < 64; ++j)
            acc += Wvc[h * 64 + j] * Woc[(size_t)(h * 64 + j) * D_ + n];
        Wmix[idx] = acc;
    }
    if (idx < D_) {
        float acc = boc[idx];
        for (int d = 0; d < D_; ++d) acc += bvc[d] * Woc[(size_t)d * D_ + idx];
        bias2[idx] = acc;
    }
}

__global__ __launch_bounds__(256) void alpha_kernel(
    const float* __restrict__ x1, const float* __restrict__ U,
    const float* __restrict__ ab, float* __restrict__ alpha)
{
    const int row = blockIdx.x;
    __shared__ float xs[D_];
    for (int d = threadIdx.x; d < D_; d += 256) xs[d] = x1[(size_t)row * D_ + d];
    __syncthreads();
    __shared__ float red[H_][16];
    int h = threadIdx.x >> 4, i = threadIdx.x & 15;
    if (h < H_) {
        float acc = 0.f;
        for (int j = i; j < D_; j += 16) acc += xs[j] * U[j * H_ + h];
        red[h][i] = acc;
    }
    __syncthreads();
    if (threadIdx.x < H_) {
        float acc = 0.f;
        for (int k = 0; k < 16; ++k) acc += red[threadIdx.x][k];
        alpha[(size_t)row * H_ + threadIdx.x] = 0.125f * (acc + ab[threadIdx.x]);
    }
}

__global__ __launch_bounds__(256) void mu_kernel(
    const float* __restrict__ alpha, const float* __restrict__ cvec,
    float* __restrict__ mu)
{
    const int wid = blockIdx.x * 4 + (threadIdx.x >> 6);
    const int lane = threadIdx.x & 63;
    const int b = wid / S_;
    float cvv[4];
#pragma unroll
    for (int i = 0; i < 4; ++i) cvv[i] = cvec[b * C_ + lane * 4 + i];
    for (int h = 0; h < H_; ++h) {
        float a = alpha[(size_t)wid * H_ + h];
        float sc[4];
        float m = -1e30f;
#pragma unroll
        for (int i = 0; i < 4; ++i) { sc[i] = a * cvv[i]; m = fmaxf(m, sc[i]); }
#pragma unroll
        for (int off = 32; off; off >>= 1) m = fmaxf(m, __shfl_xor(m, off, 64));
        float z = 0.f, ms = 0.f;
#pragma unroll
        for (int i = 0; i < 4; ++i) {
            float e = __expf(sc[i] - m);
            z += e; ms += e * cvv[i];
        }
#pragma unroll
        for (int off = 32; off; off >>= 1) {
            z += __shfl_xor(z, off, 64);
            ms += __shfl_xor(ms, off, 64);
        }
        mu[(size_t)wid * H_ + h] = ms / z;
    }
}

__global__ __launch_bounds__(256) void oc_kernel(
    const float* __restrict__ mu, const float* __restrict__ Wmix,
    const float* __restrict__ bias2, float* __restrict__ oc)
{
    const int row = blockIdx.x;
    __shared__ float ms[H_];
    if (threadIdx.x < H_) ms[threadIdx.x] = mu[(size_t)row * H_ + threadIdx.x];
    __syncthreads();
    for (int n = threadIdx.x; n < D_; n += 256) {
        float acc = bias2[n];
#pragma unroll
        for (int h = 0; h < H_; ++h) acc += ms[h] * Wmix[h * D_ + n];
        oc[(size_t)row * D_ + n] = acc;
    }
}

// ---------------------------------------------------------------------------
extern "C" void kernel_launch(void* const* d_in, const int* in_sizes, int n_in,
                              void* d_out, int out_size, void* d_ws, size_t ws_size,
                              hipStream_t stream) {
    const float* cur   = (const float*)d_in[0];
    const float* prev  = (const float*)d_in[1];
    const float* cvec  = (const float*)d_in[2];
    const int*   ridx  = (const int*)d_in[3];
    const float* Wq  = (const float*)d_in[4];
    const float* bq  = (const float*)d_in[5];
    const float* Wk  = (const float*)d_in[6];
    const float* bk  = (const float*)d_in[7];
    const float* Wv  = (const float*)d_in[8];
    const float* bv  = (const float*)d_in[9];
    const float* Wo  = (const float*)d_in[10];
    const float* bo  = (const float*)d_in[11];
    const float* g1  = (const float*)d_in[12];
    const float* b1  = (const float*)d_in[13];
    const float* Wqc = (const float*)d_in[14];
    const float* bqc = (const float*)d_in[15];
    const float* Wkc = (const float*)d_in[16];
    const float* bkc = (const float*)d_in[17];  (void)bkc;
    const float* Wvc = (const float*)d_in[18];
    const float* bvc = (const float*)d_in[19];
    const float* Woc = (const float*)d_in[20];
    const float* boc = (const float*)d_in[21];
    const float* g2  = (const float*)d_in[22];
    const float* b2  = (const float*)d_in[23];
    const float* W1  = (const float*)d_in[24];
    const float* bf1 = (const float*)d_in[25];
    const float* W2  = (const float*)d_in[26];
    const float* bf2 = (const float*)d_in[27];
    const float* g3  = (const float*)d_in[28];
    const float* b3  = (const float*)d_in[29];
    float* outp = (float*)d_out;
    (void)ws_size; (void)in_sizes; (void)n_in; (void)out_size;

    const size_t NBSD = (size_t)B_ * S_ * D_;   // 12,582,912
    const size_t NSEL = (size_t)B_ * 128 * D_;  // 393,216

    float* bufA   = (float*)d_ws;
    float* bufB   = bufA + NBSD;
    float* Psel   = bufB + NBSD;
    float* kselp  = Psel + NSEL;
    float* vselp  = kselp + NSEL;
    float* Ub     = vselp + NSEL;
    float* abv    = Ub + (size_t)D_ * H_;
    float* Wmix   = abv + 16;
    float* bias2  = Wmix + (size_t)H_ * D_;
    float* alphab = bias2 + D_;
    float* mub    = alphab + (size_t)B_ * S_ * H_;
    int*   selb   = (int*)(mub + (size_t)B_ * S_ * H_);
    __hip_bfloat16* bf0   = (__hip_bfloat16*)(selb + 512);        // cur_bf -> o_bf -> x2_bf
    __hip_bfloat16* hmidb = bf0 + NBSD;                            // FF mid chunk
    __hip_bfloat16* Wqt   = hmidb + NBSD;                          // 768x768
    __hip_bfloat16* Wot   = Wqt + (size_t)D_ * D_;
    __hip_bfloat16* W1t   = Wot + (size_t)D_ * D_;                 // 3072x768
    __hip_bfloat16* W2t   = W1t + (size_t)D_ * FF_;                // 768x3072

    const int M = B_ * S_;  // 16384

    // 1) gather + selected-row K/V projections (small, fp32)
    gather_kernel<<<B_ * 128, 256, 0, stream>>>(prev, ridx, Psel, selb);
    {
        dim3 g(D_ / 64, (B_ * 128) / 64);
        gemm_kernel<<<g, 256, 0, stream>>>(Psel, Wk, bk, kselp, B_ * 128, D_, D_, D_, D_, D_, 1);
        gemm_kernel<<<g, 256, 0, stream>>>(Psel, Wv, bv, vselp, B_ * 128, D_, D_, D_, D_, D_, 1);
    }

    // 2) weight transposes + activation convert
    transp_bf16<<<dim3(D_ / 32, D_ / 32), 256, 0, stream>>>(Wq, Wqt, D_, D_);
    transp_bf16<<<dim3(D_ / 32, D_ / 32), 256, 0, stream>>>(Wo, Wot, D_, D_);
    transp_bf16<<<dim3(FF_ / 32, D_ / 32), 256, 0, stream>>>(W1, W1t, D_, FF_);
    transp_bf16<<<dim3(D_ / 32, FF_ / 32), 256, 0, stream>>>(W2, W2t, FF_, D_);
    conv_bf16<<<(int)(NBSD / 8 + 255) / 256, 256, 0, stream>>>(cur, bf0, (int)(NBSD / 8));

    // 3) q = cur @ Wq + bq  -> bufB (fp32)
    gemm_mfma<<<dim3(D_ / 128, M / 128), 256, 0, stream>>>(
        bf0, Wqt, bq, bufB, nullptr, M, D_, D_, D_, D_, 1);

    // 4) sparse attention -> bf0 (bf16, overwrites cur_bf)
    attn2_kernel<<<dim3(S_ / 256, B_ * H_), 256, 0, stream>>>(bufB, kselp, vselp, selb, bf0);

    // 5) o @ Wo + bo -> bufB (fp32)
    gemm_mfma<<<dim3(D_ / 128, M / 128), 256, 0, stream>>>(
        bf0, Wot, bo, bufB, nullptr, M, D_, D_, D_, D_, 1);

    // 6) x1 = LN(cur + o) -> bufA (fp32 only)
    addln_kernel<<<M, 256, 0, stream>>>(cur, bufB, g1, b1, bufA, nullptr);

    // 7) class attention (collapsed) -> oc in bufB
    precompute_U<<<(D_ * H_ + 255) / 256, 256, 0, stream>>>(Wqc, Wkc, bqc, Ub, abv);
    precompute_mix<<<(H_ * D_ + 255) / 256, 256, 0, stream>>>(Wvc, Woc, bvc, boc, Wmix, bias2);
    alpha_kernel<<<M, 256, 0, stream>>>(bufA, Ub, abv, alphab);
    mu_kernel<<<M / 4, 256, 0, stream>>>(alphab, cvec, mub);
    oc_kernel<<<M, 256, 0, stream>>>(mub, Wmix, bias2, bufB);

    // 8) x2 = LN(x1 + oc) -> d_out (fp32) + bf0 (bf16)
    addln_kernel<<<M, 256, 0, stream>>>(bufA, bufB, g2, b2, outp, bf0);

    // 9) FF in 4 column chunks of 768
    for (int c = 0; c < 4; ++c) {
        gemm_mfma<<<dim3(D_ / 128, M / 128), 256, 0, stream>>>(
            bf0, W1t + (size_t)c * D_ * D_, bf1 + (size_t)c * D_,
            nullptr, hmidb, M, D_, D_, D_, D_, 1 | 2 | 8);
        gemm_mfma<<<dim3(D_ / 128, M / 128), 256, 0, stream>>>(
            hmidb, W2t + (size_t)c * D_, bf2,
            bufB, nullptr, M, D_, D_, D_, FF_, (c == 0) ? 1 : 4);
    }

    // 10) out = LN(x2 + ff)
    addln_kernel<<<M, 256, 0, stream>>>(outp, bufB, g3, b3, outp, nullptr);
}

// Round 3
// 1024.324 us; speedup vs baseline: 5.7114x; 2.2094x over previous
//
#include <hip/hip_runtime.h>
#include <hip/hip_bf16.h>

#define B_ 4
#define S_ 4096
#define D_ 768
#define H_ 12
#define DH_ 64
#define G_ 64
#define C_ 256
#define FF_ 3072

typedef __attribute__((ext_vector_type(8))) short bf16x8;
typedef __attribute__((ext_vector_type(4))) float f32x4;
typedef unsigned short u16;

// ---------------------------------------------------------------------------
// bf16 MFMA GEMM: C = op(A @ B [+bias]) [+C]
// flags: 1=bias, 2=relu, 4=accumulate into Cf, 8=store bf16 to Cb
// ---------------------------------------------------------------------------
__global__ __launch_bounds__(256) void gemm_mfma(
    const __hip_bfloat16* __restrict__ A, const __hip_bfloat16* __restrict__ Bt,
    const float* __restrict__ bias, float* __restrict__ Cf,
    __hip_bfloat16* __restrict__ Cb,
    int M, int N, int K, int lda, int ldbt, int flags)
{
    const int t = threadIdx.x;
    const int lane = t & 63;
    const int wave = t >> 6;
    const int wr = wave >> 1, wc = wave & 1;
    const int qd = lane >> 4, r = lane & 15;
    const int bm = blockIdx.y * 128, bn = blockIdx.x * 128;

    __shared__ __hip_bfloat16 As[128 * 40];
    __shared__ __hip_bfloat16 Bs[128 * 40];

    f32x4 acc[4][4] = {};

    const int ar0 = t >> 2;
    const int ac0 = (t & 3) * 8;
    const __hip_bfloat16* Ap = A + (size_t)(bm + ar0) * lda + ac0;
    const __hip_bfloat16* Bp = Bt + (size_t)(bn + ar0) * ldbt + ac0;

    for (int k0 = 0; k0 < K; k0 += 32) {
        uint4 a0 = *(const uint4*)(Ap + k0);
        uint4 a1 = *(const uint4*)(Ap + (size_t)64 * lda + k0);
        uint4 b0 = *(const uint4*)(Bp + k0);
        uint4 b1 = *(const uint4*)(Bp + (size_t)64 * ldbt + k0);
        __syncthreads();
        *(uint4*)&As[ar0 * 40 + ac0] = a0;
        *(uint4*)&As[(ar0 + 64) * 40 + ac0] = a1;
        *(uint4*)&Bs[ar0 * 40 + ac0] = b0;
        *(uint4*)&Bs[(ar0 + 64) * 40 + ac0] = b1;
        __syncthreads();

        bf16x8 afr[4], bfr[4];
#pragma unroll
        for (int m = 0; m < 4; ++m)
            afr[m] = *(const bf16x8*)&As[(wr * 64 + m * 16 + r) * 40 + qd * 8];
#pragma unroll
        for (int n = 0; n < 4; ++n)
            bfr[n] = *(const bf16x8*)&Bs[(wc * 64 + n * 16 + r) * 40 + qd * 8];
#pragma unroll
        for (int m = 0; m < 4; ++m)
#pragma unroll
            for (int n = 0; n < 4; ++n)
                acc[m][n] = __builtin_amdgcn_mfma_f32_16x16x32_bf16(
                    afr[m], bfr[n], acc[m][n], 0, 0, 0);
    }

#pragma unroll
    for (int m = 0; m < 4; ++m) {
        int row0 = bm + wr * 64 + m * 16 + qd * 4;
#pragma unroll
        for (int n = 0; n < 4; ++n) {
            int col = bn + wc * 64 + n * 16 + r;
            float bv = (flags & 1) ? bias[col] : 0.0f;
#pragma unroll
            for (int i = 0; i < 4; ++i) {
                float v = acc[m][n][i] + bv;
                if (flags & 2) v = fmaxf(v, 0.0f);
                size_t off = (size_t)(row0 + i) * N + col;
                if (flags & 4) v += Cf[off];
                if (flags & 8) Cb[off] = __float2bfloat16(v);
                else           Cf[off] = v;
            }
        }
    }
}

// ---------------------------------------------------------------------------
// fp32 tiled GEMM (small inputs): C = A@W + bias; flag 8 = store bf16 to Cb
// ---------------------------------------------------------------------------
__global__ __launch_bounds__(256) void gemm_kernel(
    const float* __restrict__ A, const float* __restrict__ W,
    const float* __restrict__ bias, float* __restrict__ C,
    __hip_bfloat16* __restrict__ Cb,
    int M, int N, int K, int lda, int ldw, int ldc, int flags)
{
    __shared__ float As[16][65];
    __shared__ float Ws[16][65];
    const int t = threadIdx.x;
    const int tx = t & 15, ty = t >> 4;
    const int bm = blockIdx.y * 64, bn = blockIdx.x * 64;
    float acc[4][4] = {};
    for (int k0 = 0; k0 < K; k0 += 16) {
#pragma unroll
        for (int i = 0; i < 4; ++i) {
            int lin = t + i * 256;
            int m = lin >> 4, kk = lin & 15;
            As[kk][m] = A[(size_t)(bm + m) * lda + (k0 + kk)];
        }
#pragma unroll
        for (int i = 0; i < 4; ++i) {
            int lin = t + i * 256;
            int n = lin & 63, kk = lin >> 6;
            Ws[kk][n] = W[(size_t)(k0 + kk) * ldw + (bn + n)];
        }
        __syncthreads();
#pragma unroll
        for (int kk = 0; kk < 16; ++kk) {
            float ra[4], rb[4];
#pragma unroll
            for (int i = 0; i < 4; ++i) ra[i] = As[kk][ty * 4 + i];
#pragma unroll
            for (int i = 0; i < 4; ++i) rb[i] = Ws[kk][tx * 4 + i];
#pragma unroll
            for (int i = 0; i < 4; ++i)
#pragma unroll
                for (int j = 0; j < 4; ++j)
                    acc[i][j] += ra[i] * rb[j];
        }
        __syncthreads();
    }
#pragma unroll
    for (int i = 0; i < 4; ++i) {
        int m = bm + ty * 4 + i;
#pragma unroll
        for (int j = 0; j < 4; ++j) {
            int n = bn + tx * 4 + j;
            float v = acc[i][j];
            if (flags & 1) v += bias[n];
            size_t off = (size_t)m * ldc + n;
            if (flags & 8) Cb[off] = __float2bfloat16(v);
            else           C[off] = v;
        }
    }
}

// ---------------------------------------------------------------------------
__global__ __launch_bounds__(256) void conv_bf16(const float* __restrict__ in,
                                                 __hip_bfloat16* __restrict__ out,
                                                 int n8)
{
    int i = blockIdx.x * 256 + threadIdx.x;
    if (i >= n8) return;
    const float4* p = (const float4*)(in + (size_t)i * 8);
    float4 v0 = p[0], v1 = p[1];
    __hip_bfloat16 o[8] = {
        __float2bfloat16(v0.x), __float2bfloat16(v0.y),
        __float2bfloat16(v0.z), __float2bfloat16(v0.w),
        __float2bfloat16(v1.x), __float2bfloat16(v1.y),
        __float2bfloat16(v1.z), __float2bfloat16(v1.w)};
    *(uint4*)(out + (size_t)i * 8) = *(const uint4*)o;
}

// ---------------------------------------------------------------------------
__global__ __launch_bounds__(256) void transp_bf16(const float* __restrict__ W,
                                                   __hip_bfloat16* __restrict__ Wt,
                                                   int K, int N)
{
    __shared__ float s[32][33];
    int n0 = blockIdx.x * 32, k0 = blockIdx.y * 32;
    int tx = threadIdx.x & 31, ty = threadIdx.x >> 5;
#pragma unroll
    for (int i = 0; i < 4; ++i)
        s[ty + i * 8][tx] = W[(size_t)(k0 + ty + i * 8) * N + n0 + tx];
    __syncthreads();
#pragma unroll
    for (int i = 0; i < 4; ++i)
        Wt[(size_t)(n0 + ty + i * 8) * K + k0 + tx] =
            __float2bfloat16(s[tx][ty + i * 8]);
}

// ---------------------------------------------------------------------------
__global__ void gather_kernel(const float* __restrict__ prev,
                              const int* __restrict__ rand_idx,
                              float* __restrict__ Psel, int* __restrict__ sel)
{
    int j = blockIdx.x;
    int b = j >> 7, i = j & 127;
    int sv = (i < 64) ? i : rand_idx[b * G_ + (i - 64)];
    if (threadIdx.x == 0) sel[j] = sv;
    const float* src = prev + ((size_t)(b * S_ + sv)) * D_;
    float* dst = Psel + (size_t)j * D_;
    for (int d = threadIdx.x; d < D_; d += blockDim.x) dst[d] = src[d];
}

// ---------------------------------------------------------------------------
// MFMA sparse attention: block = (s-chunk 256, b*h); 4 waves x 64 rows.
// q/k/v bf16. S=Q@K^T (frags direct from global), in-reg masked softmax,
// P->LDS (bf16), O=P@V with V^T staged in LDS. out bf16.
// ---------------------------------------------------------------------------
__global__ __launch_bounds__(256) void attn3_kernel(
    const u16* __restrict__ qb, const u16* __restrict__ kb,
    const u16* __restrict__ vb, const int* __restrict__ sel,
    u16* __restrict__ out)
{
    const int bh = blockIdx.y;
    const int b = bh / H_, h = bh % H_;
    const int s0 = blockIdx.x * 256;
    const int t = threadIdx.x;
    const int w = t >> 6, lane = t & 63;
    const int r = lane & 15, qd = lane >> 4;

    __shared__ u16 Vt[64][136];        // V^T [d][key]
    __shared__ u16 Plds[4][32][136];   // per-wave P [row][key]
    __shared__ int ssel[128];

    {
        int key0 = t >> 4;             // 0..15
        int d0 = (t & 15) * 4;
        for (int kk = key0; kk < 128; kk += 16) {
            ushort4 v = *(const ushort4*)(vb + (size_t)(b * 128 + kk) * D_ + h * 64 + d0);
            Vt[d0 + 0][kk] = v.x; Vt[d0 + 1][kk] = v.y;
            Vt[d0 + 2][kk] = v.z; Vt[d0 + 3][kk] = v.w;
        }
        if (t < 128) ssel[t] = sel[b * 128 + t];
    }
    __syncthreads();

    int selv[8];
#pragma unroll
    for (int n = 0; n < 8; ++n) selv[n] = ssel[n * 16 + r];

    for (int pass = 0; pass < 2; ++pass) {
        const int sbase = s0 + w * 64 + pass * 32;
        f32x4 accs[2][8] = {};

        // --- QK^T: A-frags from q rows, B-frags from ksel rows (both global)
#pragma unroll
        for (int ks = 0; ks < 2; ++ks) {
            bf16x8 af[2];
#pragma unroll
            for (int m = 0; m < 2; ++m)
                af[m] = *(const bf16x8*)(qb + (size_t)(b * S_ + sbase + m * 16 + r) * D_ + h * 64 + ks * 32 + qd * 8);
#pragma unroll
            for (int n = 0; n < 8; ++n) {
                bf16x8 bfv = *(const bf16x8*)(kb + (size_t)(b * 128 + n * 16 + r) * D_ + h * 64 + ks * 32 + qd * 8);
#pragma unroll
                for (int m = 0; m < 2; ++m)
                    accs[m][n] = __builtin_amdgcn_mfma_f32_16x16x32_bf16(
                        af[m], bfv, accs[m][n], 0, 0, 0);
            }
        }

        // --- mask + row softmax (row group = 16 lanes sharing qd)
#pragma unroll
        for (int m = 0; m < 2; ++m) {
#pragma unroll
            for (int i = 0; i < 4; ++i) {
                int srow = sbase + m * 16 + qd * 4 + i;
                float pm = -3e38f;
#pragma unroll
                for (int n = 0; n < 8; ++n) {
                    float sc = accs[m][n][i] * 0.125f;
                    if (selv[n] > srow) sc = -1e9f;
                    accs[m][n][i] = sc;
                    pm = fmaxf(pm, sc);
                }
#pragma unroll
                for (int off = 1; off < 16; off <<= 1)
                    pm = fmaxf(pm, __shfl_xor(pm, off, 64));
                float ps = 0.f;
#pragma unroll
                for (int n = 0; n < 8; ++n) {
                    float e = __expf(accs[m][n][i] - pm);
                    accs[m][n][i] = e;
                    ps += e;
                }
#pragma unroll
                for (int off = 1; off < 16; off <<= 1)
                    ps += __shfl_xor(ps, off, 64);
                float inv = 1.0f / ps;
#pragma unroll
                for (int n = 0; n < 8; ++n)
                    accs[m][n][i] *= inv;
            }
        }

        // --- P -> LDS (bf16), [row][key]
#pragma unroll
        for (int m = 0; m < 2; ++m)
#pragma unroll
            for (int n = 0; n < 8; ++n)
#pragma unroll
                for (int i = 0; i < 4; ++i) {
                    __hip_bfloat16 pb = __float2bfloat16(accs[m][n][i]);
                    Plds[w][m * 16 + qd * 4 + i][n * 16 + r] = *(u16*)&pb;
                }

        // --- O = P @ V
        f32x4 acco[2][4] = {};
#pragma unroll
        for (int ks = 0; ks < 4; ++ks) {
            bf16x8 pa[2];
#pragma unroll
            for (int m = 0; m < 2; ++m)
                pa[m] = *(const bf16x8*)&Plds[w][m * 16 + r][ks * 32 + qd * 8];
#pragma unroll
            for (int nd = 0; nd < 4; ++nd) {
                bf16x8 bv = *(const bf16x8*)&Vt[nd * 16 + r][ks * 32 + qd * 8];
#pragma unroll
                for (int m = 0; m < 2; ++m)
                    acco[m][nd] = __builtin_amdgcn_mfma_f32_16x16x32_bf16(
                        pa[m], bv, acco[m][nd], 0, 0, 0);
            }
        }

        // --- store O (bf16)
#pragma unroll
        for (int m = 0; m < 2; ++m)
#pragma unroll
            for (int nd = 0; nd < 4; ++nd)
#pragma unroll
                for (int i = 0; i < 4; ++i) {
                    __hip_bfloat16 ob = __float2bfloat16(acco[m][nd][i]);
                    out[(size_t)(b * S_ + sbase + m * 16 + qd * 4 + i) * D_ + h * 64 + nd * 16 + r] = *(u16*)&ob;
                }
    }
}

// ---------------------------------------------------------------------------
__global__ __launch_bounds__(256) void addln_kernel(
    const float* __restrict__ xa, const float* __restrict__ xb,
    const float* __restrict__ g, const float* __restrict__ beta,
    float* __restrict__ out, __hip_bfloat16* __restrict__ outb)
{
    const int row = blockIdx.x;
    const float* pa = xa + (size_t)row * D_;
    const float* pb = xb + (size_t)row * D_;
    float v[3];
    float sum = 0.f;
#pragma unroll
    for (int i = 0; i < 3; ++i) {
        int d = threadIdx.x + i * 256;
        v[i] = pa[d] + pb[d];
        sum += v[i];
    }
#pragma unroll
    for (int off = 32; off; off >>= 1) sum += __shfl_xor(sum, off, 64);
    __shared__ float r1[4], r2[4];
    int wv = threadIdx.x >> 6, ln = threadIdx.x & 63;
    if (ln == 0) r1[wv] = sum;
    __syncthreads();
    float mean = (r1[0] + r1[1] + r1[2] + r1[3]) * (1.0f / 768.0f);
    float sq = 0.f;
#pragma unroll
    for (int i = 0; i < 3; ++i) { v[i] -= mean; sq += v[i] * v[i]; }
#pragma unroll
    for (int off = 32; off; off >>= 1) sq += __shfl_xor(sq, off, 64);
    if (ln == 0) r2[wv] = sq;
    __syncthreads();
    float var = (r2[0] + r2[1] + r2[2] + r2[3]) * (1.0f / 768.0f);
    float rs = rsqrtf(var + 1e-5f);
    float* po = out + (size_t)row * D_;
#pragma unroll
    for (int i = 0; i < 3; ++i) {
        int d = threadIdx.x + i * 256;
        float val = v[i] * rs * g[d] + beta[d];
        po[d] = val;
        if (outb) outb[(size_t)row * D_ + d] = __float2bfloat16(val);
    }
}

// ---------------------------------------------------------------------------
__global__ void precompute_U(const float* __restrict__ Wqc,
                             const float* __restrict__ Wkc,
                             const float* __restrict__ bqc,
                             float* __restrict__ U, float* __restrict__ ab)
{
    int idx = blockIdx.x * blockDim.x + threadIdx.x;
    if (idx < D_ * H_) {
        int d = idx / H_, h = idx % H_;
        float acc = 0.f;
        for (int j = 0; j < 64; ++j)
            acc += Wqc[(size_t)d * D_ + h * 64 + j] * Wkc[h * 64 + j];
        U[idx] = acc;
    }
    if (idx < H_) {
        float acc = 0.f;
        for (int j = 0; j < 64; ++j) acc += bqc[idx * 64 + j] * Wkc[idx * 64 + j];
        ab[idx] = acc;
    }
}

__global__ void precompute_mix(const float* __restrict__ Wvc,
                               const float* __restrict__ Woc,
                               const float* __restrict__ bvc,
                               const float* __restrict__ boc,
                               float* __restrict__ Wmix, float* __restrict__ bias2)
{
    int idx = blockIdx.x * blockDim.x + threadIdx.x;
    if (idx < H_ * D_) {
        int h = idx / D_, n = idx % D_;
        float acc = 0.f;
        for (int j = 0; j < 64; ++j)
            acc += Wvc[h * 64 + j] * Woc[(size_t)(h * 64 + j) * D_ + n];
        Wmix[idx] = acc;
    }
    if (idx < D_) {
        float acc = boc[idx];
        for (int d = 0; d < D_; ++d) acc += bvc[d] * Woc[(size_t)d * D_ + idx];
        bias2[idx] = acc;
    }
}

__global__ __launch_bounds__(256) void alpha_kernel(
    const float* __restrict__ x1, const float* __restrict__ U,
    const float* __restrict__ ab, float* __restrict__ alpha)
{
    const int row = blockIdx.x;
    __shared__ float xs[D_];
    for (int d = threadIdx.x; d < D_; d += 256) xs[d] = x1[(size_t)row * D_ + d];
    __syncthreads();
    __shared__ float red[H_][16];
    int h = threadIdx.x >> 4, i = threadIdx.x & 15;
    if (h < H_) {
        float acc = 0.f;
        for (int j = i; j < D_; j += 16) acc += xs[j] * U[j * H_ + h];
        red[h][i] = acc;
    }
    __syncthreads();
    if (threadIdx.x < H_) {
        float acc = 0.f;
        for (int k = 0; k < 16; ++k) acc += red[threadIdx.x][k];
        alpha[(size_t)row * H_ + threadIdx.x] = 0.125f * (acc + ab[threadIdx.x]);
    }
}

__global__ __launch_bounds__(256) void mu_kernel(
    const float* __restrict__ alpha, const float* __restrict__ cvec,
    float* __restrict__ mu)
{
    const int wid = blockIdx.x * 4 + (threadIdx.x >> 6);
    const int lane = threadIdx.x & 63;
    const int b = wid / S_;
    float cvv[4];
#pragma unroll
    for (int i = 0; i < 4; ++i) cvv[i] = cvec[b * C_ + lane * 4 + i];
    for (int h = 0; h < H_; ++h) {
        float a = alpha[(size_t)wid * H_ + h];
        float sc[4];
        float m = -1e30f;
#pragma unroll
        for (int i = 0; i < 4; ++i) { sc[i] = a * cvv[i]; m = fmaxf(m, sc[i]); }
#pragma unroll
        for (int off = 32; off; off >>= 1) m = fmaxf(m, __shfl_xor(m, off, 64));
        float z = 0.f, ms = 0.f;
#pragma unroll
        for (int i = 0; i < 4; ++i) {
            float e = __expf(sc[i] - m);
            z += e; ms += e * cvv[i];
        }
#pragma unroll
        for (int off = 32; off; off >>= 1) {
            z += __shfl_xor(z, off, 64);
            ms += __shfl_xor(ms, off, 64);
        }
        mu[(size_t)wid * H_ + h] = ms / z;
    }
}

__global__ __launch_bounds__(256) void oc_kernel(
    const float* __restrict__ mu, const float* __restrict__ Wmix,
    const float* __restrict__ bias2, float* __restrict__ oc)
{
    const int row = blockIdx.x;
    __shared__ float ms[H_];
    if (threadIdx.x < H_) ms[threadIdx.x] = mu[(size_t)row * H_ + threadIdx.x];
    __syncthreads();
    for (int n = threadIdx.x; n < D_; n += 256) {
        float acc = bias2[n];
#pragma unroll
        for (int h = 0; h < H_; ++h) acc += ms[h] * Wmix[h * D_ + n];
        oc[(size_t)row * D_ + n] = acc;
    }
}

// ---------------------------------------------------------------------------
extern "C" void kernel_launch(void* const* d_in, const int* in_sizes, int n_in,
                              void* d_out, int out_size, void* d_ws, size_t ws_size,
                              hipStream_t stream) {
    const float* cur   = (const float*)d_in[0];
    const float* prev  = (const float*)d_in[1];
    const float* cvec  = (const float*)d_in[2];
    const int*   ridx  = (const int*)d_in[3];
    const float* Wq  = (const float*)d_in[4];
    const float* bq  = (const float*)d_in[5];
    const float* Wk  = (const float*)d_in[6];
    const float* bk  = (const float*)d_in[7];
    const float* Wv  = (const float*)d_in[8];
    const float* bv  = (const float*)d_in[9];
    const float* Wo  = (const float*)d_in[10];
    const float* bo  = (const float*)d_in[11];
    const float* g1  = (const float*)d_in[12];
    const float* b1  = (const float*)d_in[13];
    const float* Wqc = (const float*)d_in[14];
    const float* bqc = (const float*)d_in[15];
    const float* Wkc = (const float*)d_in[16];
    const float* bkc = (const float*)d_in[17];  (void)bkc;
    const float* Wvc = (const float*)d_in[18];
    const float* bvc = (const float*)d_in[19];
    const float* Woc = (const float*)d_in[20];
    const float* boc = (const float*)d_in[21];
    const float* g2  = (const float*)d_in[22];
    const float* b2  = (const float*)d_in[23];
    const float* W1  = (const float*)d_in[24];
    const float* bf1 = (const float*)d_in[25];
    const float* W2  = (const float*)d_in[26];
    const float* bf2 = (const float*)d_in[27];
    const float* g3  = (const float*)d_in[28];
    const float* b3  = (const float*)d_in[29];
    float* outp = (float*)d_out;
    (void)ws_size; (void)in_sizes; (void)n_in; (void)out_size;

    const size_t NBSD = (size_t)B_ * S_ * D_;
    const size_t NSEL = (size_t)B_ * 128 * D_;

    float* bufA   = (float*)d_ws;
    float* bufB   = bufA + NBSD;
    float* Psel   = bufB + NBSD;
    float* kself  = Psel + NSEL;          // reused as bf16
    float* vself  = kself + NSEL;         // reused as bf16
    float* Ub     = vself + NSEL;
    float* abv    = Ub + (size_t)D_ * H_;
    float* Wmix   = abv + 16;
    float* bias2  = Wmix + (size_t)H_ * D_;
    float* alphab = bias2 + D_;
    float* mub    = alphab + (size_t)B_ * S_ * H_;
    int*   selb   = (int*)(mub + (size_t)B_ * S_ * H_);
    __hip_bfloat16* bf0   = (__hip_bfloat16*)(selb + 512);
    __hip_bfloat16* hmidb = bf0 + NBSD;
    __hip_bfloat16* Wqt   = hmidb + NBSD;
    __hip_bfloat16* Wot   = Wqt + (size_t)D_ * D_;
    __hip_bfloat16* W1t   = Wot + (size_t)D_ * D_;
    __hip_bfloat16* W2t   = W1t + (size_t)D_ * FF_;
    __hip_bfloat16* kselb = (__hip_bfloat16*)kself;
    __hip_bfloat16* vselb = (__hip_bfloat16*)vself;

    const int M = B_ * S_;

    // 1) gather + selected-row K/V projections (bf16 out)
    gather_kernel<<<B_ * 128, 256, 0, stream>>>(prev, ridx, Psel, selb);
    {
        dim3 g(D_ / 64, (B_ * 128) / 64);
        gemm_kernel<<<g, 256, 0, stream>>>(Psel, Wk, bk, nullptr, kselb, B_ * 128, D_, D_, D_, D_, D_, 1 | 8);
        gemm_kernel<<<g, 256, 0, stream>>>(Psel, Wv, bv, nullptr, vselb, B_ * 128, D_, D_, D_, D_, D_, 1 | 8);
    }

    // 2) weight transposes + activation convert
    transp_bf16<<<dim3(D_ / 32, D_ / 32), 256, 0, stream>>>(Wq, Wqt, D_, D_);
    transp_bf16<<<dim3(D_ / 32, D_ / 32), 256, 0, stream>>>(Wo, Wot, D_, D_);
    transp_bf16<<<dim3(FF_ / 32, D_ / 32), 256, 0, stream>>>(W1, W1t, D_, FF_);
    transp_bf16<<<dim3(D_ / 32, FF_ / 32), 256, 0, stream>>>(W2, W2t, FF_, D_);
    conv_bf16<<<(int)(NBSD / 8 + 255) / 256, 256, 0, stream>>>(cur, bf0, (int)(NBSD / 8));

    // 3) q = cur @ Wq + bq -> hmidb (bf16)
    gemm_mfma<<<dim3(D_ / 128, M / 128), 256, 0, stream>>>(
        bf0, Wqt, bq, nullptr, hmidb, M, D_, D_, D_, D_, 1 | 8);

    // 4) MFMA sparse attention -> bf0 (bf16)
    attn3_kernel<<<dim3(S_ / 256, B_ * H_), 256, 0, stream>>>(
        (const u16*)hmidb, (const u16*)kselb, (const u16*)vselb, selb, (u16*)bf0);

    // 5) o @ Wo + bo -> bufB (fp32)
    gemm_mfma<<<dim3(D_ / 128, M / 128), 256, 0, stream>>>(
        bf0, Wot, bo, bufB, nullptr, M, D_, D_, D_, D_, 1);

    // 6) x1 = LN(cur + o) -> bufA
    addln_kernel<<<M, 256, 0, stream>>>(cur, bufB, g1, b1, bufA, nullptr);

    // 7) class attention (collapsed)
    precompute_U<<<(D_ * H_ + 255) / 256, 256, 0, stream>>>(Wqc, Wkc, bqc, Ub, abv);
    precompute_mix<<<(H_ * D_ + 255) / 256, 256, 0, stream>>>(Wvc, Woc, bvc, boc, Wmix, bias2);
    alpha_kernel<<<M, 256, 0, stream>>>(bufA, Ub, abv, alphab);
    mu_kernel<<<M / 4, 256, 0, stream>>>(alphab, cvec, mub);
    oc_kernel<<<M, 256, 0, stream>>>(mub, Wmix, bias2, bufB);

    // 8) x2 = LN(x1 + oc) -> d_out (fp32) + bf0 (bf16)
    addln_kernel<<<M, 256, 0, stream>>>(bufA, bufB, g2, b2, outp, bf0);

    // 9) FF in 4 column chunks of 768
    for (int c = 0; c < 4; ++c) {
        gemm_mfma<<<dim3(D_ / 128, M / 128), 256, 0, stream>>>(
            bf0, W1t + (size_t)c * D_ * D_, bf1 + (size_t)c * D_,
            nullptr, hmidb, M, D_, D_, D_, D_, 1 | 2 | 8);
        gemm_mfma<<<dim3(D_ / 128, M / 128), 256, 0, stream>>>(
            hmidb, W2t + (size_t)c * D_, bf2,
            bufB, nullptr, M, D_, D_, D_, FF_, (c == 0) ? 1 : 4);
    }

    // 10) out = LN(x2 + ff)
    addln_kernel<<<M, 256, 0, stream>>>(outp, bufB, g3, b3, outp, nullptr);
}

// Round 4
// 884.981 us; speedup vs baseline: 6.6107x; 1.1575x over previous
//
#include <hip/hip_runtime.h>
#include <hip/hip_bf16.h>

#define B_ 4
#define S_ 4096
#define D_ 768
#define H_ 12
#define DH_ 64
#define G_ 64
#define C_ 256
#define FF_ 3072

typedef __attribute__((ext_vector_type(8))) short bf16x8;
typedef __attribute__((ext_vector_type(4))) float f32x4;
typedef unsigned short u16;

// ---------------------------------------------------------------------------
// async global->LDS 16B (wave-uniform LDS base + lane*16)
// ---------------------------------------------------------------------------
__device__ __forceinline__ void gload16(const __hip_bfloat16* g, __hip_bfloat16* l) {
    __builtin_amdgcn_global_load_lds(
        (__attribute__((address_space(1))) void*)(void*)const_cast<__hip_bfloat16*>(g),
        (__attribute__((address_space(3))) void*)(void*)l,
        16, 0, 0);
}

// ---------------------------------------------------------------------------
// bf16 MFMA GEMM, m97 structure: linear [128][32] LDS via global_load_lds,
// 2-barrier K-loop. A: MxK (lda), Bt: NxK (ldbt). out fp32 Cf or bf16 Cb.
// flags: 1=bias, 2=relu, 4=accumulate into Cf, 8=store bf16 to Cb
// Requires M%128==0, N%128==0, K%32==0, (gridX*gridY)%8==0.
// ---------------------------------------------------------------------------
__global__ __launch_bounds__(256) void gemm_mfma(
    const __hip_bfloat16* __restrict__ A, const __hip_bfloat16* __restrict__ Bt,
    const float* __restrict__ bias, float* __restrict__ Cf,
    __hip_bfloat16* __restrict__ Cb,
    int M, int N, int K, int lda, int ldbt, int flags)
{
    __shared__ __hip_bfloat16 As[128 * 32];
    __shared__ __hip_bfloat16 Bs[128 * 32];

    const int t = threadIdx.x;
    const int lane = t & 63;
    const int wave = t >> 6;
    const int wr = wave >> 1, wc = wave & 1;
    const int qd = lane >> 4, r = lane & 15;

    // bijective XCD-aware swizzle (nwg % 8 == 0)
    int lin = blockIdx.y * gridDim.x + blockIdx.x;
    int nwg = gridDim.x * gridDim.y;
    int cpx = nwg >> 3;
    int swz = (lin & 7) * cpx + (lin >> 3);
    int bm = (swz / gridDim.x) * 128;
    int bn = (swz % gridDim.x) * 128;

    // staging decomposition: wave w fills rows [w*32, w*32+32) of each tile
    const int srow = lane >> 2;            // 0..15
    const int scol = (lane & 3) * 8;       // elem offset within 32-col tile
    const __hip_bfloat16* gA0 = A + (size_t)(bm + wave * 32 + srow) * lda + scol;
    const __hip_bfloat16* gA1 = gA0 + (size_t)16 * lda;
    const __hip_bfloat16* gB0 = Bt + (size_t)(bn + wave * 32 + srow) * ldbt + scol;
    const __hip_bfloat16* gB1 = gB0 + (size_t)16 * ldbt;
    __hip_bfloat16* lA0 = &As[wave * 1024];
    __hip_bfloat16* lA1 = lA0 + 512;
    __hip_bfloat16* lB0 = &Bs[wave * 1024];
    __hip_bfloat16* lB1 = lB0 + 512;

    f32x4 acc[4][4] = {};

    for (int k0 = 0; k0 < K; k0 += 32) {
        __syncthreads();
        gload16(gA0 + k0, lA0);
        gload16(gA1 + k0, lA1);
        gload16(gB0 + k0, lB0);
        gload16(gB1 + k0, lB1);
        __syncthreads();

        bf16x8 afr[4], bfr[4];
#pragma unroll
        for (int m = 0; m < 4; ++m)
            afr[m] = *(const bf16x8*)&As[(wr * 64 + m * 16 + r) * 32 + qd * 8];
#pragma unroll
        for (int n = 0; n < 4; ++n)
            bfr[n] = *(const bf16x8*)&Bs[(wc * 64 + n * 16 + r) * 32 + qd * 8];
#pragma unroll
        for (int m = 0; m < 4; ++m)
#pragma unroll
            for (int n = 0; n < 4; ++n)
                acc[m][n] = __builtin_amdgcn_mfma_f32_16x16x32_bf16(
                    afr[m], bfr[n], acc[m][n], 0, 0, 0);
    }

#pragma unroll
    for (int m = 0; m < 4; ++m) {
        int row0 = bm + wr * 64 + m * 16 + qd * 4;
#pragma unroll
        for (int n = 0; n < 4; ++n) {
            int col = bn + wc * 64 + n * 16 + r;
            float bv = (flags & 1) ? bias[col] : 0.0f;
#pragma unroll
            for (int i = 0; i < 4; ++i) {
                float v = acc[m][n][i] + bv;
                if (flags & 2) v = fmaxf(v, 0.0f);
                size_t off = (size_t)(row0 + i) * N + col;
                if (flags & 4) v += Cf[off];
                if (flags & 8) Cb[off] = __float2bfloat16(v);
                else           Cf[off] = v;
            }
        }
    }
}

// ---------------------------------------------------------------------------
// fp32 tiled GEMM (small inputs): C = A@W + bias; flag 8 = store bf16 to Cb
// ---------------------------------------------------------------------------
__global__ __launch_bounds__(256) void gemm_kernel(
    const float* __restrict__ A, const float* __restrict__ W,
    const float* __restrict__ bias, float* __restrict__ C,
    __hip_bfloat16* __restrict__ Cb,
    int M, int N, int K, int lda, int ldw, int ldc, int flags)
{
    __shared__ float As[16][65];
    __shared__ float Ws[16][65];
    const int t = threadIdx.x;
    const int tx = t & 15, ty = t >> 4;
    const int bm = blockIdx.y * 64, bn = blockIdx.x * 64;
    float acc[4][4] = {};
    for (int k0 = 0; k0 < K; k0 += 16) {
#pragma unroll
        for (int i = 0; i < 4; ++i) {
            int lin = t + i * 256;
            int m = lin >> 4, kk = lin & 15;
            As[kk][m] = A[(size_t)(bm + m) * lda + (k0 + kk)];
        }
#pragma unroll
        for (int i = 0; i < 4; ++i) {
            int lin = t + i * 256;
            int n = lin & 63, kk = lin >> 6;
            Ws[kk][n] = W[(size_t)(k0 + kk) * ldw + (bn + n)];
        }
        __syncthreads();
#pragma unroll
        for (int kk = 0; kk < 16; ++kk) {
            float ra[4], rb[4];
#pragma unroll
            for (int i = 0; i < 4; ++i) ra[i] = As[kk][ty * 4 + i];
#pragma unroll
            for (int i = 0; i < 4; ++i) rb[i] = Ws[kk][tx * 4 + i];
#pragma unroll
            for (int i = 0; i < 4; ++i)
#pragma unroll
                for (int j = 0; j < 4; ++j)
                    acc[i][j] += ra[i] * rb[j];
        }
        __syncthreads();
    }
#pragma unroll
    for (int i = 0; i < 4; ++i) {
        int m = bm + ty * 4 + i;
#pragma unroll
        for (int j = 0; j < 4; ++j) {
            int n = bn + tx * 4 + j;
            float v = acc[i][j];
            if (flags & 1) v += bias[n];
            size_t off = (size_t)m * ldc + n;
            if (flags & 8) Cb[off] = __float2bfloat16(v);
            else           C[off] = v;
        }
    }
}

// ---------------------------------------------------------------------------
__global__ __launch_bounds__(256) void conv_bf16(const float* __restrict__ in,
                                                 __hip_bfloat16* __restrict__ out,
                                                 int n8)
{
    int i = blockIdx.x * 256 + threadIdx.x;
    if (i >= n8) return;
    const float4* p = (const float4*)(in + (size_t)i * 8);
    float4 v0 = p[0], v1 = p[1];
    __hip_bfloat16 o[8] = {
        __float2bfloat16(v0.x), __float2bfloat16(v0.y),
        __float2bfloat16(v0.z), __float2bfloat16(v0.w),
        __float2bfloat16(v1.x), __float2bfloat16(v1.y),
        __float2bfloat16(v1.z), __float2bfloat16(v1.w)};
    *(uint4*)(out + (size_t)i * 8) = *(const uint4*)o;
}

// ---------------------------------------------------------------------------
__global__ __launch_bounds__(256) void transp_bf16(const float* __restrict__ W,
                                                   __hip_bfloat16* __restrict__ Wt,
                                                   int K, int N)
{
    __shared__ float s[32][33];
    int n0 = blockIdx.x * 32, k0 = blockIdx.y * 32;
    int tx = threadIdx.x & 31, ty = threadIdx.x >> 5;
#pragma unroll
    for (int i = 0; i < 4; ++i)
        s[ty + i * 8][tx] = W[(size_t)(k0 + ty + i * 8) * N + n0 + tx];
    __syncthreads();
#pragma unroll
    for (int i = 0; i < 4; ++i)
        Wt[(size_t)(n0 + ty + i * 8) * K + k0 + tx] =
            __float2bfloat16(s[tx][ty + i * 8]);
}

// ---------------------------------------------------------------------------
__global__ void gather_kernel(const float* __restrict__ prev,
                              const int* __restrict__ rand_idx,
                              float* __restrict__ Psel, int* __restrict__ sel)
{
    int j = blockIdx.x;
    int b = j >> 7, i = j & 127;
    int sv = (i < 64) ? i : rand_idx[b * G_ + (i - 64)];
    if (threadIdx.x == 0) sel[j] = sv;
    const float* src = prev + ((size_t)(b * S_ + sv)) * D_;
    float* dst = Psel + (size_t)j * D_;
    for (int d = threadIdx.x; d < D_; d += blockDim.x) dst[d] = src[d];
}

// ---------------------------------------------------------------------------
// MFMA sparse attention (unchanged from round 3)
// ---------------------------------------------------------------------------
__global__ __launch_bounds__(256) void attn3_kernel(
    const u16* __restrict__ qb, const u16* __restrict__ kb,
    const u16* __restrict__ vb, const int* __restrict__ sel,
    u16* __restrict__ out)
{
    const int bh = blockIdx.y;
    const int b = bh / H_, h = bh % H_;
    const int s0 = blockIdx.x * 256;
    const int t = threadIdx.x;
    const int w = t >> 6, lane = t & 63;
    const int r = lane & 15, qd = lane >> 4;

    __shared__ u16 Vt[64][136];
    __shared__ u16 Plds[4][32][136];
    __shared__ int ssel[128];

    {
        int key0 = t >> 4;
        int d0 = (t & 15) * 4;
        for (int kk = key0; kk < 128; kk += 16) {
            ushort4 v = *(const ushort4*)(vb + (size_t)(b * 128 + kk) * D_ + h * 64 + d0);
            Vt[d0 + 0][kk] = v.x; Vt[d0 + 1][kk] = v.y;
            Vt[d0 + 2][kk] = v.z; Vt[d0 + 3][kk] = v.w;
        }
        if (t < 128) ssel[t] = sel[b * 128 + t];
    }
    __syncthreads();

    int selv[8];
#pragma unroll
    for (int n = 0; n < 8; ++n) selv[n] = ssel[n * 16 + r];

    for (int pass = 0; pass < 2; ++pass) {
        const int sbase = s0 + w * 64 + pass * 32;
        f32x4 accs[2][8] = {};

#pragma unroll
        for (int ks = 0; ks < 2; ++ks) {
            bf16x8 af[2];
#pragma unroll
            for (int m = 0; m < 2; ++m)
                af[m] = *(const bf16x8*)(qb + (size_t)(b * S_ + sbase + m * 16 + r) * D_ + h * 64 + ks * 32 + qd * 8);
#pragma unroll
            for (int n = 0; n < 8; ++n) {
                bf16x8 bfv = *(const bf16x8*)(kb + (size_t)(b * 128 + n * 16 + r) * D_ + h * 64 + ks * 32 + qd * 8);
#pragma unroll
                for (int m = 0; m < 2; ++m)
                    accs[m][n] = __builtin_amdgcn_mfma_f32_16x16x32_bf16(
                        af[m], bfv, accs[m][n], 0, 0, 0);
            }
        }

#pragma unroll
        for (int m = 0; m < 2; ++m) {
#pragma unroll
            for (int i = 0; i < 4; ++i) {
                int srow = sbase + m * 16 + qd * 4 + i;
                float pm = -3e38f;
#pragma unroll
                for (int n = 0; n < 8; ++n) {
                    float sc = accs[m][n][i] * 0.125f;
                    if (selv[n] > srow) sc = -1e9f;
                    accs[m][n][i] = sc;
                    pm = fmaxf(pm, sc);
                }
#pragma unroll
                for (int off = 1; off < 16; off <<= 1)
                    pm = fmaxf(pm, __shfl_xor(pm, off, 64));
                float ps = 0.f;
#pragma unroll
                for (int n = 0; n < 8; ++n) {
                    float e = __expf(accs[m][n][i] - pm);
                    accs[m][n][i] = e;
                    ps += e;
                }
#pragma unroll
                for (int off = 1; off < 16; off <<= 1)
                    ps += __shfl_xor(ps, off, 64);
                float inv = 1.0f / ps;
#pragma unroll
                for (int n = 0; n < 8; ++n)
                    accs[m][n][i] *= inv;
            }
        }

#pragma unroll
        for (int m = 0; m < 2; ++m)
#pragma unroll
            for (int n = 0; n < 8; ++n)
#pragma unroll
                for (int i = 0; i < 4; ++i) {
                    __hip_bfloat16 pb = __float2bfloat16(accs[m][n][i]);
                    Plds[w][m * 16 + qd * 4 + i][n * 16 + r] = *(u16*)&pb;
                }

        f32x4 acco[2][4] = {};
#pragma unroll
        for (int ks = 0; ks < 4; ++ks) {
            bf16x8 pa[2];
#pragma unroll
            for (int m = 0; m < 2; ++m)
                pa[m] = *(const bf16x8*)&Plds[w][m * 16 + r][ks * 32 + qd * 8];
#pragma unroll
            for (int nd = 0; nd < 4; ++nd) {
                bf16x8 bv = *(const bf16x8*)&Vt[nd * 16 + r][ks * 32 + qd * 8];
#pragma unroll
                for (int m = 0; m < 2; ++m)
                    acco[m][nd] = __builtin_amdgcn_mfma_f32_16x16x32_bf16(
                        pa[m], bv, acco[m][nd], 0, 0, 0);
            }
        }

#pragma unroll
        for (int m = 0; m < 2; ++m)
#pragma unroll
            for (int nd = 0; nd < 4; ++nd)
#pragma unroll
                for (int i = 0; i < 4; ++i) {
                    __hip_bfloat16 ob = __float2bfloat16(acco[m][nd][i]);
                    out[(size_t)(b * S_ + sbase + m * 16 + qd * 4 + i) * D_ + h * 64 + nd * 16 + r] = *(u16*)&ob;
                }
    }
}

// ---------------------------------------------------------------------------
// out[row] = LN(xa[row]+xb[row])*g+beta (final LN only)
// ---------------------------------------------------------------------------
__global__ __launch_bounds__(256) void addln_kernel(
    const float* __restrict__ xa, const float* __restrict__ xb,
    const float* __restrict__ g, const float* __restrict__ beta,
    float* __restrict__ out)
{
    const int row = blockIdx.x;
    const float* pa = xa + (size_t)row * D_;
    const float* pb = xb + (size_t)row * D_;
    float v[3];
    float sum = 0.f;
#pragma unroll
    for (int i = 0; i < 3; ++i) {
        int d = threadIdx.x + i * 256;
        v[i] = pa[d] + pb[d];
        sum += v[i];
    }
#pragma unroll
    for (int off = 32; off; off >>= 1) sum += __shfl_xor(sum, off, 64);
    __shared__ float r1[4], r2[4];
    int wv = threadIdx.x >> 6, ln = threadIdx.x & 63;
    if (ln == 0) r1[wv] = sum;
    __syncthreads();
    float mean = (r1[0] + r1[1] + r1[2] + r1[3]) * (1.0f / 768.0f);
    float sq = 0.f;
#pragma unroll
    for (int i = 0; i < 3; ++i) { v[i] -= mean; sq += v[i] * v[i]; }
#pragma unroll
    for (int off = 32; off; off >>= 1) sq += __shfl_xor(sq, off, 64);
    if (ln == 0) r2[wv] = sq;
    __syncthreads();
    float var = (r2[0] + r2[1] + r2[2] + r2[3]) * (1.0f / 768.0f);
    float rs = rsqrtf(var + 1e-5f);
    float* po = out + (size_t)row * D_;
#pragma unroll
    for (int i = 0; i < 3; ++i) {
        int d = threadIdx.x + i * 256;
        po[d] = v[i] * rs * g[d] + beta[d];
    }
}

// ---------------------------------------------------------------------------
// Class-attention precompute (rank-1 K/V collapse)
// ---------------------------------------------------------------------------
__global__ void precompute_U(const float* __restrict__ Wqc,
                             const float* __restrict__ Wkc,
                             const float* __restrict__ bqc,
                             float* __restrict__ U, float* __restrict__ ab)
{
    int idx = blockIdx.x * blockDim.x + threadIdx.x;
    if (idx < D_ * H_) {
        int d = idx / H_, h = idx % H_;
        float acc = 0.f;
        for (int j = 0; j < 64; ++j)
            acc += Wqc[(size_t)d * D_ + h * 64 + j] * Wkc[h * 64 + j];
        U[idx] = acc;
    }
    if (idx < H_) {
        float acc = 0.f;
        for (int j = 0; j < 64; ++j) acc += bqc[idx * 64 + j] * Wkc[idx * 64 + j];
        ab[idx] = acc;
    }
}

__global__ void precompute_mix(const float* __restrict__ Wvc,
                               const float* __restrict__ Woc,
                               const float* __restrict__ bvc,
                               const float* __restrict__ boc,
                               float* __restrict__ Wmix, float* __restrict__ bias2)
{
    int idx = blockIdx.x * blockDim.x + threadIdx.x;
    if (idx < H_ * D_) {
        int h = idx / D_, n = idx % D_;
        float acc = 0.f;
        for (int j = 0; j < 64; ++j)
            acc += Wvc[h * 64 + j] * Woc[(size_t)(h * 64 + j) * D_ + n];
        Wmix[idx] = acc;
    }
    if (idx < D_) {
        float acc = boc[idx];
        for (int d = 0; d < D_; ++d) acc += bvc[d] * Woc[(size_t)d * D_ + idx];
        bias2[idx] = acc;
    }
}

// ---------------------------------------------------------------------------
// Fused mid-section: x1 = LN(cur+oproj); alpha = 0.125*(x1@U+ab);
// mu = sum_c softmax(alpha*cv)*cv; oc = bias2 + mu@Wmix;
// x2 = LN(x1+oc) -> x2f (fp32) + x2b (bf16).
// One wave per 4 rows; block = 4 waves = 16 rows. U/Wmix read from L2,
// amortized over the 4 rows.
// ---------------------------------------------------------------------------
__global__ __launch_bounds__(256) void fused_mid(
    const float* __restrict__ cur, const float* __restrict__ oproj,
    const float* __restrict__ g1, const float* __restrict__ b1,
    const float* __restrict__ U, const float* __restrict__ ab,
    const float* __restrict__ cvec,
    const float* __restrict__ Wmix, const float* __restrict__ bias2,
    const float* __restrict__ g2, const float* __restrict__ b2,
    float* __restrict__ x2f, __hip_bfloat16* __restrict__ x2b)
{
    const int w = threadIdx.x >> 6, lane = threadIdx.x & 63;
    const int row0 = blockIdx.x * 16 + w * 4;
    const int b = row0 >> 12;  // row / S_
    const float4 cv = ((const float4*)(cvec + b * C_))[lane];

    float x1[4][12];

    // --- x1 = LN(cur + oproj), per row
#pragma unroll
    for (int rr = 0; rr < 4; ++rr) {
        const float* pa = cur + (size_t)(row0 + rr) * D_;
        const float* pb = oproj + (size_t)(row0 + rr) * D_;
        float s = 0.f;
#pragma unroll
        for (int i = 0; i < 12; ++i) {
            float v = pa[lane + i * 64] + pb[lane + i * 64];
            x1[rr][i] = v; s += v;
        }
#pragma unroll
        for (int off = 1; off < 64; off <<= 1) s += __shfl_xor(s, off, 64);
        float mean = s * (1.0f / 768.0f);
        float sq = 0.f;
#pragma unroll
        for (int i = 0; i < 12; ++i) { x1[rr][i] -= mean; sq += x1[rr][i] * x1[rr][i]; }
#pragma unroll
        for (int off = 1; off < 64; off <<= 1) sq += __shfl_xor(sq, off, 64);
        float rs = rsqrtf(sq * (1.0f / 768.0f) + 1e-5f);
#pragma unroll
        for (int i = 0; i < 12; ++i) {
            int d = lane + i * 64;
            x1[rr][i] = x1[rr][i] * rs * g1[d] + b1[d];
        }
    }

    // --- alpha partials: acc[rr][h] += x1[rr][i] * U[d][h]
    float acc[4][12] = {};
#pragma unroll
    for (int i = 0; i < 12; ++i) {
        int d = lane + i * 64;
        const float* up = U + (size_t)d * 12;
#pragma unroll
        for (int h = 0; h < 12; ++h) {
            float uv = up[h];
#pragma unroll
            for (int rr = 0; rr < 4; ++rr) acc[rr][h] += x1[rr][i] * uv;
        }
    }

    // --- reduce alpha, then mu = sum_c softmax(alpha*cv)*cv
    float mu[4][12];
#pragma unroll
    for (int h = 0; h < 12; ++h) {
        float av = ab[h];
#pragma unroll
        for (int rr = 0; rr < 4; ++rr) {
            float a = acc[rr][h];
#pragma unroll
            for (int off = 1; off < 64; off <<= 1) a += __shfl_xor(a, off, 64);
            a = 0.125f * (a + av);
            float s0 = a * cv.x, s1 = a * cv.y, s2 = a * cv.z, s3 = a * cv.w;
            float m = fmaxf(fmaxf(s0, s1), fmaxf(s2, s3));
#pragma unroll
            for (int off = 1; off < 64; off <<= 1) m = fmaxf(m, __shfl_xor(m, off, 64));
            float e0 = __expf(s0 - m), e1 = __expf(s1 - m),
                  e2 = __expf(s2 - m), e3 = __expf(s3 - m);
            float z = e0 + e1 + e2 + e3;
            float ms = e0 * cv.x + e1 * cv.y + e2 * cv.z + e3 * cv.w;
#pragma unroll
            for (int off = 1; off < 64; off <<= 1) {
                z += __shfl_xor(z, off, 64);
                ms += __shfl_xor(ms, off, 64);
            }
            mu[rr][h] = ms / z;
        }
    }

    // --- t2 = x1 + oc; oc = bias2 + mu@Wmix
    float t2[4][12];
#pragma unroll
    for (int i = 0; i < 12; ++i) {
        int d = lane + i * 64;
        float bv = bias2[d];
        float o0 = bv, o1 = bv, o2 = bv, o3 = bv;
#pragma unroll
        for (int h = 0; h < 12; ++h) {
            float wv = Wmix[h * D_ + d];
            o0 += mu[0][h] * wv; o1 += mu[1][h] * wv;
            o2 += mu[2][h] * wv; o3 += mu[3][h] * wv;
        }
        t2[0][i] = x1[0][i] + o0; t2[1][i] = x1[1][i] + o1;
        t2[2][i] = x1[2][i] + o2; t2[3][i] = x1[3][i] + o3;
    }

    // --- x2 = LN(t2), store fp32 + bf16
#pragma unroll
    for (int rr = 0; rr < 4; ++rr) {
        float s = 0.f;
#pragma unroll
        for (int i = 0; i < 12; ++i) s += t2[rr][i];
#pragma unroll
        for (int off = 1; off < 64; off <<= 1) s += __shfl_xor(s, off, 64);
        float mean = s * (1.0f / 768.0f);
        float sq = 0.f;
#pragma unroll
        for (int i = 0; i < 12; ++i) { t2[rr][i] -= mean; sq += t2[rr][i] * t2[rr][i]; }
#pragma unroll
        for (int off = 1; off < 64; off <<= 1) sq += __shfl_xor(sq, off, 64);
        float rs = rsqrtf(sq * (1.0f / 768.0f) + 1e-5f);
        size_t base = (size_t)(row0 + rr) * D_;
#pragma unroll
        for (int i = 0; i < 12; ++i) {
            int d = lane + i * 64;
            float val = t2[rr][i] * rs * g2[d] + b2[d];
            x2f[base + d] = val;
            x2b[base + d] = __float2bfloat16(val);
        }
    }
}

// ---------------------------------------------------------------------------
extern "C" void kernel_launch(void* const* d_in, const int* in_sizes, int n_in,
                              void* d_out, int out_size, void* d_ws, size_t ws_size,
                              hipStream_t stream) {
    const float* cur   = (const float*)d_in[0];
    const float* prev  = (const float*)d_in[1];
    const float* cvec  = (const float*)d_in[2];
    const int*   ridx  = (const int*)d_in[3];
    const float* Wq  = (const float*)d_in[4];
    const float* bq  = (const float*)d_in[5];
    const float* Wk  = (const float*)d_in[6];
    const float* bk  = (const float*)d_in[7];
    const float* Wv  = (const float*)d_in[8];
    const float* bv  = (const float*)d_in[9];
    const float* Wo  = (const float*)d_in[10];
    const float* bo  = (const float*)d_in[11];
    const float* g1  = (const float*)d_in[12];
    const float* b1  = (const float*)d_in[13];
    const float* Wqc = (const float*)d_in[14];
    const float* bqc = (const float*)d_in[15];
    const float* Wkc = (const float*)d_in[16];
    const float* bkc = (const float*)d_in[17];  (void)bkc;
    const float* Wvc = (const float*)d_in[18];
    const float* bvc = (const float*)d_in[19];
    const float* Woc = (const float*)d_in[20];
    const float* boc = (const float*)d_in[21];
    const float* g2  = (const float*)d_in[22];
    const float* b2  = (const float*)d_in[23];
    const float* W1  = (const float*)d_in[24];
    const float* bf1 = (const float*)d_in[25];
    const float* W2  = (const float*)d_in[26];
    const float* bf2 = (const float*)d_in[27];
    const float* g3  = (const float*)d_in[28];
    const float* b3  = (const float*)d_in[29];
    float* outp = (float*)d_out;
    (void)ws_size; (void)in_sizes; (void)n_in; (void)out_size;

    const size_t NBSD = (size_t)B_ * S_ * D_;
    const size_t NSEL = (size_t)B_ * 128 * D_;

    float* bufA   = (float*)d_ws;
    float* bufB   = bufA + NBSD;
    float* Psel   = bufB + NBSD;
    float* kself  = Psel + NSEL;
    float* vself  = kself + NSEL;
    float* Ub     = vself + NSEL;
    float* abv    = Ub + (size_t)D_ * H_;
    float* Wmix   = abv + 16;
    float* bias2  = Wmix + (size_t)H_ * D_;
    float* alphab = bias2 + D_;
    float* mub    = alphab + (size_t)B_ * S_ * H_;
    int*   selb   = (int*)(mub + (size_t)B_ * S_ * H_);
    __hip_bfloat16* bf0   = (__hip_bfloat16*)(selb + 512);
    __hip_bfloat16* hmidb = bf0 + NBSD;
    __hip_bfloat16* Wqt   = hmidb + NBSD;
    __hip_bfloat16* Wot   = Wqt + (size_t)D_ * D_;
    __hip_bfloat16* W1t   = Wot + (size_t)D_ * D_;
    __hip_bfloat16* W2t   = W1t + (size_t)D_ * FF_;
    __hip_bfloat16* kselb = (__hip_bfloat16*)kself;
    __hip_bfloat16* vselb = (__hip_bfloat16*)vself;
    (void)bufA; (void)alphab; (void)mub;

    const int M = B_ * S_;

    // 1) gather + selected-row K/V projections (bf16 out)
    gather_kernel<<<B_ * 128, 256, 0, stream>>>(prev, ridx, Psel, selb);
    {
        dim3 g(D_ / 64, (B_ * 128) / 64);
        gemm_kernel<<<g, 256, 0, stream>>>(Psel, Wk, bk, nullptr, kselb, B_ * 128, D_, D_, D_, D_, D_, 1 | 8);
        gemm_kernel<<<g, 256, 0, stream>>>(Psel, Wv, bv, nullptr, vselb, B_ * 128, D_, D_, D_, D_, D_, 1 | 8);
    }

    // 2) weight transposes + activation convert + class-attn precompute
    transp_bf16<<<dim3(D_ / 32, D_ / 32), 256, 0, stream>>>(Wq, Wqt, D_, D_);
    transp_bf16<<<dim3(D_ / 32, D_ / 32), 256, 0, stream>>>(Wo, Wot, D_, D_);
    transp_bf16<<<dim3(FF_ / 32, D_ / 32), 256, 0, stream>>>(W1, W1t, D_, FF_);
    transp_bf16<<<dim3(D_ / 32, FF_ / 32), 256, 0, stream>>>(W2, W2t, FF_, D_);
    conv_bf16<<<(int)(NBSD / 8 + 255) / 256, 256, 0, stream>>>(cur, bf0, (int)(NBSD / 8));
    precompute_U<<<(D_ * H_ + 255) / 256, 256, 0, stream>>>(Wqc, Wkc, bqc, Ub, abv);
    precompute_mix<<<(H_ * D_ + 255) / 256, 256, 0, stream>>>(Wvc, Woc, bvc, boc, Wmix, bias2);

    // 3) q = cur @ Wq + bq -> hmidb (bf16)
    gemm_mfma<<<dim3(D_ / 128, M / 128), 256, 0, stream>>>(
        bf0, Wqt, bq, nullptr, hmidb, M, D_, D_, D_, D_, 1 | 8);

    // 4) MFMA sparse attention -> bf0 (bf16)
    attn3_kernel<<<dim3(S_ / 256, B_ * H_), 256, 0, stream>>>(
        (const u16*)hmidb, (const u16*)kselb, (const u16*)vselb, selb, (u16*)bf0);

    // 5) o @ Wo + bo -> bufB (fp32)
    gemm_mfma<<<dim3(D_ / 128, M / 128), 256, 0, stream>>>(
        bf0, Wot, bo, bufB, nullptr, M, D_, D_, D_, D_, 1);

    // 6) fused: x1=LN(cur+o); class-attn; x2=LN(x1+oc) -> outp + bf0
    fused_mid<<<M / 16, 256, 0, stream>>>(
        cur, bufB, g1, b1, Ub, abv, cvec, Wmix, bias2, g2, b2, outp, bf0);

    // 7) FF in 4 column chunks of 768
    for (int c = 0; c < 4; ++c) {
        gemm_mfma<<<dim3(D_ / 128, M / 128), 256, 0, stream>>>(
            bf0, W1t + (size_t)c * D_ * D_, bf1 + (size_t)c * D_,
            nullptr, hmidb, M, D_, D_, D_, D_, 1 | 2 | 8);
        gemm_mfma<<<dim3(D_ / 128, M / 128), 256, 0, stream>>>(
            hmidb, W2t + (size_t)c * D_, bf2,
            bufB, nullptr, M, D_, D_, D_, FF_, (c == 0) ? 1 : 4);
    }

    // 8) out = LN(x2 + ff)
    addln_kernel<<<M, 256, 0, stream>>>(outp, bufB, g3, b3, outp);
}

// Round 5
// 603.943 us; speedup vs baseline: 9.6869x; 1.4653x over previous
//
#include <hip/hip_runtime.h>
#include <hip/hip_bf16.h>

#define B_ 4
#define S_ 4096
#define D_ 768
#define H_ 12
#define DH_ 64
#define G_ 64
#define C_ 256
#define FF_ 3072

typedef __attribute__((ext_vector_type(8))) short bf16x8;
typedef __attribute__((ext_vector_type(4))) float f32x4;
typedef unsigned short u16;

// ---------------------------------------------------------------------------
// async global->LDS 16B (wave-uniform LDS base + lane*16)
// ---------------------------------------------------------------------------
__device__ __forceinline__ void gload16(const __hip_bfloat16* g, __hip_bfloat16* l) {
    __builtin_amdgcn_global_load_lds(
        (__attribute__((address_space(1))) void*)(void*)const_cast<__hip_bfloat16*>(g),
        (__attribute__((address_space(3))) void*)(void*)l,
        16, 0, 0);
}

// ---------------------------------------------------------------------------
// bf16 MFMA GEMM, double-buffered (2-phase): STAGE(t+1) issued before
// compute(t); one barrier per K-step drains after MFMA.
// A: MxK (lda), Bt: NxK (ldbt). out fp32 Cf or bf16 Cb (ldc = N).
// flags: 1=bias, 2=relu, 4=accumulate into Cf, 8=store bf16 to Cb
// M%128==0, N%128==0, K%32==0, (gridX*gridY)%8==0.
// ---------------------------------------------------------------------------
__global__ __launch_bounds__(256) void gemm_mfma(
    const __hip_bfloat16* __restrict__ A, const __hip_bfloat16* __restrict__ Bt,
    const float* __restrict__ bias, float* __restrict__ Cf,
    __hip_bfloat16* __restrict__ Cb,
    int M, int N, int K, int lda, int ldbt, int flags)
{
    __shared__ __hip_bfloat16 As[2][128 * 32];
    __shared__ __hip_bfloat16 Bs[2][128 * 32];

    const int t = threadIdx.x;
    const int lane = t & 63;
    const int wave = t >> 6;
    const int wr = wave >> 1, wc = wave & 1;
    const int qd = lane >> 4, r = lane & 15;

    // bijective XCD-aware swizzle (nwg % 8 == 0)
    int lin = blockIdx.y * gridDim.x + blockIdx.x;
    int nwg = gridDim.x * gridDim.y;
    int cpx = nwg >> 3;
    int swz = (lin & 7) * cpx + (lin >> 3);
    int bm = (swz / gridDim.x) * 128;
    int bn = (swz % gridDim.x) * 128;

    const int srow = lane >> 2;
    const int scol = (lane & 3) * 8;
    const __hip_bfloat16* gA0 = A + (size_t)(bm + wave * 32 + srow) * lda + scol;
    const __hip_bfloat16* gA1 = gA0 + (size_t)16 * lda;
    const __hip_bfloat16* gB0 = Bt + (size_t)(bn + wave * 32 + srow) * ldbt + scol;
    const __hip_bfloat16* gB1 = gB0 + (size_t)16 * ldbt;

    f32x4 acc[4][4] = {};

    // prologue
    gload16(gA0, &As[0][wave * 1024]);
    gload16(gA1, &As[0][wave * 1024 + 512]);
    gload16(gB0, &Bs[0][wave * 1024]);
    gload16(gB1, &Bs[0][wave * 1024 + 512]);
    __syncthreads();

    int cur = 0;
    for (int k0 = 0; k0 < K; k0 += 32, cur ^= 1) {
        if (k0 + 32 < K) {
            int kn = k0 + 32, nb = cur ^ 1;
            gload16(gA0 + kn, &As[nb][wave * 1024]);
            gload16(gA1 + kn, &As[nb][wave * 1024 + 512]);
            gload16(gB0 + kn, &Bs[nb][wave * 1024]);
            gload16(gB1 + kn, &Bs[nb][wave * 1024 + 512]);
        }
        bf16x8 afr[4], bfr[4];
#pragma unroll
        for (int m = 0; m < 4; ++m)
            afr[m] = *(const bf16x8*)&As[cur][(wr * 64 + m * 16 + r) * 32 + qd * 8];
#pragma unroll
        for (int n = 0; n < 4; ++n)
            bfr[n] = *(const bf16x8*)&Bs[cur][(wc * 64 + n * 16 + r) * 32 + qd * 8];
#pragma unroll
        for (int m = 0; m < 4; ++m)
#pragma unroll
            for (int n = 0; n < 4; ++n)
                acc[m][n] = __builtin_amdgcn_mfma_f32_16x16x32_bf16(
                    afr[m], bfr[n], acc[m][n], 0, 0, 0);
        __syncthreads();
    }

#pragma unroll
    for (int m = 0; m < 4; ++m) {
        int row0 = bm + wr * 64 + m * 16 + qd * 4;
#pragma unroll
        for (int n = 0; n < 4; ++n) {
            int col = bn + wc * 64 + n * 16 + r;
            float bv = (flags & 1) ? bias[col] : 0.0f;
#pragma unroll
            for (int i = 0; i < 4; ++i) {
                float v = acc[m][n][i] + bv;
                if (flags & 2) v = fmaxf(v, 0.0f);
                size_t off = (size_t)(row0 + i) * N + col;
                if (flags & 4) v += Cf[off];
                if (flags & 8) Cb[off] = __float2bfloat16(v);
                else           Cf[off] = v;
            }
        }
    }
}

// ---------------------------------------------------------------------------
__global__ __launch_bounds__(256) void conv_bf16(const float* __restrict__ in,
                                                 __hip_bfloat16* __restrict__ out,
                                                 int n8)
{
    int i = blockIdx.x * 256 + threadIdx.x;
    if (i >= n8) return;
    const float4* p = (const float4*)(in + (size_t)i * 8);
    float4 v0 = p[0], v1 = p[1];
    __hip_bfloat16 o[8] = {
        __float2bfloat16(v0.x), __float2bfloat16(v0.y),
        __float2bfloat16(v0.z), __float2bfloat16(v0.w),
        __float2bfloat16(v1.x), __float2bfloat16(v1.y),
        __float2bfloat16(v1.z), __float2bfloat16(v1.w)};
    *(uint4*)(out + (size_t)i * 8) = *(const uint4*)o;
}

// ---------------------------------------------------------------------------
__global__ __launch_bounds__(256) void transp_bf16(const float* __restrict__ W,
                                                   __hip_bfloat16* __restrict__ Wt,
                                                   int K, int N)
{
    __shared__ float s[32][33];
    int n0 = blockIdx.x * 32, k0 = blockIdx.y * 32;
    int tx = threadIdx.x & 31, ty = threadIdx.x >> 5;
#pragma unroll
    for (int i = 0; i < 4; ++i)
        s[ty + i * 8][tx] = W[(size_t)(k0 + ty + i * 8) * N + n0 + tx];
    __syncthreads();
#pragma unroll
    for (int i = 0; i < 4; ++i)
        Wt[(size_t)(n0 + ty + i * 8) * K + k0 + tx] =
            __float2bfloat16(s[tx][ty + i * 8]);
}

// ---------------------------------------------------------------------------
// Gather selected rows of prev -> bf16 Pselb, plus sel indices
// ---------------------------------------------------------------------------
__global__ void gather_kernel(const float* __restrict__ prev,
                              const int* __restrict__ rand_idx,
                              __hip_bfloat16* __restrict__ Pselb,
                              int* __restrict__ sel)
{
    int j = blockIdx.x;
    int b = j >> 7, i = j & 127;
    int sv = (i < 64) ? i : rand_idx[b * G_ + (i - 64)];
    if (threadIdx.x == 0) sel[j] = sv;
    const float* src = prev + ((size_t)(b * S_ + sv)) * D_;
    __hip_bfloat16* dst = Pselb + (size_t)j * D_;
    for (int d = threadIdx.x; d < D_; d += blockDim.x)
        dst[d] = __float2bfloat16(src[d]);
}

// ---------------------------------------------------------------------------
// MFMA sparse attention (round-3 structure)
// ---------------------------------------------------------------------------
__global__ __launch_bounds__(256) void attn3_kernel(
    const u16* __restrict__ qb, const u16* __restrict__ kb,
    const u16* __restrict__ vb, const int* __restrict__ sel,
    u16* __restrict__ out)
{
    const int bh = blockIdx.y;
    const int b = bh / H_, h = bh % H_;
    const int s0 = blockIdx.x * 256;
    const int t = threadIdx.x;
    const int w = t >> 6, lane = t & 63;
    const int r = lane & 15, qd = lane >> 4;

    __shared__ u16 Vt[64][136];
    __shared__ u16 Plds[4][32][136];
    __shared__ int ssel[128];

    {
        int key0 = t >> 4;
        int d0 = (t & 15) * 4;
        for (int kk = key0; kk < 128; kk += 16) {
            ushort4 v = *(const ushort4*)(vb + (size_t)(b * 128 + kk) * D_ + h * 64 + d0);
            Vt[d0 + 0][kk] = v.x; Vt[d0 + 1][kk] = v.y;
            Vt[d0 + 2][kk] = v.z; Vt[d0 + 3][kk] = v.w;
        }
        if (t < 128) ssel[t] = sel[b * 128 + t];
    }
    __syncthreads();

    int selv[8];
#pragma unroll
    for (int n = 0; n < 8; ++n) selv[n] = ssel[n * 16 + r];

    for (int pass = 0; pass < 2; ++pass) {
        const int sbase = s0 + w * 64 + pass * 32;
        f32x4 accs[2][8] = {};

#pragma unroll
        for (int ks = 0; ks < 2; ++ks) {
            bf16x8 af[2];
#pragma unroll
            for (int m = 0; m < 2; ++m)
                af[m] = *(const bf16x8*)(qb + (size_t)(b * S_ + sbase + m * 16 + r) * D_ + h * 64 + ks * 32 + qd * 8);
#pragma unroll
            for (int n = 0; n < 8; ++n) {
                bf16x8 bfv = *(const bf16x8*)(kb + (size_t)(b * 128 + n * 16 + r) * D_ + h * 64 + ks * 32 + qd * 8);
#pragma unroll
                for (int m = 0; m < 2; ++m)
                    accs[m][n] = __builtin_amdgcn_mfma_f32_16x16x32_bf16(
                        af[m], bfv, accs[m][n], 0, 0, 0);
            }
        }

#pragma unroll
        for (int m = 0; m < 2; ++m) {
#pragma unroll
            for (int i = 0; i < 4; ++i) {
                int srow = sbase + m * 16 + qd * 4 + i;
                float pm = -3e38f;
#pragma unroll
                for (int n = 0; n < 8; ++n) {
                    float sc = accs[m][n][i] * 0.125f;
                    if (selv[n] > srow) sc = -1e9f;
                    accs[m][n][i] = sc;
                    pm = fmaxf(pm, sc);
                }
#pragma unroll
                for (int off = 1; off < 16; off <<= 1)
                    pm = fmaxf(pm, __shfl_xor(pm, off, 64));
                float ps = 0.f;
#pragma unroll
                for (int n = 0; n < 8; ++n) {
                    float e = __expf(accs[m][n][i] - pm);
                    accs[m][n][i] = e;
                    ps += e;
                }
#pragma unroll
                for (int off = 1; off < 16; off <<= 1)
                    ps += __shfl_xor(ps, off, 64);
                float inv = 1.0f / ps;
#pragma unroll
                for (int n = 0; n < 8; ++n)
                    accs[m][n][i] *= inv;
            }
        }

#pragma unroll
        for (int m = 0; m < 2; ++m)
#pragma unroll
            for (int n = 0; n < 8; ++n)
#pragma unroll
                for (int i = 0; i < 4; ++i) {
                    __hip_bfloat16 pb = __float2bfloat16(accs[m][n][i]);
                    Plds[w][m * 16 + qd * 4 + i][n * 16 + r] = *(u16*)&pb;
                }

        f32x4 acco[2][4] = {};
#pragma unroll
        for (int ks = 0; ks < 4; ++ks) {
            bf16x8 pa[2];
#pragma unroll
            for (int m = 0; m < 2; ++m)
                pa[m] = *(const bf16x8*)&Plds[w][m * 16 + r][ks * 32 + qd * 8];
#pragma unroll
            for (int nd = 0; nd < 4; ++nd) {
                bf16x8 bv = *(const bf16x8*)&Vt[nd * 16 + r][ks * 32 + qd * 8];
#pragma unroll
                for (int m = 0; m < 2; ++m)
                    acco[m][nd] = __builtin_amdgcn_mfma_f32_16x16x32_bf16(
                        pa[m], bv, acco[m][nd], 0, 0, 0);
            }
        }

#pragma unroll
        for (int m = 0; m < 2; ++m)
#pragma unroll
            for (int nd = 0; nd < 4; ++nd)
#pragma unroll
                for (int i = 0; i < 4; ++i) {
                    __hip_bfloat16 ob = __float2bfloat16(acco[m][nd][i]);
                    out[(size_t)(b * S_ + sbase + m * 16 + qd * 4 + i) * D_ + h * 64 + nd * 16 + r] = *(u16*)&ob;
                }
    }
}

// ---------------------------------------------------------------------------
// final LN: out[row] = LN(xa+xb)*g+beta
// ---------------------------------------------------------------------------
__global__ __launch_bounds__(256) void addln_kernel(
    const float* __restrict__ xa, const float* __restrict__ xb,
    const float* __restrict__ g, const float* __restrict__ beta,
    float* __restrict__ out)
{
    const int row = blockIdx.x;
    const float* pa = xa + (size_t)row * D_;
    const float* pb = xb + (size_t)row * D_;
    float v[3];
    float sum = 0.f;
#pragma unroll
    for (int i = 0; i < 3; ++i) {
        int d = threadIdx.x + i * 256;
        v[i] = pa[d] + pb[d];
        sum += v[i];
    }
#pragma unroll
    for (int off = 32; off; off >>= 1) sum += __shfl_xor(sum, off, 64);
    __shared__ float r1[4], r2[4];
    int wv = threadIdx.x >> 6, ln = threadIdx.x & 63;
    if (ln == 0) r1[wv] = sum;
    __syncthreads();
    float mean = (r1[0] + r1[1] + r1[2] + r1[3]) * (1.0f / 768.0f);
    float sq = 0.f;
#pragma unroll
    for (int i = 0; i < 3; ++i) { v[i] -= mean; sq += v[i] * v[i]; }
#pragma unroll
    for (int off = 32; off; off >>= 1) sq += __shfl_xor(sq, off, 64);
    if (ln == 0) r2[wv] = sq;
    __syncthreads();
    float var = (r2[0] + r2[1] + r2[2] + r2[3]) * (1.0f / 768.0f);
    float rs = rsqrtf(var + 1e-5f);
    float* po = out + (size_t)row * D_;
#pragma unroll
    for (int i = 0; i < 3; ++i) {
        int d = threadIdx.x + i * 256;
        po[d] = v[i] * rs * g[d] + beta[d];
    }
}

// ---------------------------------------------------------------------------
// Class-attention precompute. Ut stored TRANSPOSED: Ut[h*768+d].
// ---------------------------------------------------------------------------
__global__ void precompute_U(const float* __restrict__ Wqc,
                             const float* __restrict__ Wkc,
                             const float* __restrict__ bqc,
                             float* __restrict__ Ut, float* __restrict__ ab)
{
    int idx = blockIdx.x * blockDim.x + threadIdx.x;  // h*768 + d
    if (idx < D_ * H_) {
        int h = idx / D_, d = idx % D_;
        float acc = 0.f;
        for (int j = 0; j < 64; ++j)
            acc += Wqc[(size_t)d * D_ + h * 64 + j] * Wkc[h * 64 + j];
        Ut[idx] = acc;
    }
    if (idx < H_) {
        float acc = 0.f;
        for (int j = 0; j < 64; ++j) acc += bqc[idx * 64 + j] * Wkc[idx * 64 + j];
        ab[idx] = acc;
    }
}

__global__ void precompute_mix(const float* __restrict__ Wvc,
                               const float* __restrict__ Woc,
                               const float* __restrict__ bvc,
                               const float* __restrict__ boc,
                               float* __restrict__ Wmix, float* __restrict__ bias2)
{
    int idx = blockIdx.x * blockDim.x + threadIdx.x;
    if (idx < H_ * D_) {
        int h = idx / D_, n = idx % D_;
        float acc = 0.f;
        for (int j = 0; j < 64; ++j)
            acc += Wvc[h * 64 + j] * Woc[(size_t)(h * 64 + j) * D_ + n];
        Wmix[idx] = acc;
    }
    if (idx < D_) {
        float acc = boc[idx];
        for (int d = 0; d < D_; ++d) acc += bvc[d] * Woc[(size_t)d * D_ + idx];
        bias2[idx] = acc;
    }
}

// ---------------------------------------------------------------------------
// Fused mid v2: x1=LN(cur+oproj); alpha=0.125*(x1@U+ab);
// mu=sum_c softmax(alpha*cv)*cv; x2=LN(x1+bias2+mu@Wmix) -> x2f + x2b.
// 2 rows/wave, 4 waves/block (8 rows). Alpha reduced via one LDS transpose;
// softmax per-lane-serial (48 lanes, 128 classes each). All d-indexed reads
// float4-coalesced (Ut is [h][d], Wmix is [h][d]).
// ---------------------------------------------------------------------------
__global__ __launch_bounds__(256) void fused_mid(
    const float* __restrict__ cur, const float* __restrict__ oproj,
    const float* __restrict__ g1, const float* __restrict__ b1,
    const float* __restrict__ Ut, const float* __restrict__ ab,
    const float* __restrict__ cvec,
    const float* __restrict__ Wmix, const float* __restrict__ bias2,
    const float* __restrict__ g2, const float* __restrict__ b2,
    float* __restrict__ x2f, __hip_bfloat16* __restrict__ x2b)
{
    const int w = threadIdx.x >> 6, lane = threadIdx.x & 63;
    const int row0 = blockIdx.x * 8 + w * 2;
    const int b = blockIdx.x >> 9;          // 512 blocks per batch

    __shared__ float4 cvs[64];              // 256 classes
    __shared__ float xp[4][64][28];         // [wave][lane][24 pad 28]
    __shared__ float muls[4][24];

    if (threadIdx.x < 64)
        cvs[threadIdx.x] = ((const float4*)(cvec + b * C_))[threadIdx.x];

    // ---- x1 = LN(cur + oproj), lane owns d = i*256 + lane*4 + {0..3}
    float4 x1[2][3];
#pragma unroll
    for (int rr = 0; rr < 2; ++rr) {
        const float4* pa = (const float4*)(cur + (size_t)(row0 + rr) * D_);
        const float4* pb = (const float4*)(oproj + (size_t)(row0 + rr) * D_);
        float s = 0.f;
#pragma unroll
        for (int i = 0; i < 3; ++i) {
            float4 a = pa[i * 64 + lane], o = pb[i * 64 + lane];
            float4 v; v.x = a.x + o.x; v.y = a.y + o.y; v.z = a.z + o.z; v.w = a.w + o.w;
            x1[rr][i] = v;
            s += v.x + v.y + v.z + v.w;
        }
#pragma unroll
        for (int off = 1; off < 64; off <<= 1) s += __shfl_xor(s, off, 64);
        float mean = s * (1.0f / 768.0f);
        float sq = 0.f;
#pragma unroll
        for (int i = 0; i < 3; ++i) {
            x1[rr][i].x -= mean; x1[rr][i].y -= mean;
            x1[rr][i].z -= mean; x1[rr][i].w -= mean;
            sq += x1[rr][i].x * x1[rr][i].x + x1[rr][i].y * x1[rr][i].y
                + x1[rr][i].z * x1[rr][i].z + x1[rr][i].w * x1[rr][i].w;
        }
#pragma unroll
        for (int off = 1; off < 64; off <<= 1) sq += __shfl_xor(sq, off, 64);
        float rs = rsqrtf(sq * (1.0f / 768.0f) + 1e-5f);
#pragma unroll
        for (int i = 0; i < 3; ++i) {
            float4 gg = ((const float4*)g1)[i * 64 + lane];
            float4 bb = ((const float4*)b1)[i * 64 + lane];
            x1[rr][i].x = x1[rr][i].x * rs * gg.x + bb.x;
            x1[rr][i].y = x1[rr][i].y * rs * gg.y + bb.y;
            x1[rr][i].z = x1[rr][i].z * rs * gg.z + bb.z;
            x1[rr][i].w = x1[rr][i].w * rs * gg.w + bb.w;
        }
    }

    // ---- alpha partials (lane-local), j = rr*12+h
    float acc[24];
#pragma unroll
    for (int j = 0; j < 24; ++j) acc[j] = 0.f;
#pragma unroll
    for (int i = 0; i < 3; ++i) {
#pragma unroll
        for (int h = 0; h < 12; ++h) {
            float4 u = ((const float4*)(Ut + (size_t)h * D_))[i * 64 + lane];
#pragma unroll
            for (int rr = 0; rr < 2; ++rr)
                acc[rr * 12 + h] += x1[rr][i].x * u.x + x1[rr][i].y * u.y
                                  + x1[rr][i].z * u.z + x1[rr][i].w * u.w;
        }
    }
#pragma unroll
    for (int j4 = 0; j4 < 6; ++j4)
        *(float4*)&xp[w][lane][j4 * 4] = *(float4*)&acc[j4 * 4];
    __syncthreads();

    // ---- alpha reduce + per-lane-serial class softmax
    if (lane < 48) {
        int j = lane >> 1, half = lane & 1;
        float ssum = 0.f;
#pragma unroll
        for (int k = 0; k < 32; ++k) ssum += xp[w][half * 32 + k][j];
        ssum += __shfl_xor(ssum, 1, 64);
        float a = 0.125f * (ssum + ab[j % 12]);
        float z = 0.f, ms = 0.f;
#pragma unroll
        for (int it = 0; it < 32; ++it) {
            float4 c = cvs[half * 32 + it];
            float e0 = __expf(a * c.x), e1 = __expf(a * c.y),
                  e2 = __expf(a * c.z), e3 = __expf(a * c.w);
            z += e0 + e1 + e2 + e3;
            ms += e0 * c.x + e1 * c.y + e2 * c.z + e3 * c.w;
        }
        z += __shfl_xor(z, 1, 64);
        ms += __shfl_xor(ms, 1, 64);
        if (half == 0) muls[w][j] = ms / z;
    }
    __syncthreads();

    // ---- t2 = x1 + bias2 + mu@Wmix; x2 = LN(t2)
    float4 t2[2][3];
#pragma unroll
    for (int i = 0; i < 3; ++i) {
        float4 bv = ((const float4*)bias2)[i * 64 + lane];
        float4 o0 = bv, o1 = bv;
#pragma unroll
        for (int h = 0; h < 12; ++h) {
            float4 wm = ((const float4*)(Wmix + (size_t)h * D_))[i * 64 + lane];
            float m0 = muls[w][h], m1 = muls[w][12 + h];
            o0.x += m0 * wm.x; o0.y += m0 * wm.y; o0.z += m0 * wm.z; o0.w += m0 * wm.w;
            o1.x += m1 * wm.x; o1.y += m1 * wm.y; o1.z += m1 * wm.z; o1.w += m1 * wm.w;
        }
        t2[0][i].x = x1[0][i].x + o0.x; t2[0][i].y = x1[0][i].y + o0.y;
        t2[0][i].z = x1[0][i].z + o0.z; t2[0][i].w = x1[0][i].w + o0.w;
        t2[1][i].x = x1[1][i].x + o1.x; t2[1][i].y = x1[1][i].y + o1.y;
        t2[1][i].z = x1[1][i].z + o1.z; t2[1][i].w = x1[1][i].w + o1.w;
    }

#pragma unroll
    for (int rr = 0; rr < 2; ++rr) {
        float s = 0.f;
#pragma unroll
        for (int i = 0; i < 3; ++i)
            s += t2[rr][i].x + t2[rr][i].y + t2[rr][i].z + t2[rr][i].w;
#pragma unroll
        for (int off = 1; off < 64; off <<= 1) s += __shfl_xor(s, off, 64);
        float mean = s * (1.0f / 768.0f);
        float sq = 0.f;
#pragma unroll
        for (int i = 0; i < 3; ++i) {
            t2[rr][i].x -= mean; t2[rr][i].y -= mean;
            t2[rr][i].z -= mean; t2[rr][i].w -= mean;
            sq += t2[rr][i].x * t2[rr][i].x + t2[rr][i].y * t2[rr][i].y
                + t2[rr][i].z * t2[rr][i].z + t2[rr][i].w * t2[rr][i].w;
        }
#pragma unroll
        for (int off = 1; off < 64; off <<= 1) sq += __shfl_xor(sq, off, 64);
        float rs = rsqrtf(sq * (1.0f / 768.0f) + 1e-5f);
        size_t base = (size_t)(row0 + rr) * D_;
#pragma unroll
        for (int i = 0; i < 3; ++i) {
            float4 gg = ((const float4*)g2)[i * 64 + lane];
            float4 bb = ((const float4*)b2)[i * 64 + lane];
            float4 v;
            v.x = t2[rr][i].x * rs * gg.x + bb.x;
            v.y = t2[rr][i].y * rs * gg.y + bb.y;
            v.z = t2[rr][i].z * rs * gg.z + bb.z;
            v.w = t2[rr][i].w * rs * gg.w + bb.w;
            ((float4*)(x2f + base))[i * 64 + lane] = v;
            __hip_bfloat16 pk[4] = {
                __float2bfloat16(v.x), __float2bfloat16(v.y),
                __float2bfloat16(v.z), __float2bfloat16(v.w)};
            *(uint2*)(x2b + base + i * 256 + lane * 4) = *(const uint2*)pk;
        }
    }
}

// ---------------------------------------------------------------------------
extern "C" void kernel_launch(void* const* d_in, const int* in_sizes, int n_in,
                              void* d_out, int out_size, void* d_ws, size_t ws_size,
                              hipStream_t stream) {
    const float* cur   = (const float*)d_in[0];
    const float* prev  = (const float*)d_in[1];
    const float* cvec  = (const float*)d_in[2];
    const int*   ridx  = (const int*)d_in[3];
    const float* Wq  = (const float*)d_in[4];
    const float* bq  = (const float*)d_in[5];
    const float* Wk  = (const float*)d_in[6];
    const float* bk  = (const float*)d_in[7];
    const float* Wv  = (const float*)d_in[8];
    const float* bv  = (const float*)d_in[9];
    const float* Wo  = (const float*)d_in[10];
    const float* bo  = (const float*)d_in[11];
    const float* g1  = (const float*)d_in[12];
    const float* b1  = (const float*)d_in[13];
    const float* Wqc = (const float*)d_in[14];
    const float* bqc = (const float*)d_in[15];
    const float* Wkc = (const float*)d_in[16];
    const float* bkc = (const float*)d_in[17];  (void)bkc;
    const float* Wvc = (const float*)d_in[18];
    const float* bvc = (const float*)d_in[19];
    const float* Woc = (const float*)d_in[20];
    const float* boc = (const float*)d_in[21];
    const float* g2  = (const float*)d_in[22];
    const float* b2  = (const float*)d_in[23];
    const float* W1  = (const float*)d_in[24];
    const float* bf1 = (const float*)d_in[25];
    const float* W2  = (const float*)d_in[26];
    const float* bf2 = (const float*)d_in[27];
    const float* g3  = (const float*)d_in[28];
    const float* b3  = (const float*)d_in[29];
    float* outp = (float*)d_out;
    (void)ws_size; (void)in_sizes; (void)n_in; (void)out_size;

    const size_t NBSD = (size_t)B_ * S_ * D_;
    const size_t NSEL = (size_t)B_ * 128 * D_;

    float* bufA   = (float*)d_ws;
    float* bufB   = bufA + NBSD;
    float* Psel   = bufB + NBSD;          // slot reused: bf16 Pselb
    float* kself  = Psel + NSEL;
    float* vself  = kself + NSEL;
    float* Ub     = vself + NSEL;
    float* abv    = Ub + (size_t)D_ * H_;
    float* Wmix   = abv + 16;
    float* bias2  = Wmix + (size_t)H_ * D_;
    float* extra  = bias2 + D_;           // 2 * B*S*H floats free
    int*   selb   = (int*)(extra + 2 * (size_t)B_ * S_ * H_);
    __hip_bfloat16* bf0   = (__hip_bfloat16*)(selb + 512);
    __hip_bfloat16* hmidb = bf0 + NBSD;
    __hip_bfloat16* Wqt   = hmidb + NBSD;
    __hip_bfloat16* Wot   = Wqt + (size_t)D_ * D_;
    __hip_bfloat16* W1t   = Wot + (size_t)D_ * D_;
    __hip_bfloat16* W2t   = W1t + (size_t)D_ * FF_;
    __hip_bfloat16* Wkt   = W2t + (size_t)FF_ * D_;
    __hip_bfloat16* Wvt   = Wkt + (size_t)D_ * D_;
    __hip_bfloat16* Pselb = (__hip_bfloat16*)Psel;
    __hip_bfloat16* kselb = (__hip_bfloat16*)kself;
    __hip_bfloat16* vselb = (__hip_bfloat16*)vself;
    (void)bufA;

    const int M = B_ * S_;

    // 1) gather (bf16) + weight transposes + converts + precomputes
    gather_kernel<<<B_ * 128, 256, 0, stream>>>(prev, ridx, Pselb, selb);
    transp_bf16<<<dim3(D_ / 32, D_ / 32), 256, 0, stream>>>(Wq, Wqt, D_, D_);
    transp_bf16<<<dim3(D_ / 32, D_ / 32), 256, 0, stream>>>(Wo, Wot, D_, D_);
    transp_bf16<<<dim3(D_ / 32, D_ / 32), 256, 0, stream>>>(Wk, Wkt, D_, D_);
    transp_bf16<<<dim3(D_ / 32, D_ / 32), 256, 0, stream>>>(Wv, Wvt, D_, D_);
    transp_bf16<<<dim3(FF_ / 32, D_ / 32), 256, 0, stream>>>(W1, W1t, D_, FF_);
    transp_bf16<<<dim3(D_ / 32, FF_ / 32), 256, 0, stream>>>(W2, W2t, FF_, D_);
    conv_bf16<<<(int)(NBSD / 8 + 255) / 256, 256, 0, stream>>>(cur, bf0, (int)(NBSD / 8));
    precompute_U<<<(D_ * H_ + 255) / 256, 256, 0, stream>>>(Wqc, Wkc, bqc, Ub, abv);
    precompute_mix<<<(H_ * D_ + 255) / 256, 256, 0, stream>>>(Wvc, Woc, bvc, boc, Wmix, bias2);

    // 2) ksel/vsel projections (MFMA, bf16 out)
    {
        dim3 g(D_ / 128, (B_ * 128) / 128);   // 6 x 4 = 24 blocks
        gemm_mfma<<<g, 256, 0, stream>>>(Pselb, Wkt, bk, nullptr, kselb,
                                         B_ * 128, D_, D_, D_, D_, 1 | 8);
        gemm_mfma<<<g, 256, 0, stream>>>(Pselb, Wvt, bv, nullptr, vselb,
                                         B_ * 128, D_, D_, D_, D_, 1 | 8);
    }

    // 3) q = cur @ Wq + bq -> hmidb (bf16)
    gemm_mfma<<<dim3(D_ / 128, M / 128), 256, 0, stream>>>(
        bf0, Wqt, bq, nullptr, hmidb, M, D_, D_, D_, D_, 1 | 8);

    // 4) MFMA sparse attention -> bf0 (bf16)
    attn3_kernel<<<dim3(S_ / 256, B_ * H_), 256, 0, stream>>>(
        (const u16*)hmidb, (const u16*)kselb, (const u16*)vselb, selb, (u16*)bf0);

    // 5) o @ Wo + bo -> bufB (fp32)
    gemm_mfma<<<dim3(D_ / 128, M / 128), 256, 0, stream>>>(
        bf0, Wot, bo, bufB, nullptr, M, D_, D_, D_, D_, 1);

    // 6) fused mid: x1, class-attn, x2 -> outp (fp32) + bf0 (bf16)
    fused_mid<<<M / 8, 256, 0, stream>>>(
        cur, bufB, g1, b1, Ub, abv, cvec, Wmix, bias2, g2, b2, outp, bf0);

    // 7) FF in 4 column chunks of 768
    for (int c = 0; c < 4; ++c) {
        gemm_mfma<<<dim3(D_ / 128, M / 128), 256, 0, stream>>>(
            bf0, W1t + (size_t)c * D_ * D_, bf1 + (size_t)c * D_,
            nullptr, hmidb, M, D_, D_, D_, D_, 1 | 2 | 8);
        gemm_mfma<<<dim3(D_ / 128, M / 128), 256, 0, stream>>>(
            hmidb, W2t + (size_t)c * D_, bf2,
            bufB, nullptr, M, D_, D_, D_, FF_, (c == 0) ? 1 : 4);
    }

    // 8) out = LN(x2 + ff)
    addln_kernel<<<M, 256, 0, stream>>>(outp, bufB, g3, b3, outp);
}

// Round 6
// 564.271 us; speedup vs baseline: 10.3680x; 1.0703x over previous
//
#include <hip/hip_runtime.h>
#include <hip/hip_bf16.h>

#define B_ 4
#define S_ 4096
#define D_ 768
#define H_ 12
#define DH_ 64
#define G_ 64
#define C_ 256
#define FF_ 3072

typedef __attribute__((ext_vector_type(8))) short bf16x8;
typedef __attribute__((ext_vector_type(4))) float f32x4;
typedef unsigned short u16;

// ---------------------------------------------------------------------------
// async global->LDS 16B (wave-uniform LDS base + lane*16)
// ---------------------------------------------------------------------------
__device__ __forceinline__ void gload16(const __hip_bfloat16* g, __hip_bfloat16* l) {
    __builtin_amdgcn_global_load_lds(
        (__attribute__((address_space(1))) void*)(void*)const_cast<__hip_bfloat16*>(g),
        (__attribute__((address_space(3))) void*)(void*)l,
        16, 0, 0);
}

// ---------------------------------------------------------------------------
// bf16 MFMA GEMM, double-buffered 2-phase, global_load_lds staging.
// flags: 1=bias, 2=relu, 4=accumulate into Cf, 8=store bf16 to Cb
// ---------------------------------------------------------------------------
__global__ __launch_bounds__(256) void gemm_mfma(
    const __hip_bfloat16* __restrict__ A, const __hip_bfloat16* __restrict__ Bt,
    const float* __restrict__ bias, float* __restrict__ Cf,
    __hip_bfloat16* __restrict__ Cb,
    int M, int N, int K, int lda, int ldbt, int flags)
{
    __shared__ __hip_bfloat16 As[2][128 * 32];
    __shared__ __hip_bfloat16 Bs[2][128 * 32];

    const int t = threadIdx.x;
    const int lane = t & 63;
    const int wave = t >> 6;
    const int wr = wave >> 1, wc = wave & 1;
    const int qd = lane >> 4, r = lane & 15;

    int lin = blockIdx.y * gridDim.x + blockIdx.x;
    int nwg = gridDim.x * gridDim.y;
    int cpx = nwg >> 3;
    int swz = (lin & 7) * cpx + (lin >> 3);
    int bm = (swz / gridDim.x) * 128;
    int bn = (swz % gridDim.x) * 128;

    const int srow = lane >> 2;
    const int scol = (lane & 3) * 8;
    const __hip_bfloat16* gA0 = A + (size_t)(bm + wave * 32 + srow) * lda + scol;
    const __hip_bfloat16* gA1 = gA0 + (size_t)16 * lda;
    const __hip_bfloat16* gB0 = Bt + (size_t)(bn + wave * 32 + srow) * ldbt + scol;
    const __hip_bfloat16* gB1 = gB0 + (size_t)16 * ldbt;

    f32x4 acc[4][4] = {};

    gload16(gA0, &As[0][wave * 1024]);
    gload16(gA1, &As[0][wave * 1024 + 512]);
    gload16(gB0, &Bs[0][wave * 1024]);
    gload16(gB1, &Bs[0][wave * 1024 + 512]);
    __syncthreads();

    int cur = 0;
    for (int k0 = 0; k0 < K; k0 += 32, cur ^= 1) {
        if (k0 + 32 < K) {
            int kn = k0 + 32, nb = cur ^ 1;
            gload16(gA0 + kn, &As[nb][wave * 1024]);
            gload16(gA1 + kn, &As[nb][wave * 1024 + 512]);
            gload16(gB0 + kn, &Bs[nb][wave * 1024]);
            gload16(gB1 + kn, &Bs[nb][wave * 1024 + 512]);
        }
        bf16x8 afr[4], bfr[4];
#pragma unroll
        for (int m = 0; m < 4; ++m)
            afr[m] = *(const bf16x8*)&As[cur][(wr * 64 + m * 16 + r) * 32 + qd * 8];
#pragma unroll
        for (int n = 0; n < 4; ++n)
            bfr[n] = *(const bf16x8*)&Bs[cur][(wc * 64 + n * 16 + r) * 32 + qd * 8];
#pragma unroll
        for (int m = 0; m < 4; ++m)
#pragma unroll
            for (int n = 0; n < 4; ++n)
                acc[m][n] = __builtin_amdgcn_mfma_f32_16x16x32_bf16(
                    afr[m], bfr[n], acc[m][n], 0, 0, 0);
        __syncthreads();
    }

#pragma unroll
    for (int m = 0; m < 4; ++m) {
        int row0 = bm + wr * 64 + m * 16 + qd * 4;
#pragma unroll
        for (int n = 0; n < 4; ++n) {
            int col = bn + wc * 64 + n * 16 + r;
            float bv = (flags & 1) ? bias[col] : 0.0f;
#pragma unroll
            for (int i = 0; i < 4; ++i) {
                float v = acc[m][n][i] + bv;
                if (flags & 2) v = fmaxf(v, 0.0f);
                size_t off = (size_t)(row0 + i) * N + col;
                if (flags & 4) v += Cf[off];
                if (flags & 8) Cb[off] = __float2bfloat16(v);
                else           Cf[off] = v;
            }
        }
    }
}

// ---------------------------------------------------------------------------
__global__ __launch_bounds__(256) void conv_bf16(const float* __restrict__ in,
                                                 __hip_bfloat16* __restrict__ out,
                                                 int n8)
{
    int i = blockIdx.x * 256 + threadIdx.x;
    if (i >= n8) return;
    const float4* p = (const float4*)(in + (size_t)i * 8);
    float4 v0 = p[0], v1 = p[1];
    __hip_bfloat16 o[8] = {
        __float2bfloat16(v0.x), __float2bfloat16(v0.y),
        __float2bfloat16(v0.z), __float2bfloat16(v0.w),
        __float2bfloat16(v1.x), __float2bfloat16(v1.y),
        __float2bfloat16(v1.z), __float2bfloat16(v1.w)};
    *(uint4*)(out + (size_t)i * 8) = *(const uint4*)o;
}

// ---------------------------------------------------------------------------
// All 6 weight transposes in one dispatch. Tiles:
// [0,2304): Wq/Wo/Wk/Wv (768x768, 576 tiles each)
// [2304,4608): W1 (768x3072), [4608,6912): W2 (3072x768)
// ---------------------------------------------------------------------------
__global__ __launch_bounds__(256) void transp_all(
    const float* __restrict__ Wq, const float* __restrict__ Wo,
    const float* __restrict__ Wk, const float* __restrict__ Wv,
    const float* __restrict__ W1, const float* __restrict__ W2,
    __hip_bfloat16* __restrict__ Wqt, __hip_bfloat16* __restrict__ Wot,
    __hip_bfloat16* __restrict__ Wkt, __hip_bfloat16* __restrict__ Wvt,
    __hip_bfloat16* __restrict__ W1t, __hip_bfloat16* __restrict__ W2t)
{
    int tile = blockIdx.x;
    const float* W; __hip_bfloat16* Wt; int K, N;
    if (tile < 2304) {
        int w = tile / 576; tile -= w * 576;
        K = 768; N = 768;
        W  = (w == 0) ? Wq : (w == 1) ? Wo : (w == 2) ? Wk : Wv;
        Wt = (w == 0) ? Wqt : (w == 1) ? Wot : (w == 2) ? Wkt : Wvt;
    } else if (tile < 4608) { tile -= 2304; K = 768; N = 3072; W = W1; Wt = W1t; }
    else                    { tile -= 4608; K = 3072; N = 768; W = W2; Wt = W2t; }
    int ntx = N >> 5;
    int k0 = (tile / ntx) * 32, n0 = (tile % ntx) * 32;
    __shared__ float s[32][33];
    int tx = threadIdx.x & 31, ty = threadIdx.x >> 5;
#pragma unroll
    for (int i = 0; i < 4; ++i)
        s[ty + i * 8][tx] = W[(size_t)(k0 + ty + i * 8) * N + n0 + tx];
    __syncthreads();
#pragma unroll
    for (int i = 0; i < 4; ++i)
        Wt[(size_t)(n0 + ty + i * 8) * K + k0 + tx] =
            __float2bfloat16(s[tx][ty + i * 8]);
}

// ---------------------------------------------------------------------------
__global__ void gather_kernel(const float* __restrict__ prev,
                              const int* __restrict__ rand_idx,
                              __hip_bfloat16* __restrict__ Pselb,
                              int* __restrict__ sel)
{
    int j = blockIdx.x;
    int b = j >> 7, i = j & 127;
    int sv = (i < 64) ? i : rand_idx[b * G_ + (i - 64)];
    if (threadIdx.x == 0) sel[j] = sv;
    const float* src = prev + ((size_t)(b * S_ + sv)) * D_;
    __hip_bfloat16* dst = Pselb + (size_t)j * D_;
    for (int d = threadIdx.x; d < D_; d += blockDim.x)
        dst[d] = __float2bfloat16(src[d]);
}

// ---------------------------------------------------------------------------
// MFMA sparse attention (round-3 structure)
// ---------------------------------------------------------------------------
__global__ __launch_bounds__(256) void attn3_kernel(
    const u16* __restrict__ qb, const u16* __restrict__ kb,
    const u16* __restrict__ vb, const int* __restrict__ sel,
    u16* __restrict__ out)
{
    const int bh = blockIdx.y;
    const int b = bh / H_, h = bh % H_;
    const int s0 = blockIdx.x * 256;
    const int t = threadIdx.x;
    const int w = t >> 6, lane = t & 63;
    const int r = lane & 15, qd = lane >> 4;

    __shared__ u16 Vt[64][136];
    __shared__ u16 Plds[4][32][136];
    __shared__ int ssel[128];

    {
        int key0 = t >> 4;
        int d0 = (t & 15) * 4;
        for (int kk = key0; kk < 128; kk += 16) {
            ushort4 v = *(const ushort4*)(vb + (size_t)(b * 128 + kk) * D_ + h * 64 + d0);
            Vt[d0 + 0][kk] = v.x; Vt[d0 + 1][kk] = v.y;
            Vt[d0 + 2][kk] = v.z; Vt[d0 + 3][kk] = v.w;
        }
        if (t < 128) ssel[t] = sel[b * 128 + t];
    }
    __syncthreads();

    int selv[8];
#pragma unroll
    for (int n = 0; n < 8; ++n) selv[n] = ssel[n * 16 + r];

    for (int pass = 0; pass < 2; ++pass) {
        const int sbase = s0 + w * 64 + pass * 32;
        f32x4 accs[2][8] = {};

#pragma unroll
        for (int ks = 0; ks < 2; ++ks) {
            bf16x8 af[2];
#pragma unroll
            for (int m = 0; m < 2; ++m)
                af[m] = *(const bf16x8*)(qb + (size_t)(b * S_ + sbase + m * 16 + r) * D_ + h * 64 + ks * 32 + qd * 8);
#pragma unroll
            for (int n = 0; n < 8; ++n) {
                bf16x8 bfv = *(const bf16x8*)(kb + (size_t)(b * 128 + n * 16 + r) * D_ + h * 64 + ks * 32 + qd * 8);
#pragma unroll
                for (int m = 0; m < 2; ++m)
                    accs[m][n] = __builtin_amdgcn_mfma_f32_16x16x32_bf16(
                        af[m], bfv, accs[m][n], 0, 0, 0);
            }
        }

#pragma unroll
        for (int m = 0; m < 2; ++m) {
#pragma unroll
            for (int i = 0; i < 4; ++i) {
                int srow = sbase + m * 16 + qd * 4 + i;
                float pm = -3e38f;
#pragma unroll
                for (int n = 0; n < 8; ++n) {
                    float sc = accs[m][n][i] * 0.125f;
                    if (selv[n] > srow) sc = -1e9f;
                    accs[m][n][i] = sc;
                    pm = fmaxf(pm, sc);
                }
#pragma unroll
                for (int off = 1; off < 16; off <<= 1)
                    pm = fmaxf(pm, __shfl_xor(pm, off, 64));
                float ps = 0.f;
#pragma unroll
                for (int n = 0; n < 8; ++n) {
                    float e = __expf(accs[m][n][i] - pm);
                    accs[m][n][i] = e;
                    ps += e;
                }
#pragma unroll
                for (int off = 1; off < 16; off <<= 1)
                    ps += __shfl_xor(ps, off, 64);
                float inv = 1.0f / ps;
#pragma unroll
                for (int n = 0; n < 8; ++n)
                    accs[m][n][i] *= inv;
            }
        }

#pragma unroll
        for (int m = 0; m < 2; ++m)
#pragma unroll
            for (int n = 0; n < 8; ++n)
#pragma unroll
                for (int i = 0; i < 4; ++i) {
                    __hip_bfloat16 pb = __float2bfloat16(accs[m][n][i]);
                    Plds[w][m * 16 + qd * 4 + i][n * 16 + r] = *(u16*)&pb;
                }

        f32x4 acco[2][4] = {};
#pragma unroll
        for (int ks = 0; ks < 4; ++ks) {
            bf16x8 pa[2];
#pragma unroll
            for (int m = 0; m < 2; ++m)
                pa[m] = *(const bf16x8*)&Plds[w][m * 16 + r][ks * 32 + qd * 8];
#pragma unroll
            for (int nd = 0; nd < 4; ++nd) {
                bf16x8 bv = *(const bf16x8*)&Vt[nd * 16 + r][ks * 32 + qd * 8];
#pragma unroll
                for (int m = 0; m < 2; ++m)
                    acco[m][nd] = __builtin_amdgcn_mfma_f32_16x16x32_bf16(
                        pa[m], bv, acco[m][nd], 0, 0, 0);
            }
        }

#pragma unroll
        for (int m = 0; m < 2; ++m)
#pragma unroll
            for (int nd = 0; nd < 4; ++nd)
#pragma unroll
                for (int i = 0; i < 4; ++i) {
                    __hip_bfloat16 ob = __float2bfloat16(acco[m][nd][i]);
                    out[(size_t)(b * S_ + sbase + m * 16 + qd * 4 + i) * D_ + h * 64 + nd * 16 + r] = *(u16*)&ob;
                }
    }
}

// ---------------------------------------------------------------------------
// final LN: out[row] = LN(bf16 xa + fp32 xb)*g+beta
// ---------------------------------------------------------------------------
__global__ __launch_bounds__(256) void addln_bf(
    const __hip_bfloat16* __restrict__ xa, const float* __restrict__ xb,
    const float* __restrict__ g, const float* __restrict__ beta,
    float* __restrict__ out)
{
    const int row = blockIdx.x;
    const __hip_bfloat16* pa = xa + (size_t)row * D_;
    const float* pb = xb + (size_t)row * D_;
    float v[3];
    float sum = 0.f;
#pragma unroll
    for (int i = 0; i < 3; ++i) {
        int d = threadIdx.x + i * 256;
        v[i] = __bfloat162float(pa[d]) + pb[d];
        sum += v[i];
    }
#pragma unroll
    for (int off = 32; off; off >>= 1) sum += __shfl_xor(sum, off, 64);
    __shared__ float r1[4], r2[4];
    int wv = threadIdx.x >> 6, ln = threadIdx.x & 63;
    if (ln == 0) r1[wv] = sum;
    __syncthreads();
    float mean = (r1[0] + r1[1] + r1[2] + r1[3]) * (1.0f / 768.0f);
    float sq = 0.f;
#pragma unroll
    for (int i = 0; i < 3; ++i) { v[i] -= mean; sq += v[i] * v[i]; }
#pragma unroll
    for (int off = 32; off; off >>= 1) sq += __shfl_xor(sq, off, 64);
    if (ln == 0) r2[wv] = sq;
    __syncthreads();
    float var = (r2[0] + r2[1] + r2[2] + r2[3]) * (1.0f / 768.0f);
    float rs = rsqrtf(var + 1e-5f);
    float* po = out + (size_t)row * D_;
#pragma unroll
    for (int i = 0; i < 3; ++i) {
        int d = threadIdx.x + i * 256;
        po[d] = v[i] * rs * g[d] + beta[d];
    }
}

// ---------------------------------------------------------------------------
// precompute_U v2: Ut[h*768+d] = dot(Wqc[d, h*64:+64], Wkc[h*64:+64]).
// Wkc staged in LDS; fully-unrolled float4 chain (16 loads in flight).
// grid 36 x 256.
// ---------------------------------------------------------------------------
__global__ __launch_bounds__(256) void precompute_U(
    const float* __restrict__ Wqc, const float* __restrict__ Wkc,
    const float* __restrict__ bqc, float* __restrict__ Ut, float* __restrict__ ab)
{
    __shared__ __attribute__((aligned(16))) float wk[D_];
    for (int i = threadIdx.x; i < D_; i += 256) wk[i] = Wkc[i];
    __syncthreads();
    int idx = blockIdx.x * 256 + threadIdx.x;   // h*768 + d
    int h = idx / D_, d = idx - h * D_;
    const float4* row = (const float4*)(Wqc + (size_t)d * D_ + h * 64);
    const float4* wkv = (const float4*)(wk + h * 64);
    float a0 = 0.f, a1 = 0.f, a2 = 0.f, a3 = 0.f;
#pragma unroll
    for (int j = 0; j < 16; j += 4) {
        float4 r0 = row[j], r1 = row[j + 1], r2 = row[j + 2], r3 = row[j + 3];
        float4 c0 = wkv[j], c1 = wkv[j + 1], c2 = wkv[j + 2], c3 = wkv[j + 3];
        a0 += r0.x * c0.x + r0.y * c0.y + r0.z * c0.z + r0.w * c0.w;
        a1 += r1.x * c1.x + r1.y * c1.y + r1.z * c1.z + r1.w * c1.w;
        a2 += r2.x * c2.x + r2.y * c2.y + r2.z * c2.z + r2.w * c2.w;
        a3 += r3.x * c3.x + r3.y * c3.y + r3.z * c3.z + r3.w * c3.w;
    }
    Ut[idx] = (a0 + a1) + (a2 + a3);
    if (idx < H_) {
        const float4* bq4 = (const float4*)(bqc + idx * 64);
        const float4* wk4 = (const float4*)(wk + idx * 64);
        float s = 0.f;
#pragma unroll
        for (int j = 0; j < 16; ++j) {
            float4 bb = bq4[j], cc = wk4[j];
            s += bb.x * cc.x + bb.y * cc.y + bb.z * cc.z + bb.w * cc.w;
        }
        ab[idx] = s;
    }
}

// ---------------------------------------------------------------------------
// precompute_mix v2: Wmix[h*768+n] = sum_j Wvc[h*64+j]*Woc[(h*64+j)*768+n].
// Wvc staged in LDS; 64-deep unroll, coalesced Woc reads. grid 36 x 256.
// ---------------------------------------------------------------------------
__global__ __launch_bounds__(256) void precompute_mix(
    const float* __restrict__ Wvc, const float* __restrict__ Woc,
    float* __restrict__ Wmix)
{
    __shared__ float wv[D_];
    for (int i = threadIdx.x; i < D_; i += 256) wv[i] = Wvc[i];
    __syncthreads();
    int idx = blockIdx.x * 256 + threadIdx.x;
    int h = idx / D_, n = idx - h * D_;
    float acc[8] = {};
#pragma unroll
    for (int j = 0; j < 64; ++j)
        acc[j & 7] += wv[h * 64 + j] * Woc[(size_t)(h * 64 + j) * D_ + n];
    Wmix[idx] = ((acc[0] + acc[1]) + (acc[2] + acc[3]))
              + ((acc[4] + acc[5]) + (acc[6] + acc[7]));
}

// ---------------------------------------------------------------------------
// bias2[n] = boc[n] + sum_d bvc[d]*Woc[d*768+n].  12 blocks x (4 stripes x 64n)
// ---------------------------------------------------------------------------
__global__ __launch_bounds__(256) void precompute_bias2(
    const float* __restrict__ Woc, const float* __restrict__ bvc,
    const float* __restrict__ boc, float* __restrict__ bias2)
{
    int tx = threadIdx.x & 63, ty = threadIdx.x >> 6;
    int n = blockIdx.x * 64 + tx;
    int d0 = ty * 192;
    float a = 0.f;
#pragma unroll 8
    for (int d = 0; d < 192; ++d)
        a += bvc[d0 + d] * Woc[(size_t)(d0 + d) * D_ + n];
    __shared__ float red[4][64];
    red[ty][tx] = a;
    __syncthreads();
    if (ty == 0)
        bias2[n] = boc[n] + red[0][tx] + red[1][tx] + red[2][tx] + red[3][tx];
}

// ---------------------------------------------------------------------------
// Fused mid v3: x1=LN(cur+oproj); alpha=0.125*(x1@U+ab);
// mu=sum_c softmax(alpha*cv)*cv; x2=LN(x1+bias2+mu@Wmix) -> x2b (bf16 only).
// ---------------------------------------------------------------------------
__global__ __launch_bounds__(256) void fused_mid(
    const float* __restrict__ cur, const float* __restrict__ oproj,
    const float* __restrict__ g1, const float* __restrict__ b1,
    const float* __restrict__ Ut, const float* __restrict__ ab,
    const float* __restrict__ cvec,
    const float* __restrict__ Wmix, const float* __restrict__ bias2,
    const float* __restrict__ g2, const float* __restrict__ b2,
    __hip_bfloat16* __restrict__ x2b)
{
    const int w = threadIdx.x >> 6, lane = threadIdx.x & 63;
    const int row0 = blockIdx.x * 8 + w * 2;
    const int b = blockIdx.x >> 9;

    __shared__ float4 cvs[64];
    __shared__ float xp[4][64][28];
    __shared__ float muls[4][24];

    if (threadIdx.x < 64)
        cvs[threadIdx.x] = ((const float4*)(cvec + b * C_))[threadIdx.x];

    float4 x1[2][3];
#pragma unroll
    for (int rr = 0; rr < 2; ++rr) {
        const float4* pa = (const float4*)(cur + (size_t)(row0 + rr) * D_);
        const float4* pb = (const float4*)(oproj + (size_t)(row0 + rr) * D_);
        float s = 0.f;
#pragma unroll
        for (int i = 0; i < 3; ++i) {
            float4 a = pa[i * 64 + lane], o = pb[i * 64 + lane];
            float4 v; v.x = a.x + o.x; v.y = a.y + o.y; v.z = a.z + o.z; v.w = a.w + o.w;
            x1[rr][i] = v;
            s += v.x + v.y + v.z + v.w;
        }
#pragma unroll
        for (int off = 1; off < 64; off <<= 1) s += __shfl_xor(s, off, 64);
        float mean = s * (1.0f / 768.0f);
        float sq = 0.f;
#pragma unroll
        for (int i = 0; i < 3; ++i) {
            x1[rr][i].x -= mean; x1[rr][i].y -= mean;
            x1[rr][i].z -= mean; x1[rr][i].w -= mean;
            sq += x1[rr][i].x * x1[rr][i].x + x1[rr][i].y * x1[rr][i].y
                + x1[rr][i].z * x1[rr][i].z + x1[rr][i].w * x1[rr][i].w;
        }
#pragma unroll
        for (int off = 1; off < 64; off <<= 1) sq += __shfl_xor(sq, off, 64);
        float rs = rsqrtf(sq * (1.0f / 768.0f) + 1e-5f);
#pragma unroll
        for (int i = 0; i < 3; ++i) {
            float4 gg = ((const float4*)g1)[i * 64 + lane];
            float4 bb = ((const float4*)b1)[i * 64 + lane];
            x1[rr][i].x = x1[rr][i].x * rs * gg.x + bb.x;
            x1[rr][i].y = x1[rr][i].y * rs * gg.y + bb.y;
            x1[rr][i].z = x1[rr][i].z * rs * gg.z + bb.z;
            x1[rr][i].w = x1[rr][i].w * rs * gg.w + bb.w;
        }
    }

    float acc[24];
#pragma unroll
    for (int j = 0; j < 24; ++j) acc[j] = 0.f;
#pragma unroll
    for (int i = 0; i < 3; ++i) {
#pragma unroll
        for (int h = 0; h < 12; ++h) {
            float4 u = ((const float4*)(Ut + (size_t)h * D_))[i * 64 + lane];
#pragma unroll
            for (int rr = 0; rr < 2; ++rr)
                acc[rr * 12 + h] += x1[rr][i].x * u.x + x1[rr][i].y * u.y
                                  + x1[rr][i].z * u.z + x1[rr][i].w * u.w;
        }
    }
#pragma unroll
    for (int j4 = 0; j4 < 6; ++j4)
        *(float4*)&xp[w][lane][j4 * 4] = *(float4*)&acc[j4 * 4];
    __syncthreads();

    if (lane < 48) {
        int j = lane >> 1, half = lane & 1;
        float ssum = 0.f;
#pragma unroll
        for (int k = 0; k < 32; ++k) ssum += xp[w][half * 32 + k][j];
        ssum += __shfl_xor(ssum, 1, 64);
        float a = 0.125f * (ssum + ab[j % 12]);
        float z = 0.f, ms = 0.f;
#pragma unroll
        for (int it = 0; it < 32; ++it) {
            float4 c = cvs[half * 32 + it];
            float e0 = __expf(a * c.x), e1 = __expf(a * c.y),
                  e2 = __expf(a * c.z), e3 = __expf(a * c.w);
            z += e0 + e1 + e2 + e3;
            ms += e0 * c.x + e1 * c.y + e2 * c.z + e3 * c.w;
        }
        z += __shfl_xor(z, 1, 64);
        ms += __shfl_xor(ms, 1, 64);
        if (half == 0) muls[w][j] = ms / z;
    }
    __syncthreads();

    float4 t2[2][3];
#pragma unroll
    for (int i = 0; i < 3; ++i) {
        float4 bv = ((const float4*)bias2)[i * 64 + lane];
        float4 o0 = bv, o1 = bv;
#pragma unroll
        for (int h = 0; h < 12; ++h) {
            float4 wm = ((const float4*)(Wmix + (size_t)h * D_))[i * 64 + lane];
            float m0 = muls[w][h], m1 = muls[w][12 + h];
            o0.x += m0 * wm.x; o0.y += m0 * wm.y; o0.z += m0 * wm.z; o0.w += m0 * wm.w;
            o1.x += m1 * wm.x; o1.y += m1 * wm.y; o1.z += m1 * wm.z; o1.w += m1 * wm.w;
        }
        t2[0][i].x = x1[0][i].x + o0.x; t2[0][i].y = x1[0][i].y + o0.y;
        t2[0][i].z = x1[0][i].z + o0.z; t2[0][i].w = x1[0][i].w + o0.w;
        t2[1][i].x = x1[1][i].x + o1.x; t2[1][i].y = x1[1][i].y + o1.y;
        t2[1][i].z = x1[1][i].z + o1.z; t2[1][i].w = x1[1][i].w + o1.w;
    }

#pragma unroll
    for (int rr = 0; rr < 2; ++rr) {
        float s = 0.f;
#pragma unroll
        for (int i = 0; i < 3; ++i)
            s += t2[rr][i].x + t2[rr][i].y + t2[rr][i].z + t2[rr][i].w;
#pragma unroll
        for (int off = 1; off < 64; off <<= 1) s += __shfl_xor(s, off, 64);
        float mean = s * (1.0f / 768.0f);
        float sq = 0.f;
#pragma unroll
        for (int i = 0; i < 3; ++i) {
            t2[rr][i].x -= mean; t2[rr][i].y -= mean;
            t2[rr][i].z -= mean; t2[rr][i].w -= mean;
            sq += t2[rr][i].x * t2[rr][i].x + t2[rr][i].y * t2[rr][i].y
                + t2[rr][i].z * t2[rr][i].z + t2[rr][i].w * t2[rr][i].w;
        }
#pragma unroll
        for (int off = 1; off < 64; off <<= 1) sq += __shfl_xor(sq, off, 64);
        float rs = rsqrtf(sq * (1.0f / 768.0f) + 1e-5f);
        size_t base = (size_t)(row0 + rr) * D_;
#pragma unroll
        for (int i = 0; i < 3; ++i) {
            float4 gg = ((const float4*)g2)[i * 64 + lane];
            float4 bb = ((const float4*)b2)[i * 64 + lane];
            float vx = t2[rr][i].x * rs * gg.x + bb.x;
            float vy = t2[rr][i].y * rs * gg.y + bb.y;
            float vz = t2[rr][i].z * rs * gg.z + bb.z;
            float vw = t2[rr][i].w * rs * gg.w + bb.w;
            __hip_bfloat16 pk[4] = {
                __float2bfloat16(vx), __float2bfloat16(vy),
                __float2bfloat16(vz), __float2bfloat16(vw)};
            *(uint2*)(x2b + base + i * 256 + lane * 4) = *(const uint2*)pk;
        }
    }
}

// ---------------------------------------------------------------------------
extern "C" void kernel_launch(void* const* d_in, const int* in_sizes, int n_in,
                              void* d_out, int out_size, void* d_ws, size_t ws_size,
                              hipStream_t stream) {
    const float* cur   = (const float*)d_in[0];
    const float* prev  = (const float*)d_in[1];
    const float* cvec  = (const float*)d_in[2];
    const int*   ridx  = (const int*)d_in[3];
    const float* Wq  = (const float*)d_in[4];
    const float* bq  = (const float*)d_in[5];
    const float* Wk  = (const float*)d_in[6];
    const float* bk  = (const float*)d_in[7];
    const float* Wv  = (const float*)d_in[8];
    const float* bv  = (const float*)d_in[9];
    const float* Wo  = (const float*)d_in[10];
    const float* bo  = (const float*)d_in[11];
    const float* g1  = (const float*)d_in[12];
    const float* b1  = (const float*)d_in[13];
    const float* Wqc = (const float*)d_in[14];
    const float* bqc = (const float*)d_in[15];
    const float* Wkc = (const float*)d_in[16];
    const float* bkc = (const float*)d_in[17];  (void)bkc;
    const float* Wvc = (const float*)d_in[18];
    const float* bvc = (const float*)d_in[19];
    const float* Woc = (const float*)d_in[20];
    const float* boc = (const float*)d_in[21];
    const float* g2  = (const float*)d_in[22];
    const float* b2  = (const float*)d_in[23];
    const float* W1  = (const float*)d_in[24];
    const float* bf1 = (const float*)d_in[25];
    const float* W2  = (const float*)d_in[26];
    const float* bf2 = (const float*)d_in[27];
    const float* g3  = (const float*)d_in[28];
    const float* b3  = (const float*)d_in[29];
    float* outp = (float*)d_out;
    (void)ws_size; (void)in_sizes; (void)n_in; (void)out_size;

    const size_t NBSD = (size_t)B_ * S_ * D_;
    const size_t NSEL = (size_t)B_ * 128 * D_;

    float* bufA   = (float*)d_ws;
    float* bufB   = bufA + NBSD;
    float* Psel   = bufB + NBSD;
    float* kself  = Psel + NSEL;
    float* vself  = kself + NSEL;
    float* Ub     = vself + NSEL;
    float* abv    = Ub + (size_t)D_ * H_;
    float* Wmix   = abv + 16;
    float* bias2  = Wmix + (size_t)H_ * D_;
    float* extra  = bias2 + D_;
    int*   selb   = (int*)(extra + 2 * (size_t)B_ * S_ * H_);
    __hip_bfloat16* bf0   = (__hip_bfloat16*)(selb + 512);
    __hip_bfloat16* hmidb = bf0 + NBSD;
    __hip_bfloat16* Wqt   = hmidb + NBSD;
    __hip_bfloat16* Wot   = Wqt + (size_t)D_ * D_;
    __hip_bfloat16* W1t   = Wot + (size_t)D_ * D_;
    __hip_bfloat16* W2t   = W1t + (size_t)D_ * FF_;
    __hip_bfloat16* Wkt   = W2t + (size_t)FF_ * D_;
    __hip_bfloat16* Wvt   = Wkt + (size_t)D_ * D_;
    __hip_bfloat16* Pselb = (__hip_bfloat16*)Psel;
    __hip_bfloat16* kselb = (__hip_bfloat16*)kself;
    __hip_bfloat16* vselb = (__hip_bfloat16*)vself;
    (void)bufA;

    const int M = B_ * S_;

    // 1) gather (bf16) + all transposes + convert + precomputes
    gather_kernel<<<B_ * 128, 256, 0, stream>>>(prev, ridx, Pselb, selb);
    transp_all<<<6912, 256, 0, stream>>>(Wq, Wo, Wk, Wv, W1, W2,
                                         Wqt, Wot, Wkt, Wvt, W1t, W2t);
    conv_bf16<<<(int)(NBSD / 8 + 255) / 256, 256, 0, stream>>>(cur, bf0, (int)(NBSD / 8));
    precompute_U<<<36, 256, 0, stream>>>(Wqc, Wkc, bqc, Ub, abv);
    precompute_mix<<<36, 256, 0, stream>>>(Wvc, Woc, Wmix);
    precompute_bias2<<<12, 256, 0, stream>>>(Woc, bvc, boc, bias2);

    // 2) ksel/vsel projections (MFMA, bf16 out)
    {
        dim3 g(D_ / 128, (B_ * 128) / 128);
        gemm_mfma<<<g, 256, 0, stream>>>(Pselb, Wkt, bk, nullptr, kselb,
                                         B_ * 128, D_, D_, D_, D_, 1 | 8);
        gemm_mfma<<<g, 256, 0, stream>>>(Pselb, Wvt, bv, nullptr, vselb,
                                         B_ * 128, D_, D_, D_, D_, 1 | 8);
    }

    // 3) q = cur @ Wq + bq -> hmidb (bf16)
    gemm_mfma<<<dim3(D_ / 128, M / 128), 256, 0, stream>>>(
        bf0, Wqt, bq, nullptr, hmidb, M, D_, D_, D_, D_, 1 | 8);

    // 4) MFMA sparse attention -> bf0 (bf16)
    attn3_kernel<<<dim3(S_ / 256, B_ * H_), 256, 0, stream>>>(
        (const u16*)hmidb, (const u16*)kselb, (const u16*)vselb, selb, (u16*)bf0);

    // 5) o @ Wo + bo -> bufB (fp32)
    gemm_mfma<<<dim3(D_ / 128, M / 128), 256, 0, stream>>>(
        bf0, Wot, bo, bufB, nullptr, M, D_, D_, D_, D_, 1);

    // 6) fused mid: x1, class-attn, x2 -> bf0 (bf16 only)
    fused_mid<<<M / 8, 256, 0, stream>>>(
        cur, bufB, g1, b1, Ub, abv, cvec, Wmix, bias2, g2, b2, bf0);

    // 7) FF in 4 column chunks of 768
    for (int c = 0; c < 4; ++c) {
        gemm_mfma<<<dim3(D_ / 128, M / 128), 256, 0, stream>>>(
            bf0, W1t + (size_t)c * D_ * D_, bf1 + (size_t)c * D_,
            nullptr, hmidb, M, D_, D_, D_, D_, 1 | 2 | 8);
        gemm_mfma<<<dim3(D_ / 128, M / 128), 256, 0, stream>>>(
            hmidb, W2t + (size_t)c * D_, bf2,
            bufB, nullptr, M, D_, D_, D_, FF_, (c == 0) ? 1 : 4);
    }

    // 8) out = LN(x2 + ff)
    addln_bf<<<M, 256, 0, stream>>>(bf0, bufB, g3, b3, outp);
}

// Round 7
// 465.501 us; speedup vs baseline: 12.5679x; 1.2122x over previous
//
#include <hip/hip_runtime.h>
#include <hip/hip_bf16.h>

#define B_ 4
#define S_ 4096
#define D_ 768
#define H_ 12
#define DH_ 64
#define G_ 64
#define C_ 256
#define FF_ 3072

typedef __attribute__((ext_vector_type(8))) short bf16x8;
typedef __attribute__((ext_vector_type(4))) float f32x4;
typedef unsigned short u16;

__device__ __forceinline__ float bfu2f(u16 u) {
    return __uint_as_float((unsigned)u << 16);
}

// ---------------------------------------------------------------------------
// async global->LDS 16B (wave-uniform LDS base + lane*16)
// ---------------------------------------------------------------------------
__device__ __forceinline__ void gload16(const __hip_bfloat16* g, __hip_bfloat16* l) {
    __builtin_amdgcn_global_load_lds(
        (__attribute__((address_space(1))) void*)(void*)const_cast<__hip_bfloat16*>(g),
        (__attribute__((address_space(3))) void*)(void*)l,
        16, 0, 0);
}

// ---------------------------------------------------------------------------
// bf16 MFMA GEMM, double-buffered 2-phase, global_load_lds staging.
// flags: 1=bias, 2=relu, 4=accumulate into Cf, 8=store bf16 to Cb
// ---------------------------------------------------------------------------
__global__ __launch_bounds__(256) void gemm_mfma(
    const __hip_bfloat16* __restrict__ A, const __hip_bfloat16* __restrict__ Bt,
    const float* __restrict__ bias, float* __restrict__ Cf,
    __hip_bfloat16* __restrict__ Cb,
    int M, int N, int K, int lda, int ldbt, int flags)
{
    __shared__ __hip_bfloat16 As[2][128 * 32];
    __shared__ __hip_bfloat16 Bs[2][128 * 32];

    const int t = threadIdx.x;
    const int lane = t & 63;
    const int wave = t >> 6;
    const int wr = wave >> 1, wc = wave & 1;
    const int qd = lane >> 4, r = lane & 15;

    int lin = blockIdx.y * gridDim.x + blockIdx.x;
    int nwg = gridDim.x * gridDim.y;
    int cpx = nwg >> 3;
    int swz = (lin & 7) * cpx + (lin >> 3);
    int bm = (swz / gridDim.x) * 128;
    int bn = (swz % gridDim.x) * 128;

    const int srow = lane >> 2;
    const int scol = (lane & 3) * 8;
    const __hip_bfloat16* gA0 = A + (size_t)(bm + wave * 32 + srow) * lda + scol;
    const __hip_bfloat16* gA1 = gA0 + (size_t)16 * lda;
    const __hip_bfloat16* gB0 = Bt + (size_t)(bn + wave * 32 + srow) * ldbt + scol;
    const __hip_bfloat16* gB1 = gB0 + (size_t)16 * ldbt;

    f32x4 acc[4][4] = {};

    gload16(gA0, &As[0][wave * 1024]);
    gload16(gA1, &As[0][wave * 1024 + 512]);
    gload16(gB0, &Bs[0][wave * 1024]);
    gload16(gB1, &Bs[0][wave * 1024 + 512]);
    __syncthreads();

    int cur = 0;
    for (int k0 = 0; k0 < K; k0 += 32, cur ^= 1) {
        if (k0 + 32 < K) {
            int kn = k0 + 32, nb = cur ^ 1;
            gload16(gA0 + kn, &As[nb][wave * 1024]);
            gload16(gA1 + kn, &As[nb][wave * 1024 + 512]);
            gload16(gB0 + kn, &Bs[nb][wave * 1024]);
            gload16(gB1 + kn, &Bs[nb][wave * 1024 + 512]);
        }
        bf16x8 afr[4], bfr[4];
#pragma unroll
        for (int m = 0; m < 4; ++m)
            afr[m] = *(const bf16x8*)&As[cur][(wr * 64 + m * 16 + r) * 32 + qd * 8];
#pragma unroll
        for (int n = 0; n < 4; ++n)
            bfr[n] = *(const bf16x8*)&Bs[cur][(wc * 64 + n * 16 + r) * 32 + qd * 8];
#pragma unroll
        for (int m = 0; m < 4; ++m)
#pragma unroll
            for (int n = 0; n < 4; ++n)
                acc[m][n] = __builtin_amdgcn_mfma_f32_16x16x32_bf16(
                    afr[m], bfr[n], acc[m][n], 0, 0, 0);
        __syncthreads();
    }

#pragma unroll
    for (int m = 0; m < 4; ++m) {
        int row0 = bm + wr * 64 + m * 16 + qd * 4;
#pragma unroll
        for (int n = 0; n < 4; ++n) {
            int col = bn + wc * 64 + n * 16 + r;
            float bv = (flags & 1) ? bias[col] : 0.0f;
#pragma unroll
            for (int i = 0; i < 4; ++i) {
                float v = acc[m][n][i] + bv;
                if (flags & 2) v = fmaxf(v, 0.0f);
                size_t off = (size_t)(row0 + i) * N + col;
                if (flags & 4) v += Cf[off];
                if (flags & 8) Cb[off] = __float2bfloat16(v);
                else           Cf[off] = v;
            }
        }
    }
}

// ---------------------------------------------------------------------------
__global__ __launch_bounds__(256) void conv_bf16(const float* __restrict__ in,
                                                 __hip_bfloat16* __restrict__ out,
                                                 int n8)
{
    int i = blockIdx.x * 256 + threadIdx.x;
    if (i >= n8) return;
    const float4* p = (const float4*)(in + (size_t)i * 8);
    float4 v0 = p[0], v1 = p[1];
    __hip_bfloat16 o[8] = {
        __float2bfloat16(v0.x), __float2bfloat16(v0.y),
        __float2bfloat16(v0.z), __float2bfloat16(v0.w),
        __float2bfloat16(v1.x), __float2bfloat16(v1.y),
        __float2bfloat16(v1.z), __float2bfloat16(v1.w)};
    *(uint4*)(out + (size_t)i * 8) = *(const uint4*)o;
}

// ---------------------------------------------------------------------------
// All 6 weight transposes in one dispatch.
// ---------------------------------------------------------------------------
__global__ __launch_bounds__(256) void transp_all(
    const float* __restrict__ Wq, const float* __restrict__ Wo,
    const float* __restrict__ Wk, const float* __restrict__ Wv,
    const float* __restrict__ W1, const float* __restrict__ W2,
    __hip_bfloat16* __restrict__ Wqt, __hip_bfloat16* __restrict__ Wot,
    __hip_bfloat16* __restrict__ Wkt, __hip_bfloat16* __restrict__ Wvt,
    __hip_bfloat16* __restrict__ W1t, __hip_bfloat16* __restrict__ W2t)
{
    int tile = blockIdx.x;
    const float* W; __hip_bfloat16* Wt; int K, N;
    if (tile < 2304) {
        int w = tile / 576; tile -= w * 576;
        K = 768; N = 768;
        W  = (w == 0) ? Wq : (w == 1) ? Wo : (w == 2) ? Wk : Wv;
        Wt = (w == 0) ? Wqt : (w == 1) ? Wot : (w == 2) ? Wkt : Wvt;
    } else if (tile < 4608) { tile -= 2304; K = 768; N = 3072; W = W1; Wt = W1t; }
    else                    { tile -= 4608; K = 3072; N = 768; W = W2; Wt = W2t; }
    int ntx = N >> 5;
    int k0 = (tile / ntx) * 32, n0 = (tile % ntx) * 32;
    __shared__ float s[32][33];
    int tx = threadIdx.x & 31, ty = threadIdx.x >> 5;
#pragma unroll
    for (int i = 0; i < 4; ++i)
        s[ty + i * 8][tx] = W[(size_t)(k0 + ty + i * 8) * N + n0 + tx];
    __syncthreads();
#pragma unroll
    for (int i = 0; i < 4; ++i)
        Wt[(size_t)(n0 + ty + i * 8) * K + k0 + tx] =
            __float2bfloat16(s[tx][ty + i * 8]);
}

// ---------------------------------------------------------------------------
__global__ void gather_kernel(const float* __restrict__ prev,
                              const int* __restrict__ rand_idx,
                              __hip_bfloat16* __restrict__ Pselb,
                              int* __restrict__ sel)
{
    int j = blockIdx.x;
    int b = j >> 7, i = j & 127;
    int sv = (i < 64) ? i : rand_idx[b * G_ + (i - 64)];
    if (threadIdx.x == 0) sel[j] = sv;
    const float* src = prev + ((size_t)(b * S_ + sv)) * D_;
    __hip_bfloat16* dst = Pselb + (size_t)j * D_;
    for (int d = threadIdx.x; d < D_; d += blockDim.x)
        dst[d] = __float2bfloat16(src[d]);
}

// ---------------------------------------------------------------------------
// MFMA sparse attention
// ---------------------------------------------------------------------------
__global__ __launch_bounds__(256) void attn3_kernel(
    const u16* __restrict__ qb, const u16* __restrict__ kb,
    const u16* __restrict__ vb, const int* __restrict__ sel,
    u16* __restrict__ out)
{
    const int bh = blockIdx.y;
    const int b = bh / H_, h = bh % H_;
    const int s0 = blockIdx.x * 256;
    const int t = threadIdx.x;
    const int w = t >> 6, lane = t & 63;
    const int r = lane & 15, qd = lane >> 4;

    __shared__ u16 Vt[64][136];
    __shared__ u16 Plds[4][32][136];
    __shared__ int ssel[128];

    {
        int key0 = t >> 4;
        int d0 = (t & 15) * 4;
        for (int kk = key0; kk < 128; kk += 16) {
            ushort4 v = *(const ushort4*)(vb + (size_t)(b * 128 + kk) * D_ + h * 64 + d0);
            Vt[d0 + 0][kk] = v.x; Vt[d0 + 1][kk] = v.y;
            Vt[d0 + 2][kk] = v.z; Vt[d0 + 3][kk] = v.w;
        }
        if (t < 128) ssel[t] = sel[b * 128 + t];
    }
    __syncthreads();

    int selv[8];
#pragma unroll
    for (int n = 0; n < 8; ++n) selv[n] = ssel[n * 16 + r];

    for (int pass = 0; pass < 2; ++pass) {
        const int sbase = s0 + w * 64 + pass * 32;
        f32x4 accs[2][8] = {};

#pragma unroll
        for (int ks = 0; ks < 2; ++ks) {
            bf16x8 af[2];
#pragma unroll
            for (int m = 0; m < 2; ++m)
                af[m] = *(const bf16x8*)(qb + (size_t)(b * S_ + sbase + m * 16 + r) * D_ + h * 64 + ks * 32 + qd * 8);
#pragma unroll
            for (int n = 0; n < 8; ++n) {
                bf16x8 bfv = *(const bf16x8*)(kb + (size_t)(b * 128 + n * 16 + r) * D_ + h * 64 + ks * 32 + qd * 8);
#pragma unroll
                for (int m = 0; m < 2; ++m)
                    accs[m][n] = __builtin_amdgcn_mfma_f32_16x16x32_bf16(
                        af[m], bfv, accs[m][n], 0, 0, 0);
            }
        }

#pragma unroll
        for (int m = 0; m < 2; ++m) {
#pragma unroll
            for (int i = 0; i < 4; ++i) {
                int srow = sbase + m * 16 + qd * 4 + i;
                float pm = -3e38f;
#pragma unroll
                for (int n = 0; n < 8; ++n) {
                    float sc = accs[m][n][i] * 0.125f;
                    if (selv[n] > srow) sc = -1e9f;
                    accs[m][n][i] = sc;
                    pm = fmaxf(pm, sc);
                }
#pragma unroll
                for (int off = 1; off < 16; off <<= 1)
                    pm = fmaxf(pm, __shfl_xor(pm, off, 64));
                float ps = 0.f;
#pragma unroll
                for (int n = 0; n < 8; ++n) {
                    float e = __expf(accs[m][n][i] - pm);
                    accs[m][n][i] = e;
                    ps += e;
                }
#pragma unroll
                for (int off = 1; off < 16; off <<= 1)
                    ps += __shfl_xor(ps, off, 64);
                float inv = 1.0f / ps;
#pragma unroll
                for (int n = 0; n < 8; ++n)
                    accs[m][n][i] *= inv;
            }
        }

#pragma unroll
        for (int m = 0; m < 2; ++m)
#pragma unroll
            for (int n = 0; n < 8; ++n)
#pragma unroll
                for (int i = 0; i < 4; ++i) {
                    __hip_bfloat16 pb = __float2bfloat16(accs[m][n][i]);
                    Plds[w][m * 16 + qd * 4 + i][n * 16 + r] = *(u16*)&pb;
                }

        f32x4 acco[2][4] = {};
#pragma unroll
        for (int ks = 0; ks < 4; ++ks) {
            bf16x8 pa[2];
#pragma unroll
            for (int m = 0; m < 2; ++m)
                pa[m] = *(const bf16x8*)&Plds[w][m * 16 + r][ks * 32 + qd * 8];
#pragma unroll
            for (int nd = 0; nd < 4; ++nd) {
                bf16x8 bv = *(const bf16x8*)&Vt[nd * 16 + r][ks * 32 + qd * 8];
#pragma unroll
                for (int m = 0; m < 2; ++m)
                    acco[m][nd] = __builtin_amdgcn_mfma_f32_16x16x32_bf16(
                        pa[m], bv, acco[m][nd], 0, 0, 0);
            }
        }

#pragma unroll
        for (int m = 0; m < 2; ++m)
#pragma unroll
            for (int nd = 0; nd < 4; ++nd)
#pragma unroll
                for (int i = 0; i < 4; ++i) {
                    __hip_bfloat16 ob = __float2bfloat16(acco[m][nd][i]);
                    out[(size_t)(b * S_ + sbase + m * 16 + qd * 4 + i) * D_ + h * 64 + nd * 16 + r] = *(u16*)&ob;
                }
    }
}

// ---------------------------------------------------------------------------
// final LN: out[row] = LN(bf16 xa + bf16 xb)*g+beta. 192 threads, ushort4.
// ---------------------------------------------------------------------------
__global__ __launch_bounds__(192) void addln_bb(
    const u16* __restrict__ xa, const u16* __restrict__ xb,
    const float* __restrict__ g, const float* __restrict__ beta,
    float* __restrict__ out)
{
    const int row = blockIdx.x;
    const int t = threadIdx.x;
    const ushort4 a = ((const ushort4*)(xa + (size_t)row * D_))[t];
    const ushort4 b4 = ((const ushort4*)(xb + (size_t)row * D_))[t];
    float v[4] = {bfu2f(a.x) + bfu2f(b4.x), bfu2f(a.y) + bfu2f(b4.y),
                  bfu2f(a.z) + bfu2f(b4.z), bfu2f(a.w) + bfu2f(b4.w)};
    float sum = v[0] + v[1] + v[2] + v[3];
#pragma unroll
    for (int off = 1; off < 64; off <<= 1) sum += __shfl_xor(sum, off, 64);
    __shared__ float r1[3], r2[3];
    int wv = t >> 6, ln = t & 63;
    if (ln == 0) r1[wv] = sum;
    __syncthreads();
    float mean = (r1[0] + r1[1] + r1[2]) * (1.0f / 768.0f);
    float sq = 0.f;
#pragma unroll
    for (int i = 0; i < 4; ++i) { v[i] -= mean; sq += v[i] * v[i]; }
#pragma unroll
    for (int off = 1; off < 64; off <<= 1) sq += __shfl_xor(sq, off, 64);
    if (ln == 0) r2[wv] = sq;
    __syncthreads();
    float var = (r2[0] + r2[1] + r2[2]) * (1.0f / 768.0f);
    float rs = rsqrtf(var + 1e-5f);
    float4 gg = ((const float4*)g)[t];
    float4 bb = ((const float4*)beta)[t];
    float4 o;
    o.x = v[0] * rs * gg.x + bb.x;
    o.y = v[1] * rs * gg.y + bb.y;
    o.z = v[2] * rs * gg.z + bb.z;
    o.w = v[3] * rs * gg.w + bb.w;
    ((float4*)(out + (size_t)row * D_))[t] = o;
}

// ---------------------------------------------------------------------------
// Class-attention precompute
// ---------------------------------------------------------------------------
__global__ __launch_bounds__(256) void precompute_U(
    const float* __restrict__ Wqc, const float* __restrict__ Wkc,
    const float* __restrict__ bqc, float* __restrict__ Ut, float* __restrict__ ab)
{
    __shared__ __attribute__((aligned(16))) float wk[D_];
    for (int i = threadIdx.x; i < D_; i += 256) wk[i] = Wkc[i];
    __syncthreads();
    int idx = blockIdx.x * 256 + threadIdx.x;
    int h = idx / D_, d = idx - h * D_;
    const float4* row = (const float4*)(Wqc + (size_t)d * D_ + h * 64);
    const float4* wkv = (const float4*)(wk + h * 64);
    float a0 = 0.f, a1 = 0.f, a2 = 0.f, a3 = 0.f;
#pragma unroll
    for (int j = 0; j < 16; j += 4) {
        float4 r0 = row[j], r1 = row[j + 1], r2 = row[j + 2], r3 = row[j + 3];
        float4 c0 = wkv[j], c1 = wkv[j + 1], c2 = wkv[j + 2], c3 = wkv[j + 3];
        a0 += r0.x * c0.x + r0.y * c0.y + r0.z * c0.z + r0.w * c0.w;
        a1 += r1.x * c1.x + r1.y * c1.y + r1.z * c1.z + r1.w * c1.w;
        a2 += r2.x * c2.x + r2.y * c2.y + r2.z * c2.z + r2.w * c2.w;
        a3 += r3.x * c3.x + r3.y * c3.y + r3.z * c3.z + r3.w * c3.w;
    }
    Ut[idx] = (a0 + a1) + (a2 + a3);
    if (idx < H_) {
        const float4* bq4 = (const float4*)(bqc + idx * 64);
        const float4* wk4 = (const float4*)(wk + idx * 64);
        float s = 0.f;
#pragma unroll
        for (int j = 0; j < 16; ++j) {
            float4 bb = bq4[j], cc = wk4[j];
            s += bb.x * cc.x + bb.y * cc.y + bb.z * cc.z + bb.w * cc.w;
        }
        ab[idx] = s;
    }
}

__global__ __launch_bounds__(256) void precompute_mix(
    const float* __restrict__ Wvc, const float* __restrict__ Woc,
    float* __restrict__ Wmix)
{
    __shared__ float wv[D_];
    for (int i = threadIdx.x; i < D_; i += 256) wv[i] = Wvc[i];
    __syncthreads();
    int idx = blockIdx.x * 256 + threadIdx.x;
    int h = idx / D_, n = idx - h * D_;
    float acc[8] = {};
#pragma unroll
    for (int j = 0; j < 64; ++j)
        acc[j & 7] += wv[h * 64 + j] * Woc[(size_t)(h * 64 + j) * D_ + n];
    Wmix[idx] = ((acc[0] + acc[1]) + (acc[2] + acc[3]))
              + ((acc[4] + acc[5]) + (acc[6] + acc[7]));
}

__global__ __launch_bounds__(256) void precompute_bias2(
    const float* __restrict__ Woc, const float* __restrict__ bvc,
    const float* __restrict__ boc, float* __restrict__ bias2)
{
    int tx = threadIdx.x & 63, ty = threadIdx.x >> 6;
    int n = blockIdx.x * 64 + tx;
    int d0 = ty * 192;
    float a = 0.f;
#pragma unroll 8
    for (int d = 0; d < 192; ++d)
        a += bvc[d0 + d] * Woc[(size_t)(d0 + d) * D_ + n];
    __shared__ float red[4][64];
    red[ty][tx] = a;
    __syncthreads();
    if (ty == 0)
        bias2[n] = boc[n] + red[0][tx] + red[1][tx] + red[2][tx] + red[3][tx];
}

// ---------------------------------------------------------------------------
// Fused mid v4: oproj now bf16. x1=LN(cur+oproj); alpha; mu; x2 -> bf16 only.
// ---------------------------------------------------------------------------
__global__ __launch_bounds__(256) void fused_mid(
    const float* __restrict__ cur, const u16* __restrict__ oprojb,
    const float* __restrict__ g1, const float* __restrict__ b1,
    const float* __restrict__ Ut, const float* __restrict__ ab,
    const float* __restrict__ cvec,
    const float* __restrict__ Wmix, const float* __restrict__ bias2,
    const float* __restrict__ g2, const float* __restrict__ b2,
    __hip_bfloat16* __restrict__ x2b)
{
    const int w = threadIdx.x >> 6, lane = threadIdx.x & 63;
    const int row0 = blockIdx.x * 8 + w * 2;
    const int b = blockIdx.x >> 9;

    __shared__ float4 cvs[64];
    __shared__ float xp[4][64][28];
    __shared__ float muls[4][24];

    if (threadIdx.x < 64)
        cvs[threadIdx.x] = ((const float4*)(cvec + b * C_))[threadIdx.x];

    float4 x1[2][3];
#pragma unroll
    for (int rr = 0; rr < 2; ++rr) {
        const float4* pa = (const float4*)(cur + (size_t)(row0 + rr) * D_);
        const ushort4* pb = (const ushort4*)(oprojb + (size_t)(row0 + rr) * D_);
        float s = 0.f;
#pragma unroll
        for (int i = 0; i < 3; ++i) {
            float4 a = pa[i * 64 + lane];
            ushort4 ou = pb[i * 64 + lane];
            float4 v;
            v.x = a.x + bfu2f(ou.x); v.y = a.y + bfu2f(ou.y);
            v.z = a.z + bfu2f(ou.z); v.w = a.w + bfu2f(ou.w);
            x1[rr][i] = v;
            s += v.x + v.y + v.z + v.w;
        }
#pragma unroll
        for (int off = 1; off < 64; off <<= 1) s += __shfl_xor(s, off, 64);
        float mean = s * (1.0f / 768.0f);
        float sq = 0.f;
#pragma unroll
        for (int i = 0; i < 3; ++i) {
            x1[rr][i].x -= mean; x1[rr][i].y -= mean;
            x1[rr][i].z -= mean; x1[rr][i].w -= mean;
            sq += x1[rr][i].x * x1[rr][i].x + x1[rr][i].y * x1[rr][i].y
                + x1[rr][i].z * x1[rr][i].z + x1[rr][i].w * x1[rr][i].w;
        }
#pragma unroll
        for (int off = 1; off < 64; off <<= 1) sq += __shfl_xor(sq, off, 64);
        float rs = rsqrtf(sq * (1.0f / 768.0f) + 1e-5f);
#pragma unroll
        for (int i = 0; i < 3; ++i) {
            float4 gg = ((const float4*)g1)[i * 64 + lane];
            float4 bb = ((const float4*)b1)[i * 64 + lane];
            x1[rr][i].x = x1[rr][i].x * rs * gg.x + bb.x;
            x1[rr][i].y = x1[rr][i].y * rs * gg.y + bb.y;
            x1[rr][i].z = x1[rr][i].z * rs * gg.z + bb.z;
            x1[rr][i].w = x1[rr][i].w * rs * gg.w + bb.w;
        }
    }

    float acc[24];
#pragma unroll
    for (int j = 0; j < 24; ++j) acc[j] = 0.f;
#pragma unroll
    for (int i = 0; i < 3; ++i) {
#pragma unroll
        for (int h = 0; h < 12; ++h) {
            float4 u = ((const float4*)(Ut + (size_t)h * D_))[i * 64 + lane];
#pragma unroll
            for (int rr = 0; rr < 2; ++rr)
                acc[rr * 12 + h] += x1[rr][i].x * u.x + x1[rr][i].y * u.y
                                  + x1[rr][i].z * u.z + x1[rr][i].w * u.w;
        }
    }
#pragma unroll
    for (int j4 = 0; j4 < 6; ++j4)
        *(float4*)&xp[w][lane][j4 * 4] = *(float4*)&acc[j4 * 4];
    __syncthreads();

    if (lane < 48) {
        int j = lane >> 1, half = lane & 1;
        float ssum = 0.f;
#pragma unroll
        for (int k = 0; k < 32; ++k) ssum += xp[w][half * 32 + k][j];
        ssum += __shfl_xor(ssum, 1, 64);
        float a = 0.125f * (ssum + ab[j % 12]);
        float z = 0.f, ms = 0.f;
#pragma unroll
        for (int it = 0; it < 32; ++it) {
            float4 c = cvs[half * 32 + it];
            float e0 = __expf(a * c.x), e1 = __expf(a * c.y),
                  e2 = __expf(a * c.z), e3 = __expf(a * c.w);
            z += e0 + e1 + e2 + e3;
            ms += e0 * c.x + e1 * c.y + e2 * c.z + e3 * c.w;
        }
        z += __shfl_xor(z, 1, 64);
        ms += __shfl_xor(ms, 1, 64);
        if (half == 0) muls[w][j] = ms / z;
    }
    __syncthreads();

    float4 t2[2][3];
#pragma unroll
    for (int i = 0; i < 3; ++i) {
        float4 bv = ((const float4*)bias2)[i * 64 + lane];
        float4 o0 = bv, o1 = bv;
#pragma unroll
        for (int h = 0; h < 12; ++h) {
            float4 wm = ((const float4*)(Wmix + (size_t)h * D_))[i * 64 + lane];
            float m0 = muls[w][h], m1 = muls[w][12 + h];
            o0.x += m0 * wm.x; o0.y += m0 * wm.y; o0.z += m0 * wm.z; o0.w += m0 * wm.w;
            o1.x += m1 * wm.x; o1.y += m1 * wm.y; o1.z += m1 * wm.z; o1.w += m1 * wm.w;
        }
        t2[0][i].x = x1[0][i].x + o0.x; t2[0][i].y = x1[0][i].y + o0.y;
        t2[0][i].z = x1[0][i].z + o0.z; t2[0][i].w = x1[0][i].w + o0.w;
        t2[1][i].x = x1[1][i].x + o1.x; t2[1][i].y = x1[1][i].y + o1.y;
        t2[1][i].z = x1[1][i].z + o1.z; t2[1][i].w = x1[1][i].w + o1.w;
    }

#pragma unroll
    for (int rr = 0; rr < 2; ++rr) {
        float s = 0.f;
#pragma unroll
        for (int i = 0; i < 3; ++i)
            s += t2[rr][i].x + t2[rr][i].y + t2[rr][i].z + t2[rr][i].w;
#pragma unroll
        for (int off = 1; off < 64; off <<= 1) s += __shfl_xor(s, off, 64);
        float mean = s * (1.0f / 768.0f);
        float sq = 0.f;
#pragma unroll
        for (int i = 0; i < 3; ++i) {
            t2[rr][i].x -= mean; t2[rr][i].y -= mean;
            t2[rr][i].z -= mean; t2[rr][i].w -= mean;
            sq += t2[rr][i].x * t2[rr][i].x + t2[rr][i].y * t2[rr][i].y
                + t2[rr][i].z * t2[rr][i].z + t2[rr][i].w * t2[rr][i].w;
        }
#pragma unroll
        for (int off = 1; off < 64; off <<= 1) sq += __shfl_xor(sq, off, 64);
        float rs = rsqrtf(sq * (1.0f / 768.0f) + 1e-5f);
        size_t base = (size_t)(row0 + rr) * D_;
#pragma unroll
        for (int i = 0; i < 3; ++i) {
            float4 gg = ((const float4*)g2)[i * 64 + lane];
            float4 bb = ((const float4*)b2)[i * 64 + lane];
            float vx = t2[rr][i].x * rs * gg.x + bb.x;
            float vy = t2[rr][i].y * rs * gg.y + bb.y;
            float vz = t2[rr][i].z * rs * gg.z + bb.z;
            float vw = t2[rr][i].w * rs * gg.w + bb.w;
            __hip_bfloat16 pk[4] = {
                __float2bfloat16(vx), __float2bfloat16(vy),
                __float2bfloat16(vz), __float2bfloat16(vw)};
            *(uint2*)(x2b + base + i * 256 + lane * 4) = *(const uint2*)pk;
        }
    }
}

// ---------------------------------------------------------------------------
extern "C" void kernel_launch(void* const* d_in, const int* in_sizes, int n_in,
                              void* d_out, int out_size, void* d_ws, size_t ws_size,
                              hipStream_t stream) {
    const float* cur   = (const float*)d_in[0];
    const float* prev  = (const float*)d_in[1];
    const float* cvec  = (const float*)d_in[2];
    const int*   ridx  = (const int*)d_in[3];
    const float* Wq  = (const float*)d_in[4];
    const float* bq  = (const float*)d_in[5];
    const float* Wk  = (const float*)d_in[6];
    const float* bk  = (const float*)d_in[7];
    const float* Wv  = (const float*)d_in[8];
    const float* bv  = (const float*)d_in[9];
    const float* Wo  = (const float*)d_in[10];
    const float* bo  = (const float*)d_in[11];
    const float* g1  = (const float*)d_in[12];
    const float* b1  = (const float*)d_in[13];
    const float* Wqc = (const float*)d_in[14];
    const float* bqc = (const float*)d_in[15];
    const float* Wkc = (const float*)d_in[16];
    const float* bkc = (const float*)d_in[17];  (void)bkc;
    const float* Wvc = (const float*)d_in[18];
    const float* bvc = (const float*)d_in[19];
    const float* Woc = (const float*)d_in[20];
    const float* boc = (const float*)d_in[21];
    const float* g2  = (const float*)d_in[22];
    const float* b2  = (const float*)d_in[23];
    const float* W1  = (const float*)d_in[24];
    const float* bf1 = (const float*)d_in[25];
    const float* W2  = (const float*)d_in[26];
    const float* bf2 = (const float*)d_in[27];
    const float* g3  = (const float*)d_in[28];
    const float* b3  = (const float*)d_in[29];
    float* outp = (float*)d_out;
    (void)ws_size; (void)in_sizes; (void)n_in; (void)out_size;

    const int M = B_ * S_;                       // 16384
    const size_t NBSD = (size_t)M * D_;          // 12,582,912
    const size_t NSEL = (size_t)B_ * 128 * D_;   // 393,216

    // workspace (all bf16 first, floats after; every offset even)
    __hip_bfloat16* hidb  = (__hip_bfloat16*)d_ws;          // M x FF (100.7 MB)
    __hip_bfloat16* bf0   = hidb + (size_t)M * FF_;         // cur_bf -> attn_out -> x2
    __hip_bfloat16* tmpb  = bf0 + NBSD;                     // q -> oproj -> ff
    __hip_bfloat16* Pselb = tmpb + NBSD;
    __hip_bfloat16* kselb = Pselb + NSEL;
    __hip_bfloat16* vselb = kselb + NSEL;
    __hip_bfloat16* Wqt   = vselb + NSEL;
    __hip_bfloat16* Wot   = Wqt + (size_t)D_ * D_;
    __hip_bfloat16* Wkt   = Wot + (size_t)D_ * D_;
    __hip_bfloat16* Wvt   = Wkt + (size_t)D_ * D_;
    __hip_bfloat16* W1t   = Wvt + (size_t)D_ * D_;          // FF x D
    __hip_bfloat16* W2t   = W1t + (size_t)D_ * FF_;         // D x FF
    float* Ub    = (float*)(W2t + (size_t)FF_ * D_);
    float* abv   = Ub + (size_t)D_ * H_;
    float* Wmix  = abv + 16;
    float* bias2 = Wmix + (size_t)H_ * D_;
    int*   selb  = (int*)(bias2 + D_);

    // 1) gather (bf16) + transposes + convert + class-attn precomputes
    gather_kernel<<<B_ * 128, 256, 0, stream>>>(prev, ridx, Pselb, selb);
    transp_all<<<6912, 256, 0, stream>>>(Wq, Wo, Wk, Wv, W1, W2,
                                         Wqt, Wot, Wkt, Wvt, W1t, W2t);
    conv_bf16<<<(int)(NBSD / 8 + 255) / 256, 256, 0, stream>>>(cur, bf0, (int)(NBSD / 8));
    precompute_U<<<36, 256, 0, stream>>>(Wqc, Wkc, bqc, Ub, abv);
    precompute_mix<<<36, 256, 0, stream>>>(Wvc, Woc, Wmix);
    precompute_bias2<<<12, 256, 0, stream>>>(Woc, bvc, boc, bias2);

    // 2) ksel/vsel projections (bf16 out)
    {
        dim3 g(D_ / 128, (B_ * 128) / 128);
        gemm_mfma<<<g, 256, 0, stream>>>(Pselb, Wkt, bk, nullptr, kselb,
                                         B_ * 128, D_, D_, D_, D_, 1 | 8);
        gemm_mfma<<<g, 256, 0, stream>>>(Pselb, Wvt, bv, nullptr, vselb,
                                         B_ * 128, D_, D_, D_, D_, 1 | 8);
    }

    // 3) q = cur @ Wq + bq -> tmpb (bf16)
    gemm_mfma<<<dim3(D_ / 128, M / 128), 256, 0, stream>>>(
        bf0, Wqt, bq, nullptr, tmpb, M, D_, D_, D_, D_, 1 | 8);

    // 4) MFMA sparse attention -> bf0 (bf16; cur_bf dead)
    attn3_kernel<<<dim3(S_ / 256, B_ * H_), 256, 0, stream>>>(
        (const u16*)tmpb, (const u16*)kselb, (const u16*)vselb, selb, (u16*)bf0);

    // 5) oproj = attn_out @ Wo + bo -> tmpb (bf16; q dead)
    gemm_mfma<<<dim3(D_ / 128, M / 128), 256, 0, stream>>>(
        bf0, Wot, bo, nullptr, tmpb, M, D_, D_, D_, D_, 1 | 8);

    // 6) fused mid: x1, class-attn, x2 -> bf0 (bf16; attn_out dead)
    fused_mid<<<M / 8, 256, 0, stream>>>(
        cur, (const u16*)tmpb, g1, b1, Ub, abv, cvec, Wmix, bias2, g2, b2, bf0);

    // 7) FF full-width: hid = relu(x2@W1+bf1) -> hidb; ff = hid@W2+bf2 -> tmpb
    gemm_mfma<<<dim3(FF_ / 128, M / 128), 256, 0, stream>>>(
        bf0, W1t, bf1, nullptr, hidb, M, FF_, D_, D_, D_, 1 | 2 | 8);
    gemm_mfma<<<dim3(D_ / 128, M / 128), 256, 0, stream>>>(
        hidb, W2t, bf2, nullptr, tmpb, M, D_, FF_, FF_, FF_, 1 | 8);

    // 8) out = LN(x2 + ff)
    addln_bb<<<M, 192, 0, stream>>>((const u16*)bf0, (const u16*)tmpb, g3, b3, outp);
}

// Round 8
// 450.559 us; speedup vs baseline: 12.9847x; 1.0332x over previous
//
#include <hip/hip_runtime.h>
#include <hip/hip_bf16.h>

#define B_ 4
#define S_ 4096
#define D_ 768
#define H_ 12
#define DH_ 64
#define G_ 64
#define C_ 256
#define FF_ 3072

typedef __attribute__((ext_vector_type(8))) short bf16x8;
typedef __attribute__((ext_vector_type(4))) float f32x4;
typedef unsigned short u16;

__device__ __forceinline__ float bfu2f(u16 u) {
    return __uint_as_float((unsigned)u << 16);
}

// ---------------------------------------------------------------------------
// async global->LDS 16B (wave-uniform LDS base + lane*16)
// ---------------------------------------------------------------------------
__device__ __forceinline__ void gload16(const __hip_bfloat16* g, __hip_bfloat16* l) {
    __builtin_amdgcn_global_load_lds(
        (__attribute__((address_space(1))) void*)(void*)const_cast<__hip_bfloat16*>(g),
        (__attribute__((address_space(3))) void*)(void*)l,
        16, 0, 0);
}

// ---------------------------------------------------------------------------
// gemm256: 256x256 tile, BK=64, 512 threads (8 waves 2Mx4N), dbuf LDS 128KB,
// counted-vmcnt pipeline (never vmcnt(0) in steady state), T2 source-swizzle
// (linear gload_lds dest + XOR'd source col; reads XOR (r&7) -> 2-way free).
// A: MxK bf16 (lda=K), Bt: NxK bf16 (ldbt=K). Out: bf16 Cb (ldc=N).
// flags: 1=bias, 2=relu. Requires M%256==0, N%256==0, K%64==0, nwg%8==0.
// ---------------------------------------------------------------------------
__global__ __launch_bounds__(512) void gemm256(
    const u16* __restrict__ A, const u16* __restrict__ Bt,
    const float* __restrict__ bias, u16* __restrict__ Cb,
    int M, int N, int K, int flags)
{
    __shared__ __attribute__((aligned(16))) u16 As[2][256 * 64];
    __shared__ __attribute__((aligned(16))) u16 Bs[2][256 * 64];

    const int tid = threadIdx.x;
    const int lane = tid & 63, w = tid >> 6;
    const int wm = w >> 2, wn = w & 3;          // 2 x 4 wave grid
    const int r = lane & 15, qd = lane >> 4;

    // bijective XCD swizzle (nwg % 8 == 0)
    int lin = blockIdx.y * gridDim.x + blockIdx.x;
    int nwg = gridDim.x * gridDim.y;
    int cpx = nwg >> 3;
    int swz = (lin & 7) * cpx + (lin >> 3);
    int bm = (swz / gridDim.x) * 256;
    int bn = (swz % gridDim.x) * 256;

    // staging: load l covers rows [l*64, l*64+64); thread -> (row, swz'd col)
    const int srow = w * 8 + (lane >> 3);               // + l*64
    const int scol = ((lane & 7) ^ (lane >> 3)) * 8;    // inverse-swizzled src
    const int sdst = w * 512;                            // elem off; +l*4096

#define STAGE256(c, k0)                                                        \
    {                                                                          \
        _Pragma("unroll")                                                      \
        for (int l = 0; l < 4; ++l)                                            \
            gload16((const __hip_bfloat16*)(A + (size_t)(bm + srow + l * 64) * K + (k0) + scol), \
                    (__hip_bfloat16*)&As[c][l * 4096 + sdst]);                 \
        _Pragma("unroll")                                                      \
        for (int l = 0; l < 4; ++l)                                            \
            gload16((const __hip_bfloat16*)(Bt + (size_t)(bn + srow + l * 64) * K + (k0) + scol), \
                    (__hip_bfloat16*)&Bs[c][l * 4096 + sdst]);                 \
    }

    f32x4 acc[8][4] = {};
    const int NT = K >> 6;

    STAGE256(0, 0)
    STAGE256(1, 64)
    asm volatile("s_waitcnt vmcnt(8)" ::: "memory");   // KT0 landed (all 8)
    __builtin_amdgcn_s_barrier();

    for (int kt = 0; kt < NT; ++kt) {
        const int c = kt & 1;
        const u16* as = As[c];
        const u16* bs = Bs[c];
#pragma unroll
        for (int kk = 0; kk < 2; ++kk) {
            bf16x8 af[8], bfv[4];
#pragma unroll
            for (int m = 0; m < 8; ++m) {
                int row = wm * 128 + m * 16 + r;
                af[m] = *(const bf16x8*)&as[row * 64 + (((kk << 2) + qd) ^ (r & 7)) * 8];
            }
#pragma unroll
            for (int n = 0; n < 4; ++n) {
                int row = wn * 64 + n * 16 + r;
                bfv[n] = *(const bf16x8*)&bs[row * 64 + (((kk << 2) + qd) ^ (r & 7)) * 8];
            }
            __builtin_amdgcn_s_setprio(1);
#pragma unroll
            for (int m = 0; m < 8; ++m)
#pragma unroll
                for (int n = 0; n < 4; ++n)
                    acc[m][n] = __builtin_amdgcn_mfma_f32_16x16x32_bf16(
                        af[m], bfv[n], acc[m][n], 0, 0, 0);
            __builtin_amdgcn_s_setprio(0);
        }
        asm volatile("s_waitcnt lgkmcnt(0)" ::: "memory");
        __builtin_amdgcn_s_barrier();                  // all reads of buf[c] done
        if (kt + 2 < NT) STAGE256(c, (kt + 2) << 6)    // overwrite buf[c] safely
        if (kt + 1 < NT) {
            if (kt + 2 < NT) asm volatile("s_waitcnt vmcnt(8)" ::: "memory");
            else             asm volatile("s_waitcnt vmcnt(0)" ::: "memory");
            __builtin_amdgcn_s_barrier();              // buf[c^1] staged everywhere
        }
    }

#pragma unroll
    for (int m = 0; m < 8; ++m) {
        int row0 = bm + wm * 128 + m * 16 + qd * 4;
#pragma unroll
        for (int n = 0; n < 4; ++n) {
            int col = bn + wn * 64 + n * 16 + r;
            float bv = (flags & 1) ? bias[col] : 0.0f;
#pragma unroll
            for (int i = 0; i < 4; ++i) {
                float v = acc[m][n][i] + bv;
                if (flags & 2) v = fmaxf(v, 0.0f);
                __hip_bfloat16 ob = __float2bfloat16(v);
                Cb[(size_t)(row0 + i) * N + col] = *(u16*)&ob;
            }
        }
    }
#undef STAGE256
}

// ---------------------------------------------------------------------------
// bf16 MFMA GEMM 128x128 (small shapes: ksel/vsel). flags: 1=bias, 8=bf16 out
// ---------------------------------------------------------------------------
__global__ __launch_bounds__(256) void gemm_mfma(
    const __hip_bfloat16* __restrict__ A, const __hip_bfloat16* __restrict__ Bt,
    const float* __restrict__ bias, float* __restrict__ Cf,
    __hip_bfloat16* __restrict__ Cb,
    int M, int N, int K, int lda, int ldbt, int flags)
{
    __shared__ __hip_bfloat16 As[2][128 * 32];
    __shared__ __hip_bfloat16 Bs[2][128 * 32];

    const int t = threadIdx.x;
    const int lane = t & 63;
    const int wave = t >> 6;
    const int wr = wave >> 1, wc = wave & 1;
    const int qd = lane >> 4, r = lane & 15;

    int lin = blockIdx.y * gridDim.x + blockIdx.x;
    int nwg = gridDim.x * gridDim.y;
    int cpx = nwg >> 3;
    int swz = (lin & 7) * cpx + (lin >> 3);
    int bm = (swz / gridDim.x) * 128;
    int bn = (swz % gridDim.x) * 128;

    const int srow = lane >> 2;
    const int scol = (lane & 3) * 8;
    const __hip_bfloat16* gA0 = A + (size_t)(bm + wave * 32 + srow) * lda + scol;
    const __hip_bfloat16* gA1 = gA0 + (size_t)16 * lda;
    const __hip_bfloat16* gB0 = Bt + (size_t)(bn + wave * 32 + srow) * ldbt + scol;
    const __hip_bfloat16* gB1 = gB0 + (size_t)16 * ldbt;

    f32x4 acc[4][4] = {};

    gload16(gA0, &As[0][wave * 1024]);
    gload16(gA1, &As[0][wave * 1024 + 512]);
    gload16(gB0, &Bs[0][wave * 1024]);
    gload16(gB1, &Bs[0][wave * 1024 + 512]);
    __syncthreads();

    int cur = 0;
    for (int k0 = 0; k0 < K; k0 += 32, cur ^= 1) {
        if (k0 + 32 < K) {
            int kn = k0 + 32, nb = cur ^ 1;
            gload16(gA0 + kn, &As[nb][wave * 1024]);
            gload16(gA1 + kn, &As[nb][wave * 1024 + 512]);
            gload16(gB0 + kn, &Bs[nb][wave * 1024]);
            gload16(gB1 + kn, &Bs[nb][wave * 1024 + 512]);
        }
        bf16x8 afr[4], bfr[4];
#pragma unroll
        for (int m = 0; m < 4; ++m)
            afr[m] = *(const bf16x8*)&As[cur][(wr * 64 + m * 16 + r) * 32 + qd * 8];
#pragma unroll
        for (int n = 0; n < 4; ++n)
            bfr[n] = *(const bf16x8*)&Bs[cur][(wc * 64 + n * 16 + r) * 32 + qd * 8];
#pragma unroll
        for (int m = 0; m < 4; ++m)
#pragma unroll
            for (int n = 0; n < 4; ++n)
                acc[m][n] = __builtin_amdgcn_mfma_f32_16x16x32_bf16(
                    afr[m], bfr[n], acc[m][n], 0, 0, 0);
        __syncthreads();
    }

#pragma unroll
    for (int m = 0; m < 4; ++m) {
        int row0 = bm + wr * 64 + m * 16 + qd * 4;
#pragma unroll
        for (int n = 0; n < 4; ++n) {
            int col = bn + wc * 64 + n * 16 + r;
            float bv = (flags & 1) ? bias[col] : 0.0f;
#pragma unroll
            for (int i = 0; i < 4; ++i) {
                float v = acc[m][n][i] + bv;
                if (flags & 2) v = fmaxf(v, 0.0f);
                size_t off = (size_t)(row0 + i) * N + col;
                if (flags & 4) v += Cf[off];
                if (flags & 8) Cb[off] = __float2bfloat16(v);
                else           Cf[off] = v;
            }
        }
    }
}

// ---------------------------------------------------------------------------
__global__ __launch_bounds__(256) void conv_bf16(const float* __restrict__ in,
                                                 __hip_bfloat16* __restrict__ out,
                                                 int n8)
{
    int i = blockIdx.x * 256 + threadIdx.x;
    if (i >= n8) return;
    const float4* p = (const float4*)(in + (size_t)i * 8);
    float4 v0 = p[0], v1 = p[1];
    __hip_bfloat16 o[8] = {
        __float2bfloat16(v0.x), __float2bfloat16(v0.y),
        __float2bfloat16(v0.z), __float2bfloat16(v0.w),
        __float2bfloat16(v1.x), __float2bfloat16(v1.y),
        __float2bfloat16(v1.z), __float2bfloat16(v1.w)};
    *(uint4*)(out + (size_t)i * 8) = *(const uint4*)o;
}

// ---------------------------------------------------------------------------
// All 6 weight transposes in one dispatch.
// ---------------------------------------------------------------------------
__global__ __launch_bounds__(256) void transp_all(
    const float* __restrict__ Wq, const float* __restrict__ Wo,
    const float* __restrict__ Wk, const float* __restrict__ Wv,
    const float* __restrict__ W1, const float* __restrict__ W2,
    __hip_bfloat16* __restrict__ Wqt, __hip_bfloat16* __restrict__ Wot,
    __hip_bfloat16* __restrict__ Wkt, __hip_bfloat16* __restrict__ Wvt,
    __hip_bfloat16* __restrict__ W1t, __hip_bfloat16* __restrict__ W2t)
{
    int tile = blockIdx.x;
    const float* W; __hip_bfloat16* Wt; int K, N;
    if (tile < 2304) {
        int w = tile / 576; tile -= w * 576;
        K = 768; N = 768;
        W  = (w == 0) ? Wq : (w == 1) ? Wo : (w == 2) ? Wk : Wv;
        Wt = (w == 0) ? Wqt : (w == 1) ? Wot : (w == 2) ? Wkt : Wvt;
    } else if (tile < 4608) { tile -= 2304; K = 768; N = 3072; W = W1; Wt = W1t; }
    else                    { tile -= 4608; K = 3072; N = 768; W = W2; Wt = W2t; }
    int ntx = N >> 5;
    int k0 = (tile / ntx) * 32, n0 = (tile % ntx) * 32;
    __shared__ float s[32][33];
    int tx = threadIdx.x & 31, ty = threadIdx.x >> 5;
#pragma unroll
    for (int i = 0; i < 4; ++i)
        s[ty + i * 8][tx] = W[(size_t)(k0 + ty + i * 8) * N + n0 + tx];
    __syncthreads();
#pragma unroll
    for (int i = 0; i < 4; ++i)
        Wt[(size_t)(n0 + ty + i * 8) * K + k0 + tx] =
            __float2bfloat16(s[tx][ty + i * 8]);
}

// ---------------------------------------------------------------------------
__global__ void gather_kernel(const float* __restrict__ prev,
                              const int* __restrict__ rand_idx,
                              __hip_bfloat16* __restrict__ Pselb,
                              int* __restrict__ sel)
{
    int j = blockIdx.x;
    int b = j >> 7, i = j & 127;
    int sv = (i < 64) ? i : rand_idx[b * G_ + (i - 64)];
    if (threadIdx.x == 0) sel[j] = sv;
    const float* src = prev + ((size_t)(b * S_ + sv)) * D_;
    __hip_bfloat16* dst = Pselb + (size_t)j * D_;
    for (int d = threadIdx.x; d < D_; d += blockDim.x)
        dst[d] = __float2bfloat16(src[d]);
}

// ---------------------------------------------------------------------------
// MFMA sparse attention
// ---------------------------------------------------------------------------
__global__ __launch_bounds__(256) void attn3_kernel(
    const u16* __restrict__ qb, const u16* __restrict__ kb,
    const u16* __restrict__ vb, const int* __restrict__ sel,
    u16* __restrict__ out)
{
    const int bh = blockIdx.y;
    const int b = bh / H_, h = bh % H_;
    const int s0 = blockIdx.x * 256;
    const int t = threadIdx.x;
    const int w = t >> 6, lane = t & 63;
    const int r = lane & 15, qd = lane >> 4;

    __shared__ u16 Vt[64][136];
    __shared__ u16 Plds[4][32][136];
    __shared__ int ssel[128];

    {
        int key0 = t >> 4;
        int d0 = (t & 15) * 4;
        for (int kk = key0; kk < 128; kk += 16) {
            ushort4 v = *(const ushort4*)(vb + (size_t)(b * 128 + kk) * D_ + h * 64 + d0);
            Vt[d0 + 0][kk] = v.x; Vt[d0 + 1][kk] = v.y;
            Vt[d0 + 2][kk] = v.z; Vt[d0 + 3][kk] = v.w;
        }
        if (t < 128) ssel[t] = sel[b * 128 + t];
    }
    __syncthreads();

    int selv[8];
#pragma unroll
    for (int n = 0; n < 8; ++n) selv[n] = ssel[n * 16 + r];

    for (int pass = 0; pass < 2; ++pass) {
        const int sbase = s0 + w * 64 + pass * 32;
        f32x4 accs[2][8] = {};

#pragma unroll
        for (int ks = 0; ks < 2; ++ks) {
            bf16x8 af[2];
#pragma unroll
            for (int m = 0; m < 2; ++m)
                af[m] = *(const bf16x8*)(qb + (size_t)(b * S_ + sbase + m * 16 + r) * D_ + h * 64 + ks * 32 + qd * 8);
#pragma unroll
            for (int n = 0; n < 8; ++n) {
                bf16x8 bfv = *(const bf16x8*)(kb + (size_t)(b * 128 + n * 16 + r) * D_ + h * 64 + ks * 32 + qd * 8);
#pragma unroll
                for (int m = 0; m < 2; ++m)
                    accs[m][n] = __builtin_amdgcn_mfma_f32_16x16x32_bf16(
                        af[m], bfv, accs[m][n], 0, 0, 0);
            }
        }

#pragma unroll
        for (int m = 0; m < 2; ++m) {
#pragma unroll
            for (int i = 0; i < 4; ++i) {
                int srow = sbase + m * 16 + qd * 4 + i;
                float pm = -3e38f;
#pragma unroll
                for (int n = 0; n < 8; ++n) {
                    float sc = accs[m][n][i] * 0.125f;
                    if (selv[n] > srow) sc = -1e9f;
                    accs[m][n][i] = sc;
                    pm = fmaxf(pm, sc);
                }
#pragma unroll
                for (int off = 1; off < 16; off <<= 1)
                    pm = fmaxf(pm, __shfl_xor(pm, off, 64));
                float ps = 0.f;
#pragma unroll
                for (int n = 0; n < 8; ++n) {
                    float e = __expf(accs[m][n][i] - pm);
                    accs[m][n][i] = e;
                    ps += e;
                }
#pragma unroll
                for (int off = 1; off < 16; off <<= 1)
                    ps += __shfl_xor(ps, off, 64);
                float inv = 1.0f / ps;
#pragma unroll
                for (int n = 0; n < 8; ++n)
                    accs[m][n][i] *= inv;
            }
        }

#pragma unroll
        for (int m = 0; m < 2; ++m)
#pragma unroll
            for (int n = 0; n < 8; ++n)
#pragma unroll
                for (int i = 0; i < 4; ++i) {
                    __hip_bfloat16 pb = __float2bfloat16(accs[m][n][i]);
                    Plds[w][m * 16 + qd * 4 + i][n * 16 + r] = *(u16*)&pb;
                }

        f32x4 acco[2][4] = {};
#pragma unroll
        for (int ks = 0; ks < 4; ++ks) {
            bf16x8 pa[2];
#pragma unroll
            for (int m = 0; m < 2; ++m)
                pa[m] = *(const bf16x8*)&Plds[w][m * 16 + r][ks * 32 + qd * 8];
#pragma unroll
            for (int nd = 0; nd < 4; ++nd) {
                bf16x8 bv = *(const bf16x8*)&Vt[nd * 16 + r][ks * 32 + qd * 8];
#pragma unroll
                for (int m = 0; m < 2; ++m)
                    acco[m][nd] = __builtin_amdgcn_mfma_f32_16x16x32_bf16(
                        pa[m], bv, acco[m][nd], 0, 0, 0);
            }
        }

#pragma unroll
        for (int m = 0; m < 2; ++m)
#pragma unroll
            for (int nd = 0; nd < 4; ++nd)
#pragma unroll
                for (int i = 0; i < 4; ++i) {
                    __hip_bfloat16 ob = __float2bfloat16(acco[m][nd][i]);
                    out[(size_t)(b * S_ + sbase + m * 16 + qd * 4 + i) * D_ + h * 64 + nd * 16 + r] = *(u16*)&ob;
                }
    }
}

// ---------------------------------------------------------------------------
// final LN: out[row] = LN(bf16 xa + bf16 xb)*g+beta. 192 threads, ushort4.
// ---------------------------------------------------------------------------
__global__ __launch_bounds__(192) void addln_bb(
    const u16* __restrict__ xa, const u16* __restrict__ xb,
    const float* __restrict__ g, const float* __restrict__ beta,
    float* __restrict__ out)
{
    const int row = blockIdx.x;
    const int t = threadIdx.x;
    const ushort4 a = ((const ushort4*)(xa + (size_t)row * D_))[t];
    const ushort4 b4 = ((const ushort4*)(xb + (size_t)row * D_))[t];
    float v[4] = {bfu2f(a.x) + bfu2f(b4.x), bfu2f(a.y) + bfu2f(b4.y),
                  bfu2f(a.z) + bfu2f(b4.z), bfu2f(a.w) + bfu2f(b4.w)};
    float sum = v[0] + v[1] + v[2] + v[3];
#pragma unroll
    for (int off = 1; off < 64; off <<= 1) sum += __shfl_xor(sum, off, 64);
    __shared__ float r1[3], r2[3];
    int wv = t >> 6, ln = t & 63;
    if (ln == 0) r1[wv] = sum;
    __syncthreads();
    float mean = (r1[0] + r1[1] + r1[2]) * (1.0f / 768.0f);
    float sq = 0.f;
#pragma unroll
    for (int i = 0; i < 4; ++i) { v[i] -= mean; sq += v[i] * v[i]; }
#pragma unroll
    for (int off = 1; off < 64; off <<= 1) sq += __shfl_xor(sq, off, 64);
    if (ln == 0) r2[wv] = sq;
    __syncthreads();
    float var = (r2[0] + r2[1] + r2[2]) * (1.0f / 768.0f);
    float rs = rsqrtf(var + 1e-5f);
    float4 gg = ((const float4*)g)[t];
    float4 bb = ((const float4*)beta)[t];
    float4 o;
    o.x = v[0] * rs * gg.x + bb.x;
    o.y = v[1] * rs * gg.y + bb.y;
    o.z = v[2] * rs * gg.z + bb.z;
    o.w = v[3] * rs * gg.w + bb.w;
    ((float4*)(out + (size_t)row * D_))[t] = o;
}

// ---------------------------------------------------------------------------
// Class-attention precompute
// ---------------------------------------------------------------------------
__global__ __launch_bounds__(256) void precompute_U(
    const float* __restrict__ Wqc, const float* __restrict__ Wkc,
    const float* __restrict__ bqc, float* __restrict__ Ut, float* __restrict__ ab)
{
    __shared__ __attribute__((aligned(16))) float wk[D_];
    for (int i = threadIdx.x; i < D_; i += 256) wk[i] = Wkc[i];
    __syncthreads();
    int idx = blockIdx.x * 256 + threadIdx.x;
    int h = idx / D_, d = idx - h * D_;
    const float4* row = (const float4*)(Wqc + (size_t)d * D_ + h * 64);
    const float4* wkv = (const float4*)(wk + h * 64);
    float a0 = 0.f, a1 = 0.f, a2 = 0.f, a3 = 0.f;
#pragma unroll
    for (int j = 0; j < 16; j += 4) {
        float4 r0 = row[j], r1 = row[j + 1], r2 = row[j + 2], r3 = row[j + 3];
        float4 c0 = wkv[j], c1 = wkv[j + 1], c2 = wkv[j + 2], c3 = wkv[j + 3];
        a0 += r0.x * c0.x + r0.y * c0.y + r0.z * c0.z + r0.w * c0.w;
        a1 += r1.x * c1.x + r1.y * c1.y + r1.z * c1.z + r1.w * c1.w;
        a2 += r2.x * c2.x + r2.y * c2.y + r2.z * c2.z + r2.w * c2.w;
        a3 += r3.x * c3.x + r3.y * c3.y + r3.z * c3.z + r3.w * c3.w;
    }
    Ut[idx] = (a0 + a1) + (a2 + a3);
    if (idx < H_) {
        const float4* bq4 = (const float4*)(bqc + idx * 64);
        const float4* wk4 = (const float4*)(wk + idx * 64);
        float s = 0.f;
#pragma unroll
        for (int j = 0; j < 16; ++j) {
            float4 bb = bq4[j], cc = wk4[j];
            s += bb.x * cc.x + bb.y * cc.y + bb.z * cc.z + bb.w * cc.w;
        }
        ab[idx] = s;
    }
}

__global__ __launch_bounds__(256) void precompute_mix(
    const float* __restrict__ Wvc, const float* __restrict__ Woc,
    float* __restrict__ Wmix)
{
    __shared__ float wv[D_];
    for (int i = threadIdx.x; i < D_; i += 256) wv[i] = Wvc[i];
    __syncthreads();
    int idx = blockIdx.x * 256 + threadIdx.x;
    int h = idx / D_, n = idx - h * D_;
    float acc[8] = {};
#pragma unroll
    for (int j = 0; j < 64; ++j)
        acc[j & 7] += wv[h * 64 + j] * Woc[(size_t)(h * 64 + j) * D_ + n];
    Wmix[idx] = ((acc[0] + acc[1]) + (acc[2] + acc[3]))
              + ((acc[4] + acc[5]) + (acc[6] + acc[7]));
}

__global__ __launch_bounds__(256) void precompute_bias2(
    const float* __restrict__ Woc, const float* __restrict__ bvc,
    const float* __restrict__ boc, float* __restrict__ bias2)
{
    int tx = threadIdx.x & 63, ty = threadIdx.x >> 6;
    int n = blockIdx.x * 64 + tx;
    int d0 = ty * 192;
    float a = 0.f;
#pragma unroll 8
    for (int d = 0; d < 192; ++d)
        a += bvc[d0 + d] * Woc[(size_t)(d0 + d) * D_ + n];
    __shared__ float red[4][64];
    red[ty][tx] = a;
    __syncthreads();
    if (ty == 0)
        bias2[n] = boc[n] + red[0][tx] + red[1][tx] + red[2][tx] + red[3][tx];
}

// ---------------------------------------------------------------------------
// Fused mid: x1=LN(cur+oproj_bf16); alpha; mu; x2=LN(x1+bias2+mu@Wmix) -> bf16
// ---------------------------------------------------------------------------
__global__ __launch_bounds__(256) void fused_mid(
    const float* __restrict__ cur, const u16* __restrict__ oprojb,
    const float* __restrict__ g1, const float* __restrict__ b1,
    const float* __restrict__ Ut, const float* __restrict__ ab,
    const float* __restrict__ cvec,
    const float* __restrict__ Wmix, const float* __restrict__ bias2,
    const float* __restrict__ g2, const float* __restrict__ b2,
    __hip_bfloat16* __restrict__ x2b)
{
    const int w = threadIdx.x >> 6, lane = threadIdx.x & 63;
    const int row0 = blockIdx.x * 8 + w * 2;
    const int b = blockIdx.x >> 9;

    __shared__ float4 cvs[64];
    __shared__ float xp[4][64][28];
    __shared__ float muls[4][24];

    if (threadIdx.x < 64)
        cvs[threadIdx.x] = ((const float4*)(cvec + b * C_))[threadIdx.x];

    float4 x1[2][3];
#pragma unroll
    for (int rr = 0; rr < 2; ++rr) {
        const float4* pa = (const float4*)(cur + (size_t)(row0 + rr) * D_);
        const ushort4* pb = (const ushort4*)(oprojb + (size_t)(row0 + rr) * D_);
        float s = 0.f;
#pragma unroll
        for (int i = 0; i < 3; ++i) {
            float4 a = pa[i * 64 + lane];
            ushort4 ou = pb[i * 64 + lane];
            float4 v;
            v.x = a.x + bfu2f(ou.x); v.y = a.y + bfu2f(ou.y);
            v.z = a.z + bfu2f(ou.z); v.w = a.w + bfu2f(ou.w);
            x1[rr][i] = v;
            s += v.x + v.y + v.z + v.w;
        }
#pragma unroll
        for (int off = 1; off < 64; off <<= 1) s += __shfl_xor(s, off, 64);
        float mean = s * (1.0f / 768.0f);
        float sq = 0.f;
#pragma unroll
        for (int i = 0; i < 3; ++i) {
            x1[rr][i].x -= mean; x1[rr][i].y -= mean;
            x1[rr][i].z -= mean; x1[rr][i].w -= mean;
            sq += x1[rr][i].x * x1[rr][i].x + x1[rr][i].y * x1[rr][i].y
                + x1[rr][i].z * x1[rr][i].z + x1[rr][i].w * x1[rr][i].w;
        }
#pragma unroll
        for (int off = 1; off < 64; off <<= 1) sq += __shfl_xor(sq, off, 64);
        float rs = rsqrtf(sq * (1.0f / 768.0f) + 1e-5f);
#pragma unroll
        for (int i = 0; i < 3; ++i) {
            float4 gg = ((const float4*)g1)[i * 64 + lane];
            float4 bb = ((const float4*)b1)[i * 64 + lane];
            x1[rr][i].x = x1[rr][i].x * rs * gg.x + bb.x;
            x1[rr][i].y = x1[rr][i].y * rs * gg.y + bb.y;
            x1[rr][i].z = x1[rr][i].z * rs * gg.z + bb.z;
            x1[rr][i].w = x1[rr][i].w * rs * gg.w + bb.w;
        }
    }

    float acc[24];
#pragma unroll
    for (int j = 0; j < 24; ++j) acc[j] = 0.f;
#pragma unroll
    for (int i = 0; i < 3; ++i) {
#pragma unroll
        for (int h = 0; h < 12; ++h) {
            float4 u = ((const float4*)(Ut + (size_t)h * D_))[i * 64 + lane];
#pragma unroll
            for (int rr = 0; rr < 2; ++rr)
                acc[rr * 12 + h] += x1[rr][i].x * u.x + x1[rr][i].y * u.y
                                  + x1[rr][i].z * u.z + x1[rr][i].w * u.w;
        }
    }
#pragma unroll
    for (int j4 = 0; j4 < 6; ++j4)
        *(float4*)&xp[w][lane][j4 * 4] = *(float4*)&acc[j4 * 4];
    __syncthreads();

    if (lane < 48) {
        int j = lane >> 1, half = lane & 1;
        float ssum = 0.f;
#pragma unroll
        for (int k = 0; k < 32; ++k) ssum += xp[w][half * 32 + k][j];
        ssum += __shfl_xor(ssum, 1, 64);
        float a = 0.125f * (ssum + ab[j % 12]);
        float z = 0.f, ms = 0.f;
#pragma unroll
        for (int it = 0; it < 32; ++it) {
            float4 c = cvs[half * 32 + it];
            float e0 = __expf(a * c.x), e1 = __expf(a * c.y),
                  e2 = __expf(a * c.z), e3 = __expf(a * c.w);
            z += e0 + e1 + e2 + e3;
            ms += e0 * c.x + e1 * c.y + e2 * c.z + e3 * c.w;
        }
        z += __shfl_xor(z, 1, 64);
        ms += __shfl_xor(ms, 1, 64);
        if (half == 0) muls[w][j] = ms / z;
    }
    __syncthreads();

    float4 t2[2][3];
#pragma unroll
    for (int i = 0; i < 3; ++i) {
        float4 bv = ((const float4*)bias2)[i * 64 + lane];
        float4 o0 = bv, o1 = bv;
#pragma unroll
        for (int h = 0; h < 12; ++h) {
            float4 wm = ((const float4*)(Wmix + (size_t)h * D_))[i * 64 + lane];
            float m0 = muls[w][h], m1 = muls[w][12 + h];
            o0.x += m0 * wm.x; o0.y += m0 * wm.y; o0.z += m0 * wm.z; o0.w += m0 * wm.w;
            o1.x += m1 * wm.x; o1.y += m1 * wm.y; o1.z += m1 * wm.z; o1.w += m1 * wm.w;
        }
        t2[0][i].x = x1[0][i].x + o0.x; t2[0][i].y = x1[0][i].y + o0.y;
        t2[0][i].z = x1[0][i].z + o0.z; t2[0][i].w = x1[0][i].w + o0.w;
        t2[1][i].x = x1[1][i].x + o1.x; t2[1][i].y = x1[1][i].y + o1.y;
        t2[1][i].z = x1[1][i].z + o1.z; t2[1][i].w = x1[1][i].w + o1.w;
    }

#pragma unroll
    for (int rr = 0; rr < 2; ++rr) {
        float s = 0.f;
#pragma unroll
        for (int i = 0; i < 3; ++i)
            s += t2[rr][i].x + t2[rr][i].y + t2[rr][i].z + t2[rr][i].w;
#pragma unroll
        for (int off = 1; off < 64; off <<= 1) s += __shfl_xor(s, off, 64);
        float mean = s * (1.0f / 768.0f);
        float sq = 0.f;
#pragma unroll
        for (int i = 0; i < 3; ++i) {
            t2[rr][i].x -= mean; t2[rr][i].y -= mean;
            t2[rr][i].z -= mean; t2[rr][i].w -= mean;
            sq += t2[rr][i].x * t2[rr][i].x + t2[rr][i].y * t2[rr][i].y
                + t2[rr][i].z * t2[rr][i].z + t2[rr][i].w * t2[rr][i].w;
        }
#pragma unroll
        for (int off = 1; off < 64; off <<= 1) sq += __shfl_xor(sq, off, 64);
        float rs = rsqrtf(sq * (1.0f / 768.0f) + 1e-5f);
        size_t base = (size_t)(row0 + rr) * D_;
#pragma unroll
        for (int i = 0; i < 3; ++i) {
            float4 gg = ((const float4*)g2)[i * 64 + lane];
            float4 bb = ((const float4*)b2)[i * 64 + lane];
            float vx = t2[rr][i].x * rs * gg.x + bb.x;
            float vy = t2[rr][i].y * rs * gg.y + bb.y;
            float vz = t2[rr][i].z * rs * gg.z + bb.z;
            float vw = t2[rr][i].w * rs * gg.w + bb.w;
            __hip_bfloat16 pk[4] = {
                __float2bfloat16(vx), __float2bfloat16(vy),
                __float2bfloat16(vz), __float2bfloat16(vw)};
            *(uint2*)(x2b + base + i * 256 + lane * 4) = *(const uint2*)pk;
        }
    }
}

// ---------------------------------------------------------------------------
extern "C" void kernel_launch(void* const* d_in, const int* in_sizes, int n_in,
                              void* d_out, int out_size, void* d_ws, size_t ws_size,
                              hipStream_t stream) {
    const float* cur   = (const float*)d_in[0];
    const float* prev  = (const float*)d_in[1];
    const float* cvec  = (const float*)d_in[2];
    const int*   ridx  = (const int*)d_in[3];
    const float* Wq  = (const float*)d_in[4];
    const float* bq  = (const float*)d_in[5];
    const float* Wk  = (const float*)d_in[6];
    const float* bk  = (const float*)d_in[7];
    const float* Wv  = (const float*)d_in[8];
    const float* bv  = (const float*)d_in[9];
    const float* Wo  = (const float*)d_in[10];
    const float* bo  = (const float*)d_in[11];
    const float* g1  = (const float*)d_in[12];
    const float* b1  = (const float*)d_in[13];
    const float* Wqc = (const float*)d_in[14];
    const float* bqc = (const float*)d_in[15];
    const float* Wkc = (const float*)d_in[16];
    const float* bkc = (const float*)d_in[17];  (void)bkc;
    const float* Wvc = (const float*)d_in[18];
    const float* bvc = (const float*)d_in[19];
    const float* Woc = (const float*)d_in[20];
    const float* boc = (const float*)d_in[21];
    const float* g2  = (const float*)d_in[22];
    const float* b2  = (const float*)d_in[23];
    const float* W1  = (const float*)d_in[24];
    const float* bf1 = (const float*)d_in[25];
    const float* W2  = (const float*)d_in[26];
    const float* bf2 = (const float*)d_in[27];
    const float* g3  = (const float*)d_in[28];
    const float* b3  = (const float*)d_in[29];
    float* outp = (float*)d_out;
    (void)ws_size; (void)in_sizes; (void)n_in; (void)out_size;

    const int M = B_ * S_;                       // 16384
    const size_t NBSD = (size_t)M * D_;          // 12,582,912
    const size_t NSEL = (size_t)B_ * 128 * D_;   // 393,216

    __hip_bfloat16* hidb  = (__hip_bfloat16*)d_ws;          // M x FF
    __hip_bfloat16* bf0   = hidb + (size_t)M * FF_;         // cur_bf -> attn_out -> x2
    __hip_bfloat16* tmpb  = bf0 + NBSD;                     // q -> oproj -> ff
    __hip_bfloat16* Pselb = tmpb + NBSD;
    __hip_bfloat16* kselb = Pselb + NSEL;
    __hip_bfloat16* vselb = kselb + NSEL;
    __hip_bfloat16* Wqt   = vselb + NSEL;
    __hip_bfloat16* Wot   = Wqt + (size_t)D_ * D_;
    __hip_bfloat16* Wkt   = Wot + (size_t)D_ * D_;
    __hip_bfloat16* Wvt   = Wkt + (size_t)D_ * D_;
    __hip_bfloat16* W1t   = Wvt + (size_t)D_ * D_;          // FF x D
    __hip_bfloat16* W2t   = W1t + (size_t)D_ * FF_;         // D x FF
    float* Ub    = (float*)(W2t + (size_t)FF_ * D_);
    float* abv   = Ub + (size_t)D_ * H_;
    float* Wmix  = abv + 16;
    float* bias2 = Wmix + (size_t)H_ * D_;
    int*   selb  = (int*)(bias2 + D_);

    // 1) gather (bf16) + transposes + convert + class-attn precomputes
    gather_kernel<<<B_ * 128, 256, 0, stream>>>(prev, ridx, Pselb, selb);
    transp_all<<<6912, 256, 0, stream>>>(Wq, Wo, Wk, Wv, W1, W2,
                                         Wqt, Wot, Wkt, Wvt, W1t, W2t);
    conv_bf16<<<(int)(NBSD / 8 + 255) / 256, 256, 0, stream>>>(cur, bf0, (int)(NBSD / 8));
    precompute_U<<<36, 256, 0, stream>>>(Wqc, Wkc, bqc, Ub, abv);
    precompute_mix<<<36, 256, 0, stream>>>(Wvc, Woc, Wmix);
    precompute_bias2<<<12, 256, 0, stream>>>(Woc, bvc, boc, bias2);

    // 2) ksel/vsel projections (small; 128^2 kernel)
    {
        dim3 g(D_ / 128, (B_ * 128) / 128);
        gemm_mfma<<<g, 256, 0, stream>>>(Pselb, Wkt, bk, nullptr, kselb,
                                         B_ * 128, D_, D_, D_, D_, 1 | 8);
        gemm_mfma<<<g, 256, 0, stream>>>(Pselb, Wvt, bv, nullptr, vselb,
                                         B_ * 128, D_, D_, D_, D_, 1 | 8);
    }

    // 3) q = cur @ Wq + bq -> tmpb (bf16)   [256^2 pipelined]
    gemm256<<<dim3(D_ / 256, M / 256), 512, 0, stream>>>(
        (const u16*)bf0, (const u16*)Wqt, bq, (u16*)tmpb, M, D_, D_, 1);

    // 4) MFMA sparse attention -> bf0 (bf16; cur_bf dead)
    attn3_kernel<<<dim3(S_ / 256, B_ * H_), 256, 0, stream>>>(
        (const u16*)tmpb, (const u16*)kselb, (const u16*)vselb, selb, (u16*)bf0);

    // 5) oproj = attn_out @ Wo + bo -> tmpb (bf16; q dead)
    gemm256<<<dim3(D_ / 256, M / 256), 512, 0, stream>>>(
        (const u16*)bf0, (const u16*)Wot, bo, (u16*)tmpb, M, D_, D_, 1);

    // 6) fused mid: x1, class-attn, x2 -> bf0 (bf16; attn_out dead)
    fused_mid<<<M / 8, 256, 0, stream>>>(
        cur, (const u16*)tmpb, g1, b1, Ub, abv, cvec, Wmix, bias2, g2, b2, bf0);

    // 7) FF full-width: hid = relu(x2@W1+bf1) -> hidb; ff = hid@W2+bf2 -> tmpb
    gemm256<<<dim3(FF_ / 256, M / 256), 512, 0, stream>>>(
        (const u16*)bf0, (const u16*)W1t, bf1, (u16*)hidb, M, FF_, D_, 1 | 2);
    gemm256<<<dim3(D_ / 256, M / 256), 512, 0, stream>>>(
        (const u16*)hidb, (const u16*)W2t, bf2, (u16*)tmpb, M, D_, FF_, 1);

    // 8) out = LN(x2 + ff)
    addln_bb<<<M, 192, 0, stream>>>((const u16*)bf0, (const u16*)tmpb, g3, b3, outp);
}

// Round 9
// 438.342 us; speedup vs baseline: 13.3465x; 1.0279x over previous
//
#include <hip/hip_runtime.h>
#include <hip/hip_bf16.h>

#define B_ 4
#define S_ 4096
#define D_ 768
#define H_ 12
#define DH_ 64
#define G_ 64
#define C_ 256
#define FF_ 3072

typedef __attribute__((ext_vector_type(8))) short bf16x8;
typedef __attribute__((ext_vector_type(4))) float f32x4;
typedef unsigned short u16;

__device__ __forceinline__ float bfu2f(u16 u) {
    return __uint_as_float((unsigned)u << 16);
}

// ---------------------------------------------------------------------------
// async global->LDS 16B (wave-uniform LDS base + lane*16)
// ---------------------------------------------------------------------------
__device__ __forceinline__ void gload16(const __hip_bfloat16* g, __hip_bfloat16* l) {
    __builtin_amdgcn_global_load_lds(
        (__attribute__((address_space(1))) void*)(void*)const_cast<__hip_bfloat16*>(g),
        (__attribute__((address_space(3))) void*)(void*)l,
        16, 0, 0);
}

// ---------------------------------------------------------------------------
// gemm256 — 8-phase schedule (m201 template): 256x256 tile, BK=64, 8 waves
// (2Mx4N), LDS 2buf x {Ah0,Ah1,Bh0,Bh1} x 16KB = 128KB. Per K-tile: 4
// quadrant-phases x 16 MFMA; 1 half-tile staged per phase; vmcnt(4) gates at
// phases 4/8 only. T2 source-swizzle (XOR granules), T5 setprio, T1 XCD swz.
// A: MxK bf16, Bt: NxK bf16. Out bf16. flags: 1=bias, 2=relu.
// M%256==0, N%256==0, K%128==0, nwg%8==0.
// ---------------------------------------------------------------------------
__global__ __launch_bounds__(512, 2) void gemm256(
    const u16* __restrict__ A, const u16* __restrict__ Bt,
    const float* __restrict__ bias, u16* __restrict__ Cb,
    int M, int N, int K, int flags)
{
    __shared__ __attribute__((aligned(16))) u16 Ah[2][2][128 * 64];
    __shared__ __attribute__((aligned(16))) u16 Bh[2][2][128 * 64];

    const int tid = threadIdx.x;
    const int lane = tid & 63, w = tid >> 6;
    const int wm = w >> 2, wn = w & 3;          // 2 x 4 wave grid
    const int r = lane & 15, qd = lane >> 4;

    // bijective XCD swizzle (nwg % 8 == 0)
    int lin = blockIdx.y * gridDim.x + blockIdx.x;
    int nwg = gridDim.x * gridDim.y;
    int cpx = nwg >> 3;
    int swz = (lin & 7) * cpx + (lin >> 3);
    int bm = (swz / gridDim.x) * 256;
    int bn = (swz % gridDim.x) * 256;

    // staging map: thread t covers rows (t>>3) and (t>>3)+64 of a 128x64 half
    const int srow = tid >> 3;                       // 0..63
    const int scol = ((tid & 7) ^ (srow & 7)) * 8;   // inverse-swizzled source
    const int sdst = tid * 8;                        // linear LDS elem offset

#define STG_A(c, h, kt) { \
    const u16* s_ = A + (size_t)(bm + (h) * 128 + srow) * K + ((kt) << 6) + scol; \
    gload16((const __hip_bfloat16*)s_, (__hip_bfloat16*)&Ah[c][h][sdst]); \
    gload16((const __hip_bfloat16*)(s_ + (size_t)64 * K), (__hip_bfloat16*)&Ah[c][h][sdst + 4096]); }
#define STG_B(c, h, kt) { \
    const u16* s_ = Bt + (size_t)(bn + (h) * 128 + srow) * K + ((kt) << 6) + scol; \
    gload16((const __hip_bfloat16*)s_, (__hip_bfloat16*)&Bh[c][h][sdst]); \
    gload16((const __hip_bfloat16*)(s_ + (size_t)64 * K), (__hip_bfloat16*)&Bh[c][h][sdst + 4096]); }

#define GRAN(kk) (((((kk) << 2) + qd) ^ (r & 7)) * 8)
#define READS_AF(c, mb) { \
    _Pragma("unroll") for (int m = 0; m < 4; ++m) { \
        const u16* p_ = &Ah[c][wm][((mb + m) * 16 + r) * 64]; \
        af[m][0] = *(const bf16x8*)(p_ + GRAN(0)); \
        af[m][1] = *(const bf16x8*)(p_ + GRAN(1)); } }
#define READS_BF(dst, c, nb) { \
    _Pragma("unroll") for (int n = 0; n < 2; ++n) { \
        const u16* p_ = &Bh[c][wn >> 1][((wn & 1) * 64 + (nb + n) * 16 + r) * 64]; \
        dst[n][0] = *(const bf16x8*)(p_ + GRAN(0)); \
        dst[n][1] = *(const bf16x8*)(p_ + GRAN(1)); } }
#define QMFMA(mb, nb, bfx) { \
    __builtin_amdgcn_s_setprio(1); \
    _Pragma("unroll") for (int kk = 0; kk < 2; ++kk) \
    _Pragma("unroll") for (int m = 0; m < 4; ++m) \
    _Pragma("unroll") for (int n = 0; n < 2; ++n) \
        acc[mb + m][nb + n] = __builtin_amdgcn_mfma_f32_16x16x32_bf16( \
            af[m][kk], bfx[n][kk], acc[mb + m][nb + n], 0, 0, 0); \
    __builtin_amdgcn_s_setprio(0); }
#define BAR() __builtin_amdgcn_s_barrier()
#define LGKM0() asm volatile("s_waitcnt lgkmcnt(0)" ::: "memory")

    f32x4 acc[8][4] = {};
    const int NT = K >> 6;
    const int J = NT >> 1;

    // prologue: tile0 -> buf0 (all 4 halves); tile1 -> buf1 (B halves only;
    // A halves of tile1 staged at ph1/ph2 of iteration 0)
    STG_A(0, 0, 0) STG_A(0, 1, 0) STG_B(0, 0, 0) STG_B(0, 1, 0)
    STG_B(1, 0, 1) STG_B(1, 1, 1)
    asm volatile("s_waitcnt vmcnt(4)" ::: "memory");   // tile0 landed
    BAR();

    bf16x8 af[4][2], bf0[2][2], bf1[2][2];

    for (int j = 0; j < J; ++j) {
        const int to1 = 2 * j + 1;      // odd tile of this iteration
        const int te2 = 2 * j + 2;      // prefetch even tile
        const int to3 = 2 * j + 3;      // prefetch odd tile
        const bool pf = (j < J - 1);

        // ---- ph1: read af0+bf0 (buf0); stage Ah0[buf1] <- tile 2j+1
        READS_AF(0, 0) READS_BF(bf0, 0, 0)
        STG_A(1, 0, to1)
        BAR(); LGKM0();
        QMFMA(0, 0, bf0)
        BAR();
        // ---- ph2: read bf1 (buf0); stage Ah1[buf1] <- tile 2j+1
        READS_BF(bf1, 0, 2)
        STG_A(1, 1, to1)
        BAR(); LGKM0();
        QMFMA(0, 2, bf1)
        BAR();
        // ---- ph3: read af1 (buf0); stage Bh0[buf0] <- tile 2j+2
        READS_AF(0, 4)
        if (pf) { STG_B(0, 0, te2) }
        BAR(); LGKM0();
        QMFMA(4, 2, bf1)
        BAR();
        // ---- ph4: stage Bh1[buf0] <- 2j+2; vmcnt gate for buf1 reads
        if (pf) { STG_B(0, 1, te2) }
        BAR();
        QMFMA(4, 0, bf0)
        if (pf) asm volatile("s_waitcnt vmcnt(4)" ::: "memory");
        else    asm volatile("s_waitcnt vmcnt(0)" ::: "memory");
        BAR();
        // ---- ph5: read af0+bf0 (buf1); stage Ah0[buf0] <- 2j+2
        READS_AF(1, 0) READS_BF(bf0, 1, 0)
        if (pf) { STG_A(0, 0, te2) }
        BAR(); LGKM0();
        QMFMA(0, 0, bf0)
        BAR();
        // ---- ph6: read bf1 (buf1); stage Ah1[buf0] <- 2j+2
        READS_BF(bf1, 1, 2)
        if (pf) { STG_A(0, 1, te2) }
        BAR(); LGKM0();
        QMFMA(0, 2, bf1)
        BAR();
        // ---- ph7: read af1 (buf1); stage Bh0[buf1] <- 2j+3
        READS_AF(1, 4)
        if (pf) { STG_B(1, 0, to3) }
        BAR(); LGKM0();
        QMFMA(4, 2, bf1)
        BAR();
        // ---- ph8: stage Bh1[buf1] <- 2j+3; vmcnt gate for next buf0 reads
        if (pf) { STG_B(1, 1, to3) }
        BAR();
        QMFMA(4, 0, bf0)
        if (pf) {
            asm volatile("s_waitcnt vmcnt(4)" ::: "memory");
            BAR();
        }
    }

#pragma unroll
    for (int m = 0; m < 8; ++m) {
        int row0 = bm + wm * 128 + m * 16 + qd * 4;
#pragma unroll
        for (int n = 0; n < 4; ++n) {
            int col = bn + wn * 64 + n * 16 + r;
            float bv = (flags & 1) ? bias[col] : 0.0f;
#pragma unroll
            for (int i = 0; i < 4; ++i) {
                float v = acc[m][n][i] + bv;
                if (flags & 2) v = fmaxf(v, 0.0f);
                __hip_bfloat16 ob = __float2bfloat16(v);
                Cb[(size_t)(row0 + i) * N + col] = *(u16*)&ob;
            }
        }
    }
#undef STG_A
#undef STG_B
#undef GRAN
#undef READS_AF
#undef READS_BF
#undef QMFMA
#undef BAR
#undef LGKM0
}

// ---------------------------------------------------------------------------
// bf16 MFMA GEMM 128x128 (small shapes: ksel/vsel). flags: 1=bias, 8=bf16 out
// ---------------------------------------------------------------------------
__global__ __launch_bounds__(256) void gemm_mfma(
    const __hip_bfloat16* __restrict__ A, const __hip_bfloat16* __restrict__ Bt,
    const float* __restrict__ bias, float* __restrict__ Cf,
    __hip_bfloat16* __restrict__ Cb,
    int M, int N, int K, int lda, int ldbt, int flags)
{
    __shared__ __hip_bfloat16 As[2][128 * 32];
    __shared__ __hip_bfloat16 Bs[2][128 * 32];

    const int t = threadIdx.x;
    const int lane = t & 63;
    const int wave = t >> 6;
    const int wr = wave >> 1, wc = wave & 1;
    const int qd = lane >> 4, r = lane & 15;

    int lin = blockIdx.y * gridDim.x + blockIdx.x;
    int nwg = gridDim.x * gridDim.y;
    int cpx = nwg >> 3;
    int swz = (lin & 7) * cpx + (lin >> 3);
    int bm = (swz / gridDim.x) * 128;
    int bn = (swz % gridDim.x) * 128;

    const int srow = lane >> 2;
    const int scol = (lane & 3) * 8;
    const __hip_bfloat16* gA0 = A + (size_t)(bm + wave * 32 + srow) * lda + scol;
    const __hip_bfloat16* gA1 = gA0 + (size_t)16 * lda;
    const __hip_bfloat16* gB0 = Bt + (size_t)(bn + wave * 32 + srow) * ldbt + scol;
    const __hip_bfloat16* gB1 = gB0 + (size_t)16 * ldbt;

    f32x4 acc[4][4] = {};

    gload16(gA0, &As[0][wave * 1024]);
    gload16(gA1, &As[0][wave * 1024 + 512]);
    gload16(gB0, &Bs[0][wave * 1024]);
    gload16(gB1, &Bs[0][wave * 1024 + 512]);
    __syncthreads();

    int cur = 0;
    for (int k0 = 0; k0 < K; k0 += 32, cur ^= 1) {
        if (k0 + 32 < K) {
            int kn = k0 + 32, nb = cur ^ 1;
            gload16(gA0 + kn, &As[nb][wave * 1024]);
            gload16(gA1 + kn, &As[nb][wave * 1024 + 512]);
            gload16(gB0 + kn, &Bs[nb][wave * 1024]);
            gload16(gB1 + kn, &Bs[nb][wave * 1024 + 512]);
        }
        bf16x8 afr[4], bfr[4];
#pragma unroll
        for (int m = 0; m < 4; ++m)
            afr[m] = *(const bf16x8*)&As[cur][(wr * 64 + m * 16 + r) * 32 + qd * 8];
#pragma unroll
        for (int n = 0; n < 4; ++n)
            bfr[n] = *(const bf16x8*)&Bs[cur][(wc * 64 + n * 16 + r) * 32 + qd * 8];
#pragma unroll
        for (int m = 0; m < 4; ++m)
#pragma unroll
            for (int n = 0; n < 4; ++n)
                acc[m][n] = __builtin_amdgcn_mfma_f32_16x16x32_bf16(
                    afr[m], bfr[n], acc[m][n], 0, 0, 0);
        __syncthreads();
    }

#pragma unroll
    for (int m = 0; m < 4; ++m) {
        int row0 = bm + wr * 64 + m * 16 + qd * 4;
#pragma unroll
        for (int n = 0; n < 4; ++n) {
            int col = bn + wc * 64 + n * 16 + r;
            float bv = (flags & 1) ? bias[col] : 0.0f;
#pragma unroll
            for (int i = 0; i < 4; ++i) {
                float v = acc[m][n][i] + bv;
                if (flags & 2) v = fmaxf(v, 0.0f);
                size_t off = (size_t)(row0 + i) * N + col;
                if (flags & 4) v += Cf[off];
                if (flags & 8) Cb[off] = __float2bfloat16(v);
                else           Cf[off] = v;
            }
        }
    }
}

// ---------------------------------------------------------------------------
__global__ __launch_bounds__(256) void conv_bf16(const float* __restrict__ in,
                                                 __hip_bfloat16* __restrict__ out,
                                                 int n8)
{
    int i = blockIdx.x * 256 + threadIdx.x;
    if (i >= n8) return;
    const float4* p = (const float4*)(in + (size_t)i * 8);
    float4 v0 = p[0], v1 = p[1];
    __hip_bfloat16 o[8] = {
        __float2bfloat16(v0.x), __float2bfloat16(v0.y),
        __float2bfloat16(v0.z), __float2bfloat16(v0.w),
        __float2bfloat16(v1.x), __float2bfloat16(v1.y),
        __float2bfloat16(v1.z), __float2bfloat16(v1.w)};
    *(uint4*)(out + (size_t)i * 8) = *(const uint4*)o;
}

// ---------------------------------------------------------------------------
// All 6 weight transposes in one dispatch.
// ---------------------------------------------------------------------------
__global__ __launch_bounds__(256) void transp_all(
    const float* __restrict__ Wq, const float* __restrict__ Wo,
    const float* __restrict__ Wk, const float* __restrict__ Wv,
    const float* __restrict__ W1, const float* __restrict__ W2,
    __hip_bfloat16* __restrict__ Wqt, __hip_bfloat16* __restrict__ Wot,
    __hip_bfloat16* __restrict__ Wkt, __hip_bfloat16* __restrict__ Wvt,
    __hip_bfloat16* __restrict__ W1t, __hip_bfloat16* __restrict__ W2t)
{
    int tile = blockIdx.x;
    const float* W; __hip_bfloat16* Wt; int K, N;
    if (tile < 2304) {
        int w = tile / 576; tile -= w * 576;
        K = 768; N = 768;
        W  = (w == 0) ? Wq : (w == 1) ? Wo : (w == 2) ? Wk : Wv;
        Wt = (w == 0) ? Wqt : (w == 1) ? Wot : (w == 2) ? Wkt : Wvt;
    } else if (tile < 4608) { tile -= 2304; K = 768; N = 3072; W = W1; Wt = W1t; }
    else                    { tile -= 4608; K = 3072; N = 768; W = W2; Wt = W2t; }
    int ntx = N >> 5;
    int k0 = (tile / ntx) * 32, n0 = (tile % ntx) * 32;
    __shared__ float s[32][33];
    int tx = threadIdx.x & 31, ty = threadIdx.x >> 5;
#pragma unroll
    for (int i = 0; i < 4; ++i)
        s[ty + i * 8][tx] = W[(size_t)(k0 + ty + i * 8) * N + n0 + tx];
    __syncthreads();
#pragma unroll
    for (int i = 0; i < 4; ++i)
        Wt[(size_t)(n0 + ty + i * 8) * K + k0 + tx] =
            __float2bfloat16(s[tx][ty + i * 8]);
}

// ---------------------------------------------------------------------------
__global__ void gather_kernel(const float* __restrict__ prev,
                              const int* __restrict__ rand_idx,
                              __hip_bfloat16* __restrict__ Pselb,
                              int* __restrict__ sel)
{
    int j = blockIdx.x;
    int b = j >> 7, i = j & 127;
    int sv = (i < 64) ? i : rand_idx[b * G_ + (i - 64)];
    if (threadIdx.x == 0) sel[j] = sv;
    const float* src = prev + ((size_t)(b * S_ + sv)) * D_;
    __hip_bfloat16* dst = Pselb + (size_t)j * D_;
    for (int d = threadIdx.x; d < D_; d += blockDim.x)
        dst[d] = __float2bfloat16(src[d]);
}

// ---------------------------------------------------------------------------
// MFMA sparse attention
// ---------------------------------------------------------------------------
__global__ __launch_bounds__(256) void attn3_kernel(
    const u16* __restrict__ qb, const u16* __restrict__ kb,
    const u16* __restrict__ vb, const int* __restrict__ sel,
    u16* __restrict__ out)
{
    const int bh = blockIdx.y;
    const int b = bh / H_, h = bh % H_;
    const int s0 = blockIdx.x * 256;
    const int t = threadIdx.x;
    const int w = t >> 6, lane = t & 63;
    const int r = lane & 15, qd = lane >> 4;

    __shared__ u16 Vt[64][136];
    __shared__ u16 Plds[4][32][136];
    __shared__ int ssel[128];

    {
        int key0 = t >> 4;
        int d0 = (t & 15) * 4;
        for (int kk = key0; kk < 128; kk += 16) {
            ushort4 v = *(const ushort4*)(vb + (size_t)(b * 128 + kk) * D_ + h * 64 + d0);
            Vt[d0 + 0][kk] = v.x; Vt[d0 + 1][kk] = v.y;
            Vt[d0 + 2][kk] = v.z; Vt[d0 + 3][kk] = v.w;
        }
        if (t < 128) ssel[t] = sel[b * 128 + t];
    }
    __syncthreads();

    int selv[8];
#pragma unroll
    for (int n = 0; n < 8; ++n) selv[n] = ssel[n * 16 + r];

    for (int pass = 0; pass < 2; ++pass) {
        const int sbase = s0 + w * 64 + pass * 32;
        f32x4 accs[2][8] = {};

#pragma unroll
        for (int ks = 0; ks < 2; ++ks) {
            bf16x8 af[2];
#pragma unroll
            for (int m = 0; m < 2; ++m)
                af[m] = *(const bf16x8*)(qb + (size_t)(b * S_ + sbase + m * 16 + r) * D_ + h * 64 + ks * 32 + qd * 8);
#pragma unroll
            for (int n = 0; n < 8; ++n) {
                bf16x8 bfv = *(const bf16x8*)(kb + (size_t)(b * 128 + n * 16 + r) * D_ + h * 64 + ks * 32 + qd * 8);
#pragma unroll
                for (int m = 0; m < 2; ++m)
                    accs[m][n] = __builtin_amdgcn_mfma_f32_16x16x32_bf16(
                        af[m], bfv, accs[m][n], 0, 0, 0);
            }
        }

#pragma unroll
        for (int m = 0; m < 2; ++m) {
#pragma unroll
            for (int i = 0; i < 4; ++i) {
                int srow = sbase + m * 16 + qd * 4 + i;
                float pm = -3e38f;
#pragma unroll
                for (int n = 0; n < 8; ++n) {
                    float sc = accs[m][n][i] * 0.125f;
                    if (selv[n] > srow) sc = -1e9f;
                    accs[m][n][i] = sc;
                    pm = fmaxf(pm, sc);
                }
#pragma unroll
                for (int off = 1; off < 16; off <<= 1)
                    pm = fmaxf(pm, __shfl_xor(pm, off, 64));
                float ps = 0.f;
#pragma unroll
                for (int n = 0; n < 8; ++n) {
                    float e = __expf(accs[m][n][i] - pm);
                    accs[m][n][i] = e;
                    ps += e;
                }
#pragma unroll
                for (int off = 1; off < 16; off <<= 1)
                    ps += __shfl_xor(ps, off, 64);
                float inv = 1.0f / ps;
#pragma unroll
                for (int n = 0; n < 8; ++n)
                    accs[m][n][i] *= inv;
            }
        }

#pragma unroll
        for (int m = 0; m < 2; ++m)
#pragma unroll
            for (int n = 0; n < 8; ++n)
#pragma unroll
                for (int i = 0; i < 4; ++i) {
                    __hip_bfloat16 pb = __float2bfloat16(accs[m][n][i]);
                    Plds[w][m * 16 + qd * 4 + i][n * 16 + r] = *(u16*)&pb;
                }

        f32x4 acco[2][4] = {};
#pragma unroll
        for (int ks = 0; ks < 4; ++ks) {
            bf16x8 pa[2];
#pragma unroll
            for (int m = 0; m < 2; ++m)
                pa[m] = *(const bf16x8*)&Plds[w][m * 16 + r][ks * 32 + qd * 8];
#pragma unroll
            for (int nd = 0; nd < 4; ++nd) {
                bf16x8 bv = *(const bf16x8*)&Vt[nd * 16 + r][ks * 32 + qd * 8];
#pragma unroll
                for (int m = 0; m < 2; ++m)
                    acco[m][nd] = __builtin_amdgcn_mfma_f32_16x16x32_bf16(
                        pa[m], bv, acco[m][nd], 0, 0, 0);
            }
        }

#pragma unroll
        for (int m = 0; m < 2; ++m)
#pragma unroll
            for (int nd = 0; nd < 4; ++nd)
#pragma unroll
                for (int i = 0; i < 4; ++i) {
                    __hip_bfloat16 ob = __float2bfloat16(acco[m][nd][i]);
                    out[(size_t)(b * S_ + sbase + m * 16 + qd * 4 + i) * D_ + h * 64 + nd * 16 + r] = *(u16*)&ob;
                }
    }
}

// ---------------------------------------------------------------------------
// final LN: out[row] = LN(bf16 xa + bf16 xb)*g+beta. 192 threads, ushort4.
// ---------------------------------------------------------------------------
__global__ __launch_bounds__(192) void addln_bb(
    const u16* __restrict__ xa, const u16* __restrict__ xb,
    const float* __restrict__ g, const float* __restrict__ beta,
    float* __restrict__ out)
{
    const int row = blockIdx.x;
    const int t = threadIdx.x;
    const ushort4 a = ((const ushort4*)(xa + (size_t)row * D_))[t];
    const ushort4 b4 = ((const ushort4*)(xb + (size_t)row * D_))[t];
    float v[4] = {bfu2f(a.x) + bfu2f(b4.x), bfu2f(a.y) + bfu2f(b4.y),
                  bfu2f(a.z) + bfu2f(b4.z), bfu2f(a.w) + bfu2f(b4.w)};
    float sum = v[0] + v[1] + v[2] + v[3];
#pragma unroll
    for (int off = 1; off < 64; off <<= 1) sum += __shfl_xor(sum, off, 64);
    __shared__ float r1[3], r2[3];
    int wv = t >> 6, ln = t & 63;
    if (ln == 0) r1[wv] = sum;
    __syncthreads();
    float mean = (r1[0] + r1[1] + r1[2]) * (1.0f / 768.0f);
    float sq = 0.f;
#pragma unroll
    for (int i = 0; i < 4; ++i) { v[i] -= mean; sq += v[i] * v[i]; }
#pragma unroll
    for (int off = 1; off < 64; off <<= 1) sq += __shfl_xor(sq, off, 64);
    if (ln == 0) r2[wv] = sq;
    __syncthreads();
    float var = (r2[0] + r2[1] + r2[2]) * (1.0f / 768.0f);
    float rs = rsqrtf(var + 1e-5f);
    float4 gg = ((const float4*)g)[t];
    float4 bb = ((const float4*)beta)[t];
    float4 o;
    o.x = v[0] * rs * gg.x + bb.x;
    o.y = v[1] * rs * gg.y + bb.y;
    o.z = v[2] * rs * gg.z + bb.z;
    o.w = v[3] * rs * gg.w + bb.w;
    ((float4*)(out + (size_t)row * D_))[t] = o;
}

// ---------------------------------------------------------------------------
// Class-attention precompute
// ---------------------------------------------------------------------------
__global__ __launch_bounds__(256) void precompute_U(
    const float* __restrict__ Wqc, const float* __restrict__ Wkc,
    const float* __restrict__ bqc, float* __restrict__ Ut, float* __restrict__ ab)
{
    __shared__ __attribute__((aligned(16))) float wk[D_];
    for (int i = threadIdx.x; i < D_; i += 256) wk[i] = Wkc[i];
    __syncthreads();
    int idx = blockIdx.x * 256 + threadIdx.x;
    int h = idx / D_, d = idx - h * D_;
    const float4* row = (const float4*)(Wqc + (size_t)d * D_ + h * 64);
    const float4* wkv = (const float4*)(wk + h * 64);
    float a0 = 0.f, a1 = 0.f, a2 = 0.f, a3 = 0.f;
#pragma unroll
    for (int j = 0; j < 16; j += 4) {
        float4 r0 = row[j], r1 = row[j + 1], r2 = row[j + 2], r3 = row[j + 3];
        float4 c0 = wkv[j], c1 = wkv[j + 1], c2 = wkv[j + 2], c3 = wkv[j + 3];
        a0 += r0.x * c0.x + r0.y * c0.y + r0.z * c0.z + r0.w * c0.w;
        a1 += r1.x * c1.x + r1.y * c1.y + r1.z * c1.z + r1.w * c1.w;
        a2 += r2.x * c2.x + r2.y * c2.y + r2.z * c2.z + r2.w * c2.w;
        a3 += r3.x * c3.x + r3.y * c3.y + r3.z * c3.z + r3.w * c3.w;
    }
    Ut[idx] = (a0 + a1) + (a2 + a3);
    if (idx < H_) {
        const float4* bq4 = (const float4*)(bqc + idx * 64);
        const float4* wk4 = (const float4*)(wk + idx * 64);
        float s = 0.f;
#pragma unroll
        for (int j = 0; j < 16; ++j) {
            float4 bb = bq4[j], cc = wk4[j];
            s += bb.x * cc.x + bb.y * cc.y + bb.z * cc.z + bb.w * cc.w;
        }
        ab[idx] = s;
    }
}

__global__ __launch_bounds__(256) void precompute_mix(
    const float* __restrict__ Wvc, const float* __restrict__ Woc,
    float* __restrict__ Wmix)
{
    __shared__ float wv[D_];
    for (int i = threadIdx.x; i < D_; i += 256) wv[i] = Wvc[i];
    __syncthreads();
    int idx = blockIdx.x * 256 + threadIdx.x;
    int h = idx / D_, n = idx - h * D_;
    float acc[8] = {};
#pragma unroll
    for (int j = 0; j < 64; ++j)
        acc[j & 7] += wv[h * 64 + j] * Woc[(size_t)(h * 64 + j) * D_ + n];
    Wmix[idx] = ((acc[0] + acc[1]) + (acc[2] + acc[3]))
              + ((acc[4] + acc[5]) + (acc[6] + acc[7]));
}

__global__ __launch_bounds__(256) void precompute_bias2(
    const float* __restrict__ Woc, const float* __restrict__ bvc,
    const float* __restrict__ boc, float* __restrict__ bias2)
{
    int tx = threadIdx.x & 63, ty = threadIdx.x >> 6;
    int n = blockIdx.x * 64 + tx;
    int d0 = ty * 192;
    float a = 0.f;
#pragma unroll 8
    for (int d = 0; d < 192; ++d)
        a += bvc[d0 + d] * Woc[(size_t)(d0 + d) * D_ + n];
    __shared__ float red[4][64];
    red[ty][tx] = a;
    __syncthreads();
    if (ty == 0)
        bias2[n] = boc[n] + red[0][tx] + red[1][tx] + red[2][tx] + red[3][tx];
}

// ---------------------------------------------------------------------------
// Fused mid: x1=LN(cur+oproj_bf16); alpha; mu; x2=LN(x1+bias2+mu@Wmix) -> bf16
// ---------------------------------------------------------------------------
__global__ __launch_bounds__(256) void fused_mid(
    const float* __restrict__ cur, const u16* __restrict__ oprojb,
    const float* __restrict__ g1, const float* __restrict__ b1,
    const float* __restrict__ Ut, const float* __restrict__ ab,
    const float* __restrict__ cvec,
    const float* __restrict__ Wmix, const float* __restrict__ bias2,
    const float* __restrict__ g2, const float* __restrict__ b2,
    __hip_bfloat16* __restrict__ x2b)
{
    const int w = threadIdx.x >> 6, lane = threadIdx.x & 63;
    const int row0 = blockIdx.x * 8 + w * 2;
    const int b = blockIdx.x >> 9;

    __shared__ float4 cvs[64];
    __shared__ float xp[4][64][28];
    __shared__ float muls[4][24];

    if (threadIdx.x < 64)
        cvs[threadIdx.x] = ((const float4*)(cvec + b * C_))[threadIdx.x];

    float4 x1[2][3];
#pragma unroll
    for (int rr = 0; rr < 2; ++rr) {
        const float4* pa = (const float4*)(cur + (size_t)(row0 + rr) * D_);
        const ushort4* pb = (const ushort4*)(oprojb + (size_t)(row0 + rr) * D_);
        float s = 0.f;
#pragma unroll
        for (int i = 0; i < 3; ++i) {
            float4 a = pa[i * 64 + lane];
            ushort4 ou = pb[i * 64 + lane];
            float4 v;
            v.x = a.x + bfu2f(ou.x); v.y = a.y + bfu2f(ou.y);
            v.z = a.z + bfu2f(ou.z); v.w = a.w + bfu2f(ou.w);
            x1[rr][i] = v;
            s += v.x + v.y + v.z + v.w;
        }
#pragma unroll
        for (int off = 1; off < 64; off <<= 1) s += __shfl_xor(s, off, 64);
        float mean = s * (1.0f / 768.0f);
        float sq = 0.f;
#pragma unroll
        for (int i = 0; i < 3; ++i) {
            x1[rr][i].x -= mean; x1[rr][i].y -= mean;
            x1[rr][i].z -= mean; x1[rr][i].w -= mean;
            sq += x1[rr][i].x * x1[rr][i].x + x1[rr][i].y * x1[rr][i].y
                + x1[rr][i].z * x1[rr][i].z + x1[rr][i].w * x1[rr][i].w;
        }
#pragma unroll
        for (int off = 1; off < 64; off <<= 1) sq += __shfl_xor(sq, off, 64);
        float rs = rsqrtf(sq * (1.0f / 768.0f) + 1e-5f);
#pragma unroll
        for (int i = 0; i < 3; ++i) {
            float4 gg = ((const float4*)g1)[i * 64 + lane];
            float4 bb = ((const float4*)b1)[i * 64 + lane];
            x1[rr][i].x = x1[rr][i].x * rs * gg.x + bb.x;
            x1[rr][i].y = x1[rr][i].y * rs * gg.y + bb.y;
            x1[rr][i].z = x1[rr][i].z * rs * gg.z + bb.z;
            x1[rr][i].w = x1[rr][i].w * rs * gg.w + bb.w;
        }
    }

    float acc[24];
#pragma unroll
    for (int j = 0; j < 24; ++j) acc[j] = 0.f;
#pragma unroll
    for (int i = 0; i < 3; ++i) {
#pragma unroll
        for (int h = 0; h < 12; ++h) {
            float4 u = ((const float4*)(Ut + (size_t)h * D_))[i * 64 + lane];
#pragma unroll
            for (int rr = 0; rr < 2; ++rr)
                acc[rr * 12 + h] += x1[rr][i].x * u.x + x1[rr][i].y * u.y
                                  + x1[rr][i].z * u.z + x1[rr][i].w * u.w;
        }
    }
#pragma unroll
    for (int j4 = 0; j4 < 6; ++j4)
        *(float4*)&xp[w][lane][j4 * 4] = *(float4*)&acc[j4 * 4];
    __syncthreads();

    if (lane < 48) {
        int j = lane >> 1, half = lane & 1;
        float ssum = 0.f;
#pragma unroll
        for (int k = 0; k < 32; ++k) ssum += xp[w][half * 32 + k][j];
        ssum += __shfl_xor(ssum, 1, 64);
        float a = 0.125f * (ssum + ab[j % 12]);
        float z = 0.f, ms = 0.f;
#pragma unroll
        for (int it = 0; it < 32; ++it) {
            float4 c = cvs[half * 32 + it];
            float e0 = __expf(a * c.x), e1 = __expf(a * c.y),
                  e2 = __expf(a * c.z), e3 = __expf(a * c.w);
            z += e0 + e1 + e2 + e3;
            ms += e0 * c.x + e1 * c.y + e2 * c.z + e3 * c.w;
        }
        z += __shfl_xor(z, 1, 64);
        ms += __shfl_xor(ms, 1, 64);
        if (half == 0) muls[w][j] = ms / z;
    }
    __syncthreads();

    float4 t2[2][3];
#pragma unroll
    for (int i = 0; i < 3; ++i) {
        float4 bv = ((const float4*)bias2)[i * 64 + lane];
        float4 o0 = bv, o1 = bv;
#pragma unroll
        for (int h = 0; h < 12; ++h) {
            float4 wm = ((const float4*)(Wmix + (size_t)h * D_))[i * 64 + lane];
            float m0 = muls[w][h], m1 = muls[w][12 + h];
            o0.x += m0 * wm.x; o0.y += m0 * wm.y; o0.z += m0 * wm.z; o0.w += m0 * wm.w;
            o1.x += m1 * wm.x; o1.y += m1 * wm.y; o1.z += m1 * wm.z; o1.w += m1 * wm.w;
        }
        t2[0][i].x = x1[0][i].x + o0.x; t2[0][i].y = x1[0][i].y + o0.y;
        t2[0][i].z = x1[0][i].z + o0.z; t2[0][i].w = x1[0][i].w + o0.w;
        t2[1][i].x = x1[1][i].x + o1.x; t2[1][i].y = x1[1][i].y + o1.y;
        t2[1][i].z = x1[1][i].z + o1.z; t2[1][i].w = x1[1][i].w + o1.w;
    }

#pragma unroll
    for (int rr = 0; rr < 2; ++rr) {
        float s = 0.f;
#pragma unroll
        for (int i = 0; i < 3; ++i)
            s += t2[rr][i].x + t2[rr][i].y + t2[rr][i].z + t2[rr][i].w;
#pragma unroll
        for (int off = 1; off < 64; off <<= 1) s += __shfl_xor(s, off, 64);
        float mean = s * (1.0f / 768.0f);
        float sq = 0.f;
#pragma unroll
        for (int i = 0; i < 3; ++i) {
            t2[rr][i].x -= mean; t2[rr][i].y -= mean;
            t2[rr][i].z -= mean; t2[rr][i].w -= mean;
            sq += t2[rr][i].x * t2[rr][i].x + t2[rr][i].y * t2[rr][i].y
                + t2[rr][i].z * t2[rr][i].z + t2[rr][i].w * t2[rr][i].w;
        }
#pragma unroll
        for (int off = 1; off < 64; off <<= 1) sq += __shfl_xor(sq, off, 64);
        float rs = rsqrtf(sq * (1.0f / 768.0f) + 1e-5f);
        size_t base = (size_t)(row0 + rr) * D_;
#pragma unroll
        for (int i = 0; i < 3; ++i) {
            float4 gg = ((const float4*)g2)[i * 64 + lane];
            float4 bb = ((const float4*)b2)[i * 64 + lane];
            float vx = t2[rr][i].x * rs * gg.x + bb.x;
            float vy = t2[rr][i].y * rs * gg.y + bb.y;
            float vz = t2[rr][i].z * rs * gg.z + bb.z;
            float vw = t2[rr][i].w * rs * gg.w + bb.w;
            __hip_bfloat16 pk[4] = {
                __float2bfloat16(vx), __float2bfloat16(vy),
                __float2bfloat16(vz), __float2bfloat16(vw)};
            *(uint2*)(x2b + base + i * 256 + lane * 4) = *(const uint2*)pk;
        }
    }
}

// ---------------------------------------------------------------------------
extern "C" void kernel_launch(void* const* d_in, const int* in_sizes, int n_in,
                              void* d_out, int out_size, void* d_ws, size_t ws_size,
                              hipStream_t stream) {
    const float* cur   = (const float*)d_in[0];
    const float* prev  = (const float*)d_in[1];
    const float* cvec  = (const float*)d_in[2];
    const int*   ridx  = (const int*)d_in[3];
    const float* Wq  = (const float*)d_in[4];
    const float* bq  = (const float*)d_in[5];
    const float* Wk  = (const float*)d_in[6];
    const float* bk  = (const float*)d_in[7];
    const float* Wv  = (const float*)d_in[8];
    const float* bv  = (const float*)d_in[9];
    const float* Wo  = (const float*)d_in[10];
    const float* bo  = (const float*)d_in[11];
    const float* g1  = (const float*)d_in[12];
    const float* b1  = (const float*)d_in[13];
    const float* Wqc = (const float*)d_in[14];
    const float* bqc = (const float*)d_in[15];
    const float* Wkc = (const float*)d_in[16];
    const float* bkc = (const float*)d_in[17];  (void)bkc;
    const float* Wvc = (const float*)d_in[18];
    const float* bvc = (const float*)d_in[19];
    const float* Woc = (const float*)d_in[20];
    const float* boc = (const float*)d_in[21];
    const float* g2  = (const float*)d_in[22];
    const float* b2  = (const float*)d_in[23];
    const float* W1  = (const float*)d_in[24];
    const float* bf1 = (const float*)d_in[25];
    const float* W2  = (const float*)d_in[26];
    const float* bf2 = (const float*)d_in[27];
    const float* g3  = (const float*)d_in[28];
    const float* b3  = (const float*)d_in[29];
    float* outp = (float*)d_out;
    (void)ws_size; (void)in_sizes; (void)n_in; (void)out_size;

    const int M = B_ * S_;                       // 16384
    const size_t NBSD = (size_t)M * D_;          // 12,582,912
    const size_t NSEL = (size_t)B_ * 128 * D_;   // 393,216

    __hip_bfloat16* hidb  = (__hip_bfloat16*)d_ws;          // M x FF
    __hip_bfloat16* bf0   = hidb + (size_t)M * FF_;         // cur_bf -> attn_out -> x2
    __hip_bfloat16* tmpb  = bf0 + NBSD;                     // q -> oproj -> ff
    __hip_bfloat16* Pselb = tmpb + NBSD;
    __hip_bfloat16* kselb = Pselb + NSEL;
    __hip_bfloat16* vselb = kselb + NSEL;
    __hip_bfloat16* Wqt   = vselb + NSEL;
    __hip_bfloat16* Wot   = Wqt + (size_t)D_ * D_;
    __hip_bfloat16* Wkt   = Wot + (size_t)D_ * D_;
    __hip_bfloat16* Wvt   = Wkt + (size_t)D_ * D_;
    __hip_bfloat16* W1t   = Wvt + (size_t)D_ * D_;          // FF x D
    __hip_bfloat16* W2t   = W1t + (size_t)D_ * FF_;         // D x FF
    float* Ub    = (float*)(W2t + (size_t)FF_ * D_);
    float* abv   = Ub + (size_t)D_ * H_;
    float* Wmix  = abv + 16;
    float* bias2 = Wmix + (size_t)H_ * D_;
    int*   selb  = (int*)(bias2 + D_);

    // 1) gather (bf16) + transposes + convert + class-attn precomputes
    gather_kernel<<<B_ * 128, 256, 0, stream>>>(prev, ridx, Pselb, selb);
    transp_all<<<6912, 256, 0, stream>>>(Wq, Wo, Wk, Wv, W1, W2,
                                         Wqt, Wot, Wkt, Wvt, W1t, W2t);
    conv_bf16<<<(int)(NBSD / 8 + 255) / 256, 256, 0, stream>>>(cur, bf0, (int)(NBSD / 8));
    precompute_U<<<36, 256, 0, stream>>>(Wqc, Wkc, bqc, Ub, abv);
    precompute_mix<<<36, 256, 0, stream>>>(Wvc, Woc, Wmix);
    precompute_bias2<<<12, 256, 0, stream>>>(Woc, bvc, boc, bias2);

    // 2) ksel/vsel projections (small; 128^2 kernel)
    {
        dim3 g(D_ / 128, (B_ * 128) / 128);
        gemm_mfma<<<g, 256, 0, stream>>>(Pselb, Wkt, bk, nullptr, kselb,
                                         B_ * 128, D_, D_, D_, D_, 1 | 8);
        gemm_mfma<<<g, 256, 0, stream>>>(Pselb, Wvt, bv, nullptr, vselb,
                                         B_ * 128, D_, D_, D_, D_, 1 | 8);
    }

    // 3) q = cur @ Wq + bq -> tmpb (bf16)   [8-phase 256^2]
    gemm256<<<dim3(D_ / 256, M / 256), 512, 0, stream>>>(
        (const u16*)bf0, (const u16*)Wqt, bq, (u16*)tmpb, M, D_, D_, 1);

    // 4) MFMA sparse attention -> bf0 (bf16; cur_bf dead)
    attn3_kernel<<<dim3(S_ / 256, B_ * H_), 256, 0, stream>>>(
        (const u16*)tmpb, (const u16*)kselb, (const u16*)vselb, selb, (u16*)bf0);

    // 5) oproj = attn_out @ Wo + bo -> tmpb (bf16; q dead)
    gemm256<<<dim3(D_ / 256, M / 256), 512, 0, stream>>>(
        (const u16*)bf0, (const u16*)Wot, bo, (u16*)tmpb, M, D_, D_, 1);

    // 6) fused mid: x1, class-attn, x2 -> bf0 (bf16; attn_out dead)
    fused_mid<<<M / 8, 256, 0, stream>>>(
        cur, (const u16*)tmpb, g1, b1, Ub, abv, cvec, Wmix, bias2, g2, b2, bf0);

    // 7) FF full-width: hid = relu(x2@W1+bf1) -> hidb; ff = hid@W2+bf2 -> tmpb
    gemm256<<<dim3(FF_ / 256, M / 256), 512, 0, stream>>>(
        (const u16*)bf0, (const u16*)W1t, bf1, (u16*)hidb, M, FF_, D_, 1 | 2);
    gemm256<<<dim3(D_ / 256, M / 256), 512, 0, stream>>>(
        (const u16*)hidb, (const u16*)W2t, bf2, (u16*)tmpb, M, D_, FF_, 1);

    // 8) out = LN(x2 + ff)
    addln_bb<<<M, 192, 0, stream>>>((const u16*)bf0, (const u16*)tmpb, g3, b3, outp);
}

// Round 10
// 430.752 us; speedup vs baseline: 13.5817x; 1.0176x over previous
//
#include <hip/hip_runtime.h>
#include <hip/hip_bf16.h>

#define B_ 4
#define S_ 4096
#define D_ 768
#define H_ 12
#define DH_ 64
#define G_ 64
#define C_ 256
#define FF_ 3072

typedef __attribute__((ext_vector_type(8))) short bf16x8;
typedef __attribute__((ext_vector_type(4))) float f32x4;
typedef unsigned short u16;

__device__ __forceinline__ float bfu2f(u16 u) {
    return __uint_as_float((unsigned)u << 16);
}

// ---------------------------------------------------------------------------
// async global->LDS 16B (wave-uniform LDS base + lane*16)
// ---------------------------------------------------------------------------
__device__ __forceinline__ void gload16(const __hip_bfloat16* g, __hip_bfloat16* l) {
    __builtin_amdgcn_global_load_lds(
        (__attribute__((address_space(1))) void*)(void*)const_cast<__hip_bfloat16*>(g),
        (__attribute__((address_space(3))) void*)(void*)l,
        16, 0, 0);
}

// ---------------------------------------------------------------------------
// gemm256 — 8-phase, ds_reads pipelined ONE PHASE AHEAD (full-phase shadow):
// phase k: [STG][BAR][LGKM0][MFMA_k][tail-reads for k+1][BAR].
// Stage slots: ph1/ph2 B[buf1], ph4 A[buf0]x2, ph5/ph6 B[buf0], ph8 A[buf1]x2;
// vmcnt(4) gates at ph4/ph8 (leaves newest A-halves in flight); buffer
// overwrites are >=1 reader-LGKM0+BAR after last read (window table in notes).
// T2 source-swizzle (0 conflicts), T5 setprio, T1 XCD swizzle.
// A: MxK bf16, Bt: NxK bf16. Out bf16. flags: 1=bias, 2=relu.
// M%256==0, N%256==0, K%128==0, nwg%8==0.
// ---------------------------------------------------------------------------
__global__ __launch_bounds__(512, 2) void gemm256(
    const u16* __restrict__ A, const u16* __restrict__ Bt,
    const float* __restrict__ bias, u16* __restrict__ Cb,
    int M, int N, int K, int flags)
{
    __shared__ __attribute__((aligned(16))) u16 Ah[2][2][128 * 64];
    __shared__ __attribute__((aligned(16))) u16 Bh[2][2][128 * 64];

    const int tid = threadIdx.x;
    const int lane = tid & 63, w = tid >> 6;
    const int wm = w >> 2, wn = w & 3;          // 2 x 4 wave grid
    const int r = lane & 15, qd = lane >> 4;

    // bijective XCD swizzle (nwg % 8 == 0)
    int lin = blockIdx.y * gridDim.x + blockIdx.x;
    int nwg = gridDim.x * gridDim.y;
    int cpx = nwg >> 3;
    int swz = (lin & 7) * cpx + (lin >> 3);
    int bm = (swz / gridDim.x) * 256;
    int bn = (swz % gridDim.x) * 256;

    // staging map: thread t covers rows (t>>3) and (t>>3)+64 of a 128x64 half
    const int srow = tid >> 3;                       // 0..63
    const int scol = ((tid & 7) ^ (srow & 7)) * 8;   // inverse-swizzled source
    const int sdst = tid * 8;                        // linear LDS elem offset

#define STG_A(c, h, kt) { \
    const u16* s_ = A + (size_t)(bm + (h) * 128 + srow) * K + ((kt) << 6) + scol; \
    gload16((const __hip_bfloat16*)s_, (__hip_bfloat16*)&Ah[c][h][sdst]); \
    gload16((const __hip_bfloat16*)(s_ + (size_t)64 * K), (__hip_bfloat16*)&Ah[c][h][sdst + 4096]); }
#define STG_B(c, h, kt) { \
    const u16* s_ = Bt + (size_t)(bn + (h) * 128 + srow) * K + ((kt) << 6) + scol; \
    gload16((const __hip_bfloat16*)s_, (__hip_bfloat16*)&Bh[c][h][sdst]); \
    gload16((const __hip_bfloat16*)(s_ + (size_t)64 * K), (__hip_bfloat16*)&Bh[c][h][sdst + 4096]); }

#define GRAN(kk) (((((kk) << 2) + qd) ^ (r & 7)) * 8)
#define READS_AF(c, mb) { \
    _Pragma("unroll") for (int m = 0; m < 4; ++m) { \
        const u16* p_ = &Ah[c][wm][((mb + m) * 16 + r) * 64]; \
        af[m][0] = *(const bf16x8*)(p_ + GRAN(0)); \
        af[m][1] = *(const bf16x8*)(p_ + GRAN(1)); } }
#define READS_BF(dst, c, nb) { \
    _Pragma("unroll") for (int n = 0; n < 2; ++n) { \
        const u16* p_ = &Bh[c][wn >> 1][((wn & 1) * 64 + (nb + n) * 16 + r) * 64]; \
        dst[n][0] = *(const bf16x8*)(p_ + GRAN(0)); \
        dst[n][1] = *(const bf16x8*)(p_ + GRAN(1)); } }
#define QMFMA(mb, nb, bfx) { \
    __builtin_amdgcn_s_setprio(1); \
    _Pragma("unroll") for (int kk = 0; kk < 2; ++kk) \
    _Pragma("unroll") for (int m = 0; m < 4; ++m) \
    _Pragma("unroll") for (int n = 0; n < 2; ++n) \
        acc[mb + m][nb + n] = __builtin_amdgcn_mfma_f32_16x16x32_bf16( \
            af[m][kk], bfx[n][kk], acc[mb + m][nb + n], 0, 0, 0); \
    __builtin_amdgcn_s_setprio(0); }
#define BAR() __builtin_amdgcn_s_barrier()
#define LGKM0() asm volatile("s_waitcnt lgkmcnt(0)" ::: "memory")

    f32x4 acc[8][4] = {};
    const int NT = K >> 6;
    const int J = NT >> 1;

    bf16x8 af[4][2], bfa[2][2], bfb[2][2];

    // prologue: tile0 full -> buf0 (8 loads); tile1 A-halves -> buf1 (4 loads)
    STG_A(0, 0, 0) STG_A(0, 1, 0) STG_B(0, 0, 0) STG_B(0, 1, 0)
    STG_A(1, 0, 1) STG_A(1, 1, 1)
    asm volatile("s_waitcnt vmcnt(4)" ::: "memory");   // tile0 landed
    BAR();
    READS_AF(0, 0) READS_BF(bfa, 0, 0)                 // af0+bf0 of buf0

    for (int j = 0; j < J; ++j) {
        const int to1 = 2 * j + 1, te2 = 2 * j + 2, to3 = 2 * j + 3;
        const bool pf = (j + 1 < J);

        // ph1: stage Bh0[buf1]<-to1; compute Q00(buf0); tail: bf1(buf0)
        STG_B(1, 0, to1)
        BAR(); LGKM0();
        QMFMA(0, 0, bfa)
        READS_BF(bfb, 0, 2)
        BAR();
        // ph2: stage Bh1[buf1]; compute Q01; tail: af1(buf0)
        STG_B(1, 1, to1)
        BAR(); LGKM0();
        QMFMA(0, 2, bfb)
        READS_AF(0, 4)
        BAR();
        // ph3: compute Q11 (no stage, no tail)
        LGKM0();
        QMFMA(4, 2, bfb)
        BAR();
        // ph4: stage Ah0+Ah1[buf0]<-te2; compute Q10; gate buf1; tail: af0+bf0(buf1)
        if (pf) { STG_A(0, 0, te2) STG_A(0, 1, te2) }
        BAR();
        QMFMA(4, 0, bfa)
        if (pf) asm volatile("s_waitcnt vmcnt(4)" ::: "memory");
        else    asm volatile("s_waitcnt vmcnt(0)" ::: "memory");
        BAR();
        READS_AF(1, 0) READS_BF(bfa, 1, 0)
        // ph5: stage Bh0[buf0]; compute Q00(buf1); tail: bf1(buf1)
        if (pf) { STG_B(0, 0, te2) }
        BAR(); LGKM0();
        QMFMA(0, 0, bfa)
        READS_BF(bfb, 1, 2)
        BAR();
        // ph6: stage Bh1[buf0]; compute Q01; tail: af1(buf1)
        if (pf) { STG_B(0, 1, te2) }
        BAR(); LGKM0();
        QMFMA(0, 2, bfb)
        READS_AF(1, 4)
        BAR();
        // ph7: compute Q11
        LGKM0();
        QMFMA(4, 2, bfb)
        BAR();
        // ph8: stage Ah[buf1]<-to3; compute Q10; gate buf0; tail: af0+bf0(buf0)
        if (pf) { STG_A(1, 0, to3) STG_A(1, 1, to3) }
        BAR();
        QMFMA(4, 0, bfa)
        if (pf) {
            asm volatile("s_waitcnt vmcnt(4)" ::: "memory");
            BAR();
            READS_AF(0, 0) READS_BF(bfa, 0, 0)
        }
    }

#pragma unroll
    for (int m = 0; m < 8; ++m) {
        int row0 = bm + wm * 128 + m * 16 + qd * 4;
#pragma unroll
        for (int n = 0; n < 4; ++n) {
            int col = bn + wn * 64 + n * 16 + r;
            float bv = (flags & 1) ? bias[col] : 0.0f;
#pragma unroll
            for (int i = 0; i < 4; ++i) {
                float v = acc[m][n][i] + bv;
                if (flags & 2) v = fmaxf(v, 0.0f);
                __hip_bfloat16 ob = __float2bfloat16(v);
                Cb[(size_t)(row0 + i) * N + col] = *(u16*)&ob;
            }
        }
    }
#undef STG_A
#undef STG_B
#undef GRAN
#undef READS_AF
#undef READS_BF
#undef QMFMA
#undef BAR
#undef LGKM0
}

// ---------------------------------------------------------------------------
// bf16 MFMA GEMM 128x128 (small shapes: ksel/vsel). flags: 1=bias, 8=bf16 out
// ---------------------------------------------------------------------------
__global__ __launch_bounds__(256) void gemm_mfma(
    const __hip_bfloat16* __restrict__ A, const __hip_bfloat16* __restrict__ Bt,
    const float* __restrict__ bias, float* __restrict__ Cf,
    __hip_bfloat16* __restrict__ Cb,
    int M, int N, int K, int lda, int ldbt, int flags)
{
    __shared__ __hip_bfloat16 As[2][128 * 32];
    __shared__ __hip_bfloat16 Bs[2][128 * 32];

    const int t = threadIdx.x;
    const int lane = t & 63;
    const int wave = t >> 6;
    const int wr = wave >> 1, wc = wave & 1;
    const int qd = lane >> 4, r = lane & 15;

    int lin = blockIdx.y * gridDim.x + blockIdx.x;
    int nwg = gridDim.x * gridDim.y;
    int cpx = nwg >> 3;
    int swz = (lin & 7) * cpx + (lin >> 3);
    int bm = (swz / gridDim.x) * 128;
    int bn = (swz % gridDim.x) * 128;

    const int srow = lane >> 2;
    const int scol = (lane & 3) * 8;
    const __hip_bfloat16* gA0 = A + (size_t)(bm + wave * 32 + srow) * lda + scol;
    const __hip_bfloat16* gA1 = gA0 + (size_t)16 * lda;
    const __hip_bfloat16* gB0 = Bt + (size_t)(bn + wave * 32 + srow) * ldbt + scol;
    const __hip_bfloat16* gB1 = gB0 + (size_t)16 * ldbt;

    f32x4 acc[4][4] = {};

    gload16(gA0, &As[0][wave * 1024]);
    gload16(gA1, &As[0][wave * 1024 + 512]);
    gload16(gB0, &Bs[0][wave * 1024]);
    gload16(gB1, &Bs[0][wave * 1024 + 512]);
    __syncthreads();

    int cur = 0;
    for (int k0 = 0; k0 < K; k0 += 32, cur ^= 1) {
        if (k0 + 32 < K) {
            int kn = k0 + 32, nb = cur ^ 1;
            gload16(gA0 + kn, &As[nb][wave * 1024]);
            gload16(gA1 + kn, &As[nb][wave * 1024 + 512]);
            gload16(gB0 + kn, &Bs[nb][wave * 1024]);
            gload16(gB1 + kn, &Bs[nb][wave * 1024 + 512]);
        }
        bf16x8 afr[4], bfr[4];
#pragma unroll
        for (int m = 0; m < 4; ++m)
            afr[m] = *(const bf16x8*)&As[cur][(wr * 64 + m * 16 + r) * 32 + qd * 8];
#pragma unroll
        for (int n = 0; n < 4; ++n)
            bfr[n] = *(const bf16x8*)&Bs[cur][(wc * 64 + n * 16 + r) * 32 + qd * 8];
#pragma unroll
        for (int m = 0; m < 4; ++m)
#pragma unroll
            for (int n = 0; n < 4; ++n)
                acc[m][n] = __builtin_amdgcn_mfma_f32_16x16x32_bf16(
                    afr[m], bfr[n], acc[m][n], 0, 0, 0);
        __syncthreads();
    }

#pragma unroll
    for (int m = 0; m < 4; ++m) {
        int row0 = bm + wr * 64 + m * 16 + qd * 4;
#pragma unroll
        for (int n = 0; n < 4; ++n) {
            int col = bn + wc * 64 + n * 16 + r;
            float bv = (flags & 1) ? bias[col] : 0.0f;
#pragma unroll
            for (int i = 0; i < 4; ++i) {
                float v = acc[m][n][i] + bv;
                if (flags & 2) v = fmaxf(v, 0.0f);
                size_t off = (size_t)(row0 + i) * N + col;
                if (flags & 4) v += Cf[off];
                if (flags & 8) Cb[off] = __float2bfloat16(v);
                else           Cf[off] = v;
            }
        }
    }
}

// ---------------------------------------------------------------------------
__global__ __launch_bounds__(256) void conv_bf16(const float* __restrict__ in,
                                                 __hip_bfloat16* __restrict__ out,
                                                 int n8)
{
    int i = blockIdx.x * 256 + threadIdx.x;
    if (i >= n8) return;
    const float4* p = (const float4*)(in + (size_t)i * 8);
    float4 v0 = p[0], v1 = p[1];
    __hip_bfloat16 o[8] = {
        __float2bfloat16(v0.x), __float2bfloat16(v0.y),
        __float2bfloat16(v0.z), __float2bfloat16(v0.w),
        __float2bfloat16(v1.x), __float2bfloat16(v1.y),
        __float2bfloat16(v1.z), __float2bfloat16(v1.w)};
    *(uint4*)(out + (size_t)i * 8) = *(const uint4*)o;
}

// ---------------------------------------------------------------------------
// All 6 weight transposes in one dispatch.
// ---------------------------------------------------------------------------
__global__ __launch_bounds__(256) void transp_all(
    const float* __restrict__ Wq, const float* __restrict__ Wo,
    const float* __restrict__ Wk, const float* __restrict__ Wv,
    const float* __restrict__ W1, const float* __restrict__ W2,
    __hip_bfloat16* __restrict__ Wqt, __hip_bfloat16* __restrict__ Wot,
    __hip_bfloat16* __restrict__ Wkt, __hip_bfloat16* __restrict__ Wvt,
    __hip_bfloat16* __restrict__ W1t, __hip_bfloat16* __restrict__ W2t)
{
    int tile = blockIdx.x;
    const float* W; __hip_bfloat16* Wt; int K, N;
    if (tile < 2304) {
        int w = tile / 576; tile -= w * 576;
        K = 768; N = 768;
        W  = (w == 0) ? Wq : (w == 1) ? Wo : (w == 2) ? Wk : Wv;
        Wt = (w == 0) ? Wqt : (w == 1) ? Wot : (w == 2) ? Wkt : Wvt;
    } else if (tile < 4608) { tile -= 2304; K = 768; N = 3072; W = W1; Wt = W1t; }
    else                    { tile -= 4608; K = 3072; N = 768; W = W2; Wt = W2t; }
    int ntx = N >> 5;
    int k0 = (tile / ntx) * 32, n0 = (tile % ntx) * 32;
    __shared__ float s[32][33];
    int tx = threadIdx.x & 31, ty = threadIdx.x >> 5;
#pragma unroll
    for (int i = 0; i < 4; ++i)
        s[ty + i * 8][tx] = W[(size_t)(k0 + ty + i * 8) * N + n0 + tx];
    __syncthreads();
#pragma unroll
    for (int i = 0; i < 4; ++i)
        Wt[(size_t)(n0 + ty + i * 8) * K + k0 + tx] =
            __float2bfloat16(s[tx][ty + i * 8]);
}

// ---------------------------------------------------------------------------
__global__ void gather_kernel(const float* __restrict__ prev,
                              const int* __restrict__ rand_idx,
                              __hip_bfloat16* __restrict__ Pselb,
                              int* __restrict__ sel)
{
    int j = blockIdx.x;
    int b = j >> 7, i = j & 127;
    int sv = (i < 64) ? i : rand_idx[b * G_ + (i - 64)];
    if (threadIdx.x == 0) sel[j] = sv;
    const float* src = prev + ((size_t)(b * S_ + sv)) * D_;
    __hip_bfloat16* dst = Pselb + (size_t)j * D_;
    for (int d = threadIdx.x; d < D_; d += blockDim.x)
        dst[d] = __float2bfloat16(src[d]);
}

// ---------------------------------------------------------------------------
// MFMA sparse attention
// ---------------------------------------------------------------------------
__global__ __launch_bounds__(256) void attn3_kernel(
    const u16* __restrict__ qb, const u16* __restrict__ kb,
    const u16* __restrict__ vb, const int* __restrict__ sel,
    u16* __restrict__ out)
{
    const int bh = blockIdx.y;
    const int b = bh / H_, h = bh % H_;
    const int s0 = blockIdx.x * 256;
    const int t = threadIdx.x;
    const int w = t >> 6, lane = t & 63;
    const int r = lane & 15, qd = lane >> 4;

    __shared__ u16 Vt[64][136];
    __shared__ u16 Plds[4][32][136];
    __shared__ int ssel[128];

    {
        int key0 = t >> 4;
        int d0 = (t & 15) * 4;
        for (int kk = key0; kk < 128; kk += 16) {
            ushort4 v = *(const ushort4*)(vb + (size_t)(b * 128 + kk) * D_ + h * 64 + d0);
            Vt[d0 + 0][kk] = v.x; Vt[d0 + 1][kk] = v.y;
            Vt[d0 + 2][kk] = v.z; Vt[d0 + 3][kk] = v.w;
        }
        if (t < 128) ssel[t] = sel[b * 128 + t];
    }
    __syncthreads();

    int selv[8];
#pragma unroll
    for (int n = 0; n < 8; ++n) selv[n] = ssel[n * 16 + r];

    for (int pass = 0; pass < 2; ++pass) {
        const int sbase = s0 + w * 64 + pass * 32;
        f32x4 accs[2][8] = {};

#pragma unroll
        for (int ks = 0; ks < 2; ++ks) {
            bf16x8 af[2];
#pragma unroll
            for (int m = 0; m < 2; ++m)
                af[m] = *(const bf16x8*)(qb + (size_t)(b * S_ + sbase + m * 16 + r) * D_ + h * 64 + ks * 32 + qd * 8);
#pragma unroll
            for (int n = 0; n < 8; ++n) {
                bf16x8 bfv = *(const bf16x8*)(kb + (size_t)(b * 128 + n * 16 + r) * D_ + h * 64 + ks * 32 + qd * 8);
#pragma unroll
                for (int m = 0; m < 2; ++m)
                    accs[m][n] = __builtin_amdgcn_mfma_f32_16x16x32_bf16(
                        af[m], bfv, accs[m][n], 0, 0, 0);
            }
        }

#pragma unroll
        for (int m = 0; m < 2; ++m) {
#pragma unroll
            for (int i = 0; i < 4; ++i) {
                int srow = sbase + m * 16 + qd * 4 + i;
                float pm = -3e38f;
#pragma unroll
                for (int n = 0; n < 8; ++n) {
                    float sc = accs[m][n][i] * 0.125f;
                    if (selv[n] > srow) sc = -1e9f;
                    accs[m][n][i] = sc;
                    pm = fmaxf(pm, sc);
                }
#pragma unroll
                for (int off = 1; off < 16; off <<= 1)
                    pm = fmaxf(pm, __shfl_xor(pm, off, 64));
                float ps = 0.f;
#pragma unroll
                for (int n = 0; n < 8; ++n) {
                    float e = __expf(accs[m][n][i] - pm);
                    accs[m][n][i] = e;
                    ps += e;
                }
#pragma unroll
                for (int off = 1; off < 16; off <<= 1)
                    ps += __shfl_xor(ps, off, 64);
                float inv = 1.0f / ps;
#pragma unroll
                for (int n = 0; n < 8; ++n)
                    accs[m][n][i] *= inv;
            }
        }

#pragma unroll
        for (int m = 0; m < 2; ++m)
#pragma unroll
            for (int n = 0; n < 8; ++n)
#pragma unroll
                for (int i = 0; i < 4; ++i) {
                    __hip_bfloat16 pb = __float2bfloat16(accs[m][n][i]);
                    Plds[w][m * 16 + qd * 4 + i][n * 16 + r] = *(u16*)&pb;
                }

        f32x4 acco[2][4] = {};
#pragma unroll
        for (int ks = 0; ks < 4; ++ks) {
            bf16x8 pa[2];
#pragma unroll
            for (int m = 0; m < 2; ++m)
                pa[m] = *(const bf16x8*)&Plds[w][m * 16 + r][ks * 32 + qd * 8];
#pragma unroll
            for (int nd = 0; nd < 4; ++nd) {
                bf16x8 bv = *(const bf16x8*)&Vt[nd * 16 + r][ks * 32 + qd * 8];
#pragma unroll
                for (int m = 0; m < 2; ++m)
                    acco[m][nd] = __builtin_amdgcn_mfma_f32_16x16x32_bf16(
                        pa[m], bv, acco[m][nd], 0, 0, 0);
            }
        }

#pragma unroll
        for (int m = 0; m < 2; ++m)
#pragma unroll
            for (int nd = 0; nd < 4; ++nd)
#pragma unroll
                for (int i = 0; i < 4; ++i) {
                    __hip_bfloat16 ob = __float2bfloat16(acco[m][nd][i]);
                    out[(size_t)(b * S_ + sbase + m * 16 + qd * 4 + i) * D_ + h * 64 + nd * 16 + r] = *(u16*)&ob;
                }
    }
}

// ---------------------------------------------------------------------------
// final LN: out[row] = LN(bf16 xa + bf16 xb)*g+beta. 192 threads, ushort4.
// ---------------------------------------------------------------------------
__global__ __launch_bounds__(192) void addln_bb(
    const u16* __restrict__ xa, const u16* __restrict__ xb,
    const float* __restrict__ g, const float* __restrict__ beta,
    float* __restrict__ out)
{
    const int row = blockIdx.x;
    const int t = threadIdx.x;
    const ushort4 a = ((const ushort4*)(xa + (size_t)row * D_))[t];
    const ushort4 b4 = ((const ushort4*)(xb + (size_t)row * D_))[t];
    float v[4] = {bfu2f(a.x) + bfu2f(b4.x), bfu2f(a.y) + bfu2f(b4.y),
                  bfu2f(a.z) + bfu2f(b4.z), bfu2f(a.w) + bfu2f(b4.w)};
    float sum = v[0] + v[1] + v[2] + v[3];
#pragma unroll
    for (int off = 1; off < 64; off <<= 1) sum += __shfl_xor(sum, off, 64);
    __shared__ float r1[3], r2[3];
    int wv = t >> 6, ln = t & 63;
    if (ln == 0) r1[wv] = sum;
    __syncthreads();
    float mean = (r1[0] + r1[1] + r1[2]) * (1.0f / 768.0f);
    float sq = 0.f;
#pragma unroll
    for (int i = 0; i < 4; ++i) { v[i] -= mean; sq += v[i] * v[i]; }
#pragma unroll
    for (int off = 1; off < 64; off <<= 1) sq += __shfl_xor(sq, off, 64);
    if (ln == 0) r2[wv] = sq;
    __syncthreads();
    float var = (r2[0] + r2[1] + r2[2]) * (1.0f / 768.0f);
    float rs = rsqrtf(var + 1e-5f);
    float4 gg = ((const float4*)g)[t];
    float4 bb = ((const float4*)beta)[t];
    float4 o;
    o.x = v[0] * rs * gg.x + bb.x;
    o.y = v[1] * rs * gg.y + bb.y;
    o.z = v[2] * rs * gg.z + bb.z;
    o.w = v[3] * rs * gg.w + bb.w;
    ((float4*)(out + (size_t)row * D_))[t] = o;
}

// ---------------------------------------------------------------------------
// Class-attention precompute
// ---------------------------------------------------------------------------
__global__ __launch_bounds__(256) void precompute_U(
    const float* __restrict__ Wqc, const float* __restrict__ Wkc,
    const float* __restrict__ bqc, float* __restrict__ Ut, float* __restrict__ ab)
{
    __shared__ __attribute__((aligned(16))) float wk[D_];
    for (int i = threadIdx.x; i < D_; i += 256) wk[i] = Wkc[i];
    __syncthreads();
    int idx = blockIdx.x * 256 + threadIdx.x;
    int h = idx / D_, d = idx - h * D_;
    const float4* row = (const float4*)(Wqc + (size_t)d * D_ + h * 64);
    const float4* wkv = (const float4*)(wk + h * 64);
    float a0 = 0.f, a1 = 0.f, a2 = 0.f, a3 = 0.f;
#pragma unroll
    for (int j = 0; j < 16; j += 4) {
        float4 r0 = row[j], r1 = row[j + 1], r2 = row[j + 2], r3 = row[j + 3];
        float4 c0 = wkv[j], c1 = wkv[j + 1], c2 = wkv[j + 2], c3 = wkv[j + 3];
        a0 += r0.x * c0.x + r0.y * c0.y + r0.z * c0.z + r0.w * c0.w;
        a1 += r1.x * c1.x + r1.y * c1.y + r1.z * c1.z + r1.w * c1.w;
        a2 += r2.x * c2.x + r2.y * c2.y + r2.z * c2.z + r2.w * c2.w;
        a3 += r3.x * c3.x + r3.y * c3.y + r3.z * c3.z + r3.w * c3.w;
    }
    Ut[idx] = (a0 + a1) + (a2 + a3);
    if (idx < H_) {
        const float4* bq4 = (const float4*)(bqc + idx * 64);
        const float4* wk4 = (const float4*)(wk + idx * 64);
        float s = 0.f;
#pragma unroll
        for (int j = 0; j < 16; ++j) {
            float4 bb = bq4[j], cc = wk4[j];
            s += bb.x * cc.x + bb.y * cc.y + bb.z * cc.z + bb.w * cc.w;
        }
        ab[idx] = s;
    }
}

__global__ __launch_bounds__(256) void precompute_mix(
    const float* __restrict__ Wvc, const float* __restrict__ Woc,
    float* __restrict__ Wmix)
{
    __shared__ float wv[D_];
    for (int i = threadIdx.x; i < D_; i += 256) wv[i] = Wvc[i];
    __syncthreads();
    int idx = blockIdx.x * 256 + threadIdx.x;
    int h = idx / D_, n = idx - h * D_;
    float acc[8] = {};
#pragma unroll
    for (int j = 0; j < 64; ++j)
        acc[j & 7] += wv[h * 64 + j] * Woc[(size_t)(h * 64 + j) * D_ + n];
    Wmix[idx] = ((acc[0] + acc[1]) + (acc[2] + acc[3]))
              + ((acc[4] + acc[5]) + (acc[6] + acc[7]));
}

__global__ __launch_bounds__(256) void precompute_bias2(
    const float* __restrict__ Woc, const float* __restrict__ bvc,
    const float* __restrict__ boc, float* __restrict__ bias2)
{
    int tx = threadIdx.x & 63, ty = threadIdx.x >> 6;
    int n = blockIdx.x * 64 + tx;
    int d0 = ty * 192;
    float a = 0.f;
#pragma unroll 8
    for (int d = 0; d < 192; ++d)
        a += bvc[d0 + d] * Woc[(size_t)(d0 + d) * D_ + n];
    __shared__ float red[4][64];
    red[ty][tx] = a;
    __syncthreads();
    if (ty == 0)
        bias2[n] = boc[n] + red[0][tx] + red[1][tx] + red[2][tx] + red[3][tx];
}

// ---------------------------------------------------------------------------
// Fused mid: x1=LN(cur_bf16+oproj_bf16); alpha; mu; x2=LN(x1+bias2+mu@Wmix)
// -> bf16 (in-place over cur_bf: rows read early, written late, block-local)
// ---------------------------------------------------------------------------
__global__ __launch_bounds__(256) void fused_mid(
    const u16* __restrict__ curb, const u16* __restrict__ oprojb,
    const float* __restrict__ g1, const float* __restrict__ b1,
    const float* __restrict__ Ut, const float* __restrict__ ab,
    const float* __restrict__ cvec,
    const float* __restrict__ Wmix, const float* __restrict__ bias2,
    const float* __restrict__ g2, const float* __restrict__ b2,
    __hip_bfloat16* __restrict__ x2b)
{
    const int w = threadIdx.x >> 6, lane = threadIdx.x & 63;
    const int row0 = blockIdx.x * 8 + w * 2;
    const int b = blockIdx.x >> 9;

    __shared__ float4 cvs[64];
    __shared__ float xp[4][64][28];
    __shared__ float muls[4][24];

    if (threadIdx.x < 64)
        cvs[threadIdx.x] = ((const float4*)(cvec + b * C_))[threadIdx.x];

    float4 x1[2][3];
#pragma unroll
    for (int rr = 0; rr < 2; ++rr) {
        const ushort4* pa = (const ushort4*)(curb + (size_t)(row0 + rr) * D_);
        const ushort4* pb = (const ushort4*)(oprojb + (size_t)(row0 + rr) * D_);
        float s = 0.f;
#pragma unroll
        for (int i = 0; i < 3; ++i) {
            ushort4 au = pa[i * 64 + lane];
            ushort4 ou = pb[i * 64 + lane];
            float4 v;
            v.x = bfu2f(au.x) + bfu2f(ou.x); v.y = bfu2f(au.y) + bfu2f(ou.y);
            v.z = bfu2f(au.z) + bfu2f(ou.z); v.w = bfu2f(au.w) + bfu2f(ou.w);
            x1[rr][i] = v;
            s += v.x + v.y + v.z + v.w;
        }
#pragma unroll
        for (int off = 1; off < 64; off <<= 1) s += __shfl_xor(s, off, 64);
        float mean = s * (1.0f / 768.0f);
        float sq = 0.f;
#pragma unroll
        for (int i = 0; i < 3; ++i) {
            x1[rr][i].x -= mean; x1[rr][i].y -= mean;
            x1[rr][i].z -= mean; x1[rr][i].w -= mean;
            sq += x1[rr][i].x * x1[rr][i].x + x1[rr][i].y * x1[rr][i].y
                + x1[rr][i].z * x1[rr][i].z + x1[rr][i].w * x1[rr][i].w;
        }
#pragma unroll
        for (int off = 1; off < 64; off <<= 1) sq += __shfl_xor(sq, off, 64);
        float rs = rsqrtf(sq * (1.0f / 768.0f) + 1e-5f);
#pragma unroll
        for (int i = 0; i < 3; ++i) {
            float4 gg = ((const float4*)g1)[i * 64 + lane];
            float4 bb = ((const float4*)b1)[i * 64 + lane];
            x1[rr][i].x = x1[rr][i].x * rs * gg.x + bb.x;
            x1[rr][i].y = x1[rr][i].y * rs * gg.y + bb.y;
            x1[rr][i].z = x1[rr][i].z * rs * gg.z + bb.z;
            x1[rr][i].w = x1[rr][i].w * rs * gg.w + bb.w;
        }
    }

    float acc[24];
#pragma unroll
    for (int j = 0; j < 24; ++j) acc[j] = 0.f;
#pragma unroll
    for (int i = 0; i < 3; ++i) {
#pragma unroll
        for (int h = 0; h < 12; ++h) {
            float4 u = ((const float4*)(Ut + (size_t)h * D_))[i * 64 + lane];
#pragma unroll
            for (int rr = 0; rr < 2; ++rr)
                acc[rr * 12 + h] += x1[rr][i].x * u.x + x1[rr][i].y * u.y
                                  + x1[rr][i].z * u.z + x1[rr][i].w * u.w;
        }
    }
#pragma unroll
    for (int j4 = 0; j4 < 6; ++j4)
        *(float4*)&xp[w][lane][j4 * 4] = *(float4*)&acc[j4 * 4];
    __syncthreads();

    if (lane < 48) {
        int j = lane >> 1, half = lane & 1;
        float ssum = 0.f;
#pragma unroll
        for (int k = 0; k < 32; ++k) ssum += xp[w][half * 32 + k][j];
        ssum += __shfl_xor(ssum, 1, 64);
        float a = 0.125f * (ssum + ab[j % 12]);
        float z = 0.f, ms = 0.f;
#pragma unroll
        for (int it = 0; it < 32; ++it) {
            float4 c = cvs[half * 32 + it];
            float e0 = __expf(a * c.x), e1 = __expf(a * c.y),
                  e2 = __expf(a * c.z), e3 = __expf(a * c.w);
            z += e0 + e1 + e2 + e3;
            ms += e0 * c.x + e1 * c.y + e2 * c.z + e3 * c.w;
        }
        z += __shfl_xor(z, 1, 64);
        ms += __shfl_xor(ms, 1, 64);
        if (half == 0) muls[w][j] = ms / z;
    }
    __syncthreads();

    float4 t2[2][3];
#pragma unroll
    for (int i = 0; i < 3; ++i) {
        float4 bv = ((const float4*)bias2)[i * 64 + lane];
        float4 o0 = bv, o1 = bv;
#pragma unroll
        for (int h = 0; h < 12; ++h) {
            float4 wm = ((const float4*)(Wmix + (size_t)h * D_))[i * 64 + lane];
            float m0 = muls[w][h], m1 = muls[w][12 + h];
            o0.x += m0 * wm.x; o0.y += m0 * wm.y; o0.z += m0 * wm.z; o0.w += m0 * wm.w;
            o1.x += m1 * wm.x; o1.y += m1 * wm.y; o1.z += m1 * wm.z; o1.w += m1 * wm.w;
        }
        t2[0][i].x = x1[0][i].x + o0.x; t2[0][i].y = x1[0][i].y + o0.y;
        t2[0][i].z = x1[0][i].z + o0.z; t2[0][i].w = x1[0][i].w + o0.w;
        t2[1][i].x = x1[1][i].x + o1.x; t2[1][i].y = x1[1][i].y + o1.y;
        t2[1][i].z = x1[1][i].z + o1.z; t2[1][i].w = x1[1][i].w + o1.w;
    }

#pragma unroll
    for (int rr = 0; rr < 2; ++rr) {
        float s = 0.f;
#pragma unroll
        for (int i = 0; i < 3; ++i)
            s += t2[rr][i].x + t2[rr][i].y + t2[rr][i].z + t2[rr][i].w;
#pragma unroll
        for (int off = 1; off < 64; off <<= 1) s += __shfl_xor(s, off, 64);
        float mean = s * (1.0f / 768.0f);
        float sq = 0.f;
#pragma unroll
        for (int i = 0; i < 3; ++i) {
            t2[rr][i].x -= mean; t2[rr][i].y -= mean;
            t2[rr][i].z -= mean; t2[rr][i].w -= mean;
            sq += t2[rr][i].x * t2[rr][i].x + t2[rr][i].y * t2[rr][i].y
                + t2[rr][i].z * t2[rr][i].z + t2[rr][i].w * t2[rr][i].w;
        }
#pragma unroll
        for (int off = 1; off < 64; off <<= 1) sq += __shfl_xor(sq, off, 64);
        float rs = rsqrtf(sq * (1.0f / 768.0f) + 1e-5f);
        size_t base = (size_t)(row0 + rr) * D_;
#pragma unroll
        for (int i = 0; i < 3; ++i) {
            float4 gg = ((const float4*)g2)[i * 64 + lane];
            float4 bb = ((const float4*)b2)[i * 64 + lane];
            float vx = t2[rr][i].x * rs * gg.x + bb.x;
            float vy = t2[rr][i].y * rs * gg.y + bb.y;
            float vz = t2[rr][i].z * rs * gg.z + bb.z;
            float vw = t2[rr][i].w * rs * gg.w + bb.w;
            __hip_bfloat16 pk[4] = {
                __float2bfloat16(vx), __float2bfloat16(vy),
                __float2bfloat16(vz), __float2bfloat16(vw)};
            *(uint2*)(x2b + base + i * 256 + lane * 4) = *(const uint2*)pk;
        }
    }
}

// ---------------------------------------------------------------------------
extern "C" void kernel_launch(void* const* d_in, const int* in_sizes, int n_in,
                              void* d_out, int out_size, void* d_ws, size_t ws_size,
                              hipStream_t stream) {
    const float* cur   = (const float*)d_in[0];
    const float* prev  = (const float*)d_in[1];
    const float* cvec  = (const float*)d_in[2];
    const int*   ridx  = (const int*)d_in[3];
    const float* Wq  = (const float*)d_in[4];
    const float* bq  = (const float*)d_in[5];
    const float* Wk  = (const float*)d_in[6];
    const float* bk  = (const float*)d_in[7];
    const float* Wv  = (const float*)d_in[8];
    const float* bv  = (const float*)d_in[9];
    const float* Wo  = (const float*)d_in[10];
    const float* bo  = (const float*)d_in[11];
    const float* g1  = (const float*)d_in[12];
    const float* b1  = (const float*)d_in[13];
    const float* Wqc = (const float*)d_in[14];
    const float* bqc = (const float*)d_in[15];
    const float* Wkc = (const float*)d_in[16];
    const float* bkc = (const float*)d_in[17];  (void)bkc;
    const float* Wvc = (const float*)d_in[18];
    const float* bvc = (const float*)d_in[19];
    const float* Woc = (const float*)d_in[20];
    const float* boc = (const float*)d_in[21];
    const float* g2  = (const float*)d_in[22];
    const float* b2  = (const float*)d_in[23];
    const float* W1  = (const float*)d_in[24];
    const float* bf1 = (const float*)d_in[25];
    const float* W2  = (const float*)d_in[26];
    const float* bf2 = (const float*)d_in[27];
    const float* g3  = (const float*)d_in[28];
    const float* b3  = (const float*)d_in[29];
    float* outp = (float*)d_out;
    (void)ws_size; (void)in_sizes; (void)n_in; (void)out_size;

    const int M = B_ * S_;                       // 16384
    const size_t NBSD = (size_t)M * D_;          // 12,582,912
    const size_t NSEL = (size_t)B_ * 128 * D_;   // 393,216

    __hip_bfloat16* hidb  = (__hip_bfloat16*)d_ws;          // M x FF (attn_out, then hid)
    __hip_bfloat16* bf0   = hidb + (size_t)M * FF_;         // cur_bf -> x2
    __hip_bfloat16* tmpb  = bf0 + NBSD;                     // q -> oproj -> ff
    __hip_bfloat16* Pselb = tmpb + NBSD;
    __hip_bfloat16* kselb = Pselb + NSEL;
    __hip_bfloat16* vselb = kselb + NSEL;
    __hip_bfloat16* Wqt   = vselb + NSEL;
    __hip_bfloat16* Wot   = Wqt + (size_t)D_ * D_;
    __hip_bfloat16* Wkt   = Wot + (size_t)D_ * D_;
    __hip_bfloat16* Wvt   = Wkt + (size_t)D_ * D_;
    __hip_bfloat16* W1t   = Wvt + (size_t)D_ * D_;          // FF x D
    __hip_bfloat16* W2t   = W1t + (size_t)D_ * FF_;         // D x FF
    float* Ub    = (float*)(W2t + (size_t)FF_ * D_);
    float* abv   = Ub + (size_t)D_ * H_;
    float* Wmix  = abv + 16;
    float* bias2 = Wmix + (size_t)H_ * D_;
    int*   selb  = (int*)(bias2 + D_);

    // 1) gather (bf16) + transposes + convert + class-attn precomputes
    gather_kernel<<<B_ * 128, 256, 0, stream>>>(prev, ridx, Pselb, selb);
    transp_all<<<6912, 256, 0, stream>>>(Wq, Wo, Wk, Wv, W1, W2,
                                         Wqt, Wot, Wkt, Wvt, W1t, W2t);
    conv_bf16<<<(int)(NBSD / 8 + 255) / 256, 256, 0, stream>>>(cur, bf0, (int)(NBSD / 8));
    precompute_U<<<36, 256, 0, stream>>>(Wqc, Wkc, bqc, Ub, abv);
    precompute_mix<<<36, 256, 0, stream>>>(Wvc, Woc, Wmix);
    precompute_bias2<<<12, 256, 0, stream>>>(Woc, bvc, boc, bias2);

    // 2) ksel/vsel projections (small; 128^2 kernel)
    {
        dim3 g(D_ / 128, (B_ * 128) / 128);
        gemm_mfma<<<g, 256, 0, stream>>>(Pselb, Wkt, bk, nullptr, kselb,
                                         B_ * 128, D_, D_, D_, D_, 1 | 8);
        gemm_mfma<<<g, 256, 0, stream>>>(Pselb, Wvt, bv, nullptr, vselb,
                                         B_ * 128, D_, D_, D_, D_, 1 | 8);
    }

    // 3) q = cur_bf @ Wq + bq -> tmpb (bf16)
    gemm256<<<dim3(D_ / 256, M / 256), 512, 0, stream>>>(
        (const u16*)bf0, (const u16*)Wqt, bq, (u16*)tmpb, M, D_, D_, 1);

    // 4) MFMA sparse attention -> hidb (bf16; cur_bf preserved in bf0)
    attn3_kernel<<<dim3(S_ / 256, B_ * H_), 256, 0, stream>>>(
        (const u16*)tmpb, (const u16*)kselb, (const u16*)vselb, selb, (u16*)hidb);

    // 5) oproj = attn_out @ Wo + bo -> tmpb (bf16; q dead)
    gemm256<<<dim3(D_ / 256, M / 256), 512, 0, stream>>>(
        (const u16*)hidb, (const u16*)Wot, bo, (u16*)tmpb, M, D_, D_, 1);

    // 6) fused mid: x1, class-attn, x2 -> bf0 (in-place over cur_bf)
    fused_mid<<<M / 8, 256, 0, stream>>>(
        (const u16*)bf0, (const u16*)tmpb, g1, b1, Ub, abv, cvec, Wmix, bias2,
        g2, b2, bf0);

    // 7) FF: hid = relu(x2@W1+bf1) -> hidb (attn_out dead); ff -> tmpb
    gemm256<<<dim3(FF_ / 256, M / 256), 512, 0, stream>>>(
        (const u16*)bf0, (const u16*)W1t, bf1, (u16*)hidb, M, FF_, D_, 1 | 2);
    gemm256<<<dim3(D_ / 256, M / 256), 512, 0, stream>>>(
        (const u16*)hidb, (const u16*)W2t, bf2, (u16*)tmpb, M, D_, FF_, 1);

    // 8) out = LN(x2 + ff)
    addln_bb<<<M, 192, 0, stream>>>((const u16*)bf0, (const u16*)tmpb, g3, b3, outp);
}

// Round 11
// 428.643 us; speedup vs baseline: 13.6486x; 1.0049x over previous
//
#include <hip/hip_runtime.h>
#include <hip/hip_bf16.h>

#define B_ 4
#define S_ 4096
#define D_ 768
#define H_ 12
#define DH_ 64
#define G_ 64
#define C_ 256
#define FF_ 3072

typedef __attribute__((ext_vector_type(8))) short bf16x8;
typedef __attribute__((ext_vector_type(4))) float f32x4;
typedef unsigned short u16;

__device__ __forceinline__ float bfu2f(u16 u) {
    return __uint_as_float((unsigned)u << 16);
}

// ---------------------------------------------------------------------------
// async global->LDS 16B (wave-uniform LDS base + lane*16)
// ---------------------------------------------------------------------------
__device__ __forceinline__ void gload16(const __hip_bfloat16* g, __hip_bfloat16* l) {
    __builtin_amdgcn_global_load_lds(
        (__attribute__((address_space(1))) void*)(void*)const_cast<__hip_bfloat16*>(g),
        (__attribute__((address_space(3))) void*)(void*)l,
        16, 0, 0);
}

// ---------------------------------------------------------------------------
// gemm128 — 128x128 tile, BK=64, 8 waves (2M x 4N, wave-tile 64x32, acc=32
// regs). LDS 64KB double-buffered -> 2 blocks/CU (16 waves) via
// __launch_bounds__(512,4): cross-BLOCK overlap hides barrier/vmcnt stalls.
// 2-phase counted-vmcnt pipeline (depth 2, vmcnt(4) gate, never 0 steady).
// XOR-granule swizzle: LDS row = 64 elems (8x16B granules); read granule
// G^(r&7); source pre-swizzled (both-sides rule); balanced 8 lanes/cluster.
// A: MxK bf16, Bt: NxK bf16. Out bf16. flags: 1=bias, 2=relu.
// M%128==0, N%128==0, K%64==0, NT>=2, nwg%8==0.
// ---------------------------------------------------------------------------
__global__ __launch_bounds__(512, 4) void gemm128(
    const u16* __restrict__ A, const u16* __restrict__ Bt,
    const float* __restrict__ bias, u16* __restrict__ Cb,
    int M, int N, int K, int flags)
{
    __shared__ __attribute__((aligned(16))) u16 As[2][128 * 64];
    __shared__ __attribute__((aligned(16))) u16 Bs[2][128 * 64];

    const int tid = threadIdx.x;
    const int lane = tid & 63, w = tid >> 6;
    const int wm = w >> 2, wn = w & 3;           // 2 x 4 wave grid
    const int r = lane & 15, qd = lane >> 4;

    // bijective XCD swizzle (nwg % 8 == 0)
    int lin = blockIdx.y * gridDim.x + blockIdx.x;
    int nwg = gridDim.x * gridDim.y;
    int cpx = nwg >> 3;
    int swz = (lin & 7) * cpx + (lin >> 3);
    int bm = (swz / gridDim.x) * 128;
    int bn = (swz % gridDim.x) * 128;

    // staging: per matrix 2 loads; load l covers rows l*64+(tid>>3);
    // source granule pre-swizzled by row&7 (= (tid>>3)&7)
    const int srow = tid >> 3;                        // 0..63
    const int sg = ((tid & 7) ^ (srow & 7)) * 8;      // elem offset in row
    // linear LDS dest elem offset = l*4096 + tid*8

#define STG(c, kt) { \
    const u16* a_ = A + (size_t)(bm + srow) * K + ((kt) << 6) + sg; \
    gload16((const __hip_bfloat16*)a_, (__hip_bfloat16*)&As[c][tid * 8]); \
    gload16((const __hip_bfloat16*)(a_ + (size_t)64 * K), (__hip_bfloat16*)&As[c][4096 + tid * 8]); \
    const u16* b_ = Bt + (size_t)(bn + srow) * K + ((kt) << 6) + sg; \
    gload16((const __hip_bfloat16*)b_, (__hip_bfloat16*)&Bs[c][tid * 8]); \
    gload16((const __hip_bfloat16*)(b_ + (size_t)64 * K), (__hip_bfloat16*)&Bs[c][4096 + tid * 8]); }

#define GR(kk) (((((kk) << 2) + qd) ^ (r & 7)) * 8)

    f32x4 acc[4][2] = {};
    const int NT = K >> 6;

    STG(0, 0)
    STG(1, 1)
    asm volatile("s_waitcnt vmcnt(4)" ::: "memory");   // tile0 landed
    __builtin_amdgcn_s_barrier();

    for (int kt = 0; kt < NT; ++kt) {
        const int c = kt & 1;
        const u16* as = As[c];
        const u16* bs = Bs[c];
#pragma unroll
        for (int kk = 0; kk < 2; ++kk) {
            bf16x8 af[4], bf[2];
#pragma unroll
            for (int m = 0; m < 4; ++m)
                af[m] = *(const bf16x8*)&as[(wm * 64 + m * 16 + r) * 64 + GR(kk)];
#pragma unroll
            for (int n = 0; n < 2; ++n)
                bf[n] = *(const bf16x8*)&bs[(wn * 32 + n * 16 + r) * 64 + GR(kk)];
            __builtin_amdgcn_s_setprio(1);
#pragma unroll
            for (int m = 0; m < 4; ++m)
#pragma unroll
                for (int n = 0; n < 2; ++n)
                    acc[m][n] = __builtin_amdgcn_mfma_f32_16x16x32_bf16(
                        af[m], bf[n], acc[m][n], 0, 0, 0);
            __builtin_amdgcn_s_setprio(0);
        }
        __builtin_amdgcn_s_barrier();                 // all reads of buf c done
        if (kt + 2 < NT) STG(c, kt + 2)               // overwrite buf c safely
        if (kt + 1 < NT) {
            if (kt + 2 < NT) asm volatile("s_waitcnt vmcnt(4)" ::: "memory");
            else             asm volatile("s_waitcnt vmcnt(0)" ::: "memory");
            __builtin_amdgcn_s_barrier();             // buf c^1 staged everywhere
        }
    }

#pragma unroll
    for (int m = 0; m < 4; ++m) {
        int row0 = bm + wm * 64 + m * 16 + qd * 4;
#pragma unroll
        for (int n = 0; n < 2; ++n) {
            int col = bn + wn * 32 + n * 16 + r;
            float bv = (flags & 1) ? bias[col] : 0.0f;
#pragma unroll
            for (int i = 0; i < 4; ++i) {
                float v = acc[m][n][i] + bv;
                if (flags & 2) v = fmaxf(v, 0.0f);
                __hip_bfloat16 ob = __float2bfloat16(v);
                Cb[(size_t)(row0 + i) * N + col] = *(u16*)&ob;
            }
        }
    }
#undef STG
#undef GR
}

// ---------------------------------------------------------------------------
__global__ __launch_bounds__(256) void conv_bf16(const float* __restrict__ in,
                                                 __hip_bfloat16* __restrict__ out,
                                                 int n8)
{
    int i = blockIdx.x * 256 + threadIdx.x;
    if (i >= n8) return;
    const float4* p = (const float4*)(in + (size_t)i * 8);
    float4 v0 = p[0], v1 = p[1];
    __hip_bfloat16 o[8] = {
        __float2bfloat16(v0.x), __float2bfloat16(v0.y),
        __float2bfloat16(v0.z), __float2bfloat16(v0.w),
        __float2bfloat16(v1.x), __float2bfloat16(v1.y),
        __float2bfloat16(v1.z), __float2bfloat16(v1.w)};
    *(uint4*)(out + (size_t)i * 8) = *(const uint4*)o;
}

// ---------------------------------------------------------------------------
// All 6 weight transposes in one dispatch.
// ---------------------------------------------------------------------------
__global__ __launch_bounds__(256) void transp_all(
    const float* __restrict__ Wq, const float* __restrict__ Wo,
    const float* __restrict__ Wk, const float* __restrict__ Wv,
    const float* __restrict__ W1, const float* __restrict__ W2,
    __hip_bfloat16* __restrict__ Wqt, __hip_bfloat16* __restrict__ Wot,
    __hip_bfloat16* __restrict__ Wkt, __hip_bfloat16* __restrict__ Wvt,
    __hip_bfloat16* __restrict__ W1t, __hip_bfloat16* __restrict__ W2t)
{
    int tile = blockIdx.x;
    const float* W; __hip_bfloat16* Wt; int K, N;
    if (tile < 2304) {
        int w = tile / 576; tile -= w * 576;
        K = 768; N = 768;
        W  = (w == 0) ? Wq : (w == 1) ? Wo : (w == 2) ? Wk : Wv;
        Wt = (w == 0) ? Wqt : (w == 1) ? Wot : (w == 2) ? Wkt : Wvt;
    } else if (tile < 4608) { tile -= 2304; K = 768; N = 3072; W = W1; Wt = W1t; }
    else                    { tile -= 4608; K = 3072; N = 768; W = W2; Wt = W2t; }
    int ntx = N >> 5;
    int k0 = (tile / ntx) * 32, n0 = (tile % ntx) * 32;
    __shared__ float s[32][33];
    int tx = threadIdx.x & 31, ty = threadIdx.x >> 5;
#pragma unroll
    for (int i = 0; i < 4; ++i)
        s[ty + i * 8][tx] = W[(size_t)(k0 + ty + i * 8) * N + n0 + tx];
    __syncthreads();
#pragma unroll
    for (int i = 0; i < 4; ++i)
        Wt[(size_t)(n0 + ty + i * 8) * K + k0 + tx] =
            __float2bfloat16(s[tx][ty + i * 8]);
}

// ---------------------------------------------------------------------------
__global__ void gather_kernel(const float* __restrict__ prev,
                              const int* __restrict__ rand_idx,
                              __hip_bfloat16* __restrict__ Pselb,
                              int* __restrict__ sel)
{
    int j = blockIdx.x;
    int b = j >> 7, i = j & 127;
    int sv = (i < 64) ? i : rand_idx[b * G_ + (i - 64)];
    if (threadIdx.x == 0) sel[j] = sv;
    const float* src = prev + ((size_t)(b * S_ + sv)) * D_;
    __hip_bfloat16* dst = Pselb + (size_t)j * D_;
    for (int d = threadIdx.x; d < D_; d += blockDim.x)
        dst[d] = __float2bfloat16(src[d]);
}

// ---------------------------------------------------------------------------
// MFMA sparse attention
// ---------------------------------------------------------------------------
__global__ __launch_bounds__(256) void attn3_kernel(
    const u16* __restrict__ qb, const u16* __restrict__ kb,
    const u16* __restrict__ vb, const int* __restrict__ sel,
    u16* __restrict__ out)
{
    const int bh = blockIdx.y;
    const int b = bh / H_, h = bh % H_;
    const int s0 = blockIdx.x * 256;
    const int t = threadIdx.x;
    const int w = t >> 6, lane = t & 63;
    const int r = lane & 15, qd = lane >> 4;

    __shared__ u16 Vt[64][136];
    __shared__ u16 Plds[4][32][136];
    __shared__ int ssel[128];

    {
        int key0 = t >> 4;
        int d0 = (t & 15) * 4;
        for (int kk = key0; kk < 128; kk += 16) {
            ushort4 v = *(const ushort4*)(vb + (size_t)(b * 128 + kk) * D_ + h * 64 + d0);
            Vt[d0 + 0][kk] = v.x; Vt[d0 + 1][kk] = v.y;
            Vt[d0 + 2][kk] = v.z; Vt[d0 + 3][kk] = v.w;
        }
        if (t < 128) ssel[t] = sel[b * 128 + t];
    }
    __syncthreads();

    int selv[8];
#pragma unroll
    for (int n = 0; n < 8; ++n) selv[n] = ssel[n * 16 + r];

    for (int pass = 0; pass < 2; ++pass) {
        const int sbase = s0 + w * 64 + pass * 32;
        f32x4 accs[2][8] = {};

#pragma unroll
        for (int ks = 0; ks < 2; ++ks) {
            bf16x8 af[2];
#pragma unroll
            for (int m = 0; m < 2; ++m)
                af[m] = *(const bf16x8*)(qb + (size_t)(b * S_ + sbase + m * 16 + r) * D_ + h * 64 + ks * 32 + qd * 8);
#pragma unroll
            for (int n = 0; n < 8; ++n) {
                bf16x8 bfv = *(const bf16x8*)(kb + (size_t)(b * 128 + n * 16 + r) * D_ + h * 64 + ks * 32 + qd * 8);
#pragma unroll
                for (int m = 0; m < 2; ++m)
                    accs[m][n] = __builtin_amdgcn_mfma_f32_16x16x32_bf16(
                        af[m], bfv, accs[m][n], 0, 0, 0);
            }
        }

#pragma unroll
        for (int m = 0; m < 2; ++m) {
#pragma unroll
            for (int i = 0; i < 4; ++i) {
                int srow = sbase + m * 16 + qd * 4 + i;
                float pm = -3e38f;
#pragma unroll
                for (int n = 0; n < 8; ++n) {
                    float sc = accs[m][n][i] * 0.125f;
                    if (selv[n] > srow) sc = -1e9f;
                    accs[m][n][i] = sc;
                    pm = fmaxf(pm, sc);
                }
#pragma unroll
                for (int off = 1; off < 16; off <<= 1)
                    pm = fmaxf(pm, __shfl_xor(pm, off, 64));
                float ps = 0.f;
#pragma unroll
                for (int n = 0; n < 8; ++n) {
                    float e = __expf(accs[m][n][i] - pm);
                    accs[m][n][i] = e;
                    ps += e;
                }
#pragma unroll
                for (int off = 1; off < 16; off <<= 1)
                    ps += __shfl_xor(ps, off, 64);
                float inv = 1.0f / ps;
#pragma unroll
                for (int n = 0; n < 8; ++n)
                    accs[m][n][i] *= inv;
            }
        }

#pragma unroll
        for (int m = 0; m < 2; ++m)
#pragma unroll
            for (int n = 0; n < 8; ++n)
#pragma unroll
                for (int i = 0; i < 4; ++i) {
                    __hip_bfloat16 pb = __float2bfloat16(accs[m][n][i]);
                    Plds[w][m * 16 + qd * 4 + i][n * 16 + r] = *(u16*)&pb;
                }

        f32x4 acco[2][4] = {};
#pragma unroll
        for (int ks = 0; ks < 4; ++ks) {
            bf16x8 pa[2];
#pragma unroll
            for (int m = 0; m < 2; ++m)
                pa[m] = *(const bf16x8*)&Plds[w][m * 16 + r][ks * 32 + qd * 8];
#pragma unroll
            for (int nd = 0; nd < 4; ++nd) {
                bf16x8 bv = *(const bf16x8*)&Vt[nd * 16 + r][ks * 32 + qd * 8];
#pragma unroll
                for (int m = 0; m < 2; ++m)
                    acco[m][nd] = __builtin_amdgcn_mfma_f32_16x16x32_bf16(
                        pa[m], bv, acco[m][nd], 0, 0, 0);
            }
        }

#pragma unroll
        for (int m = 0; m < 2; ++m)
#pragma unroll
            for (int nd = 0; nd < 4; ++nd)
#pragma unroll
                for (int i = 0; i < 4; ++i) {
                    __hip_bfloat16 ob = __float2bfloat16(acco[m][nd][i]);
                    out[(size_t)(b * S_ + sbase + m * 16 + qd * 4 + i) * D_ + h * 64 + nd * 16 + r] = *(u16*)&ob;
                }
    }
}

// ---------------------------------------------------------------------------
// final LN: out[row] = LN(bf16 xa + bf16 xb)*g+beta. 192 threads, ushort4.
// ---------------------------------------------------------------------------
__global__ __launch_bounds__(192) void addln_bb(
    const u16* __restrict__ xa, const u16* __restrict__ xb,
    const float* __restrict__ g, const float* __restrict__ beta,
    float* __restrict__ out)
{
    const int row = blockIdx.x;
    const int t = threadIdx.x;
    const ushort4 a = ((const ushort4*)(xa + (size_t)row * D_))[t];
    const ushort4 b4 = ((const ushort4*)(xb + (size_t)row * D_))[t];
    float v[4] = {bfu2f(a.x) + bfu2f(b4.x), bfu2f(a.y) + bfu2f(b4.y),
                  bfu2f(a.z) + bfu2f(b4.z), bfu2f(a.w) + bfu2f(b4.w)};
    float sum = v[0] + v[1] + v[2] + v[3];
#pragma unroll
    for (int off = 1; off < 64; off <<= 1) sum += __shfl_xor(sum, off, 64);
    __shared__ float r1[3], r2[3];
    int wv = t >> 6, ln = t & 63;
    if (ln == 0) r1[wv] = sum;
    __syncthreads();
    float mean = (r1[0] + r1[1] + r1[2]) * (1.0f / 768.0f);
    float sq = 0.f;
#pragma unroll
    for (int i = 0; i < 4; ++i) { v[i] -= mean; sq += v[i] * v[i]; }
#pragma unroll
    for (int off = 1; off < 64; off <<= 1) sq += __shfl_xor(sq, off, 64);
    if (ln == 0) r2[wv] = sq;
    __syncthreads();
    float var = (r2[0] + r2[1] + r2[2]) * (1.0f / 768.0f);
    float rs = rsqrtf(var + 1e-5f);
    float4 gg = ((const float4*)g)[t];
    float4 bb = ((const float4*)beta)[t];
    float4 o;
    o.x = v[0] * rs * gg.x + bb.x;
    o.y = v[1] * rs * gg.y + bb.y;
    o.z = v[2] * rs * gg.z + bb.z;
    o.w = v[3] * rs * gg.w + bb.w;
    ((float4*)(out + (size_t)row * D_))[t] = o;
}

// ---------------------------------------------------------------------------
// Class-attention precompute
// ---------------------------------------------------------------------------
__global__ __launch_bounds__(256) void precompute_U(
    const float* __restrict__ Wqc, const float* __restrict__ Wkc,
    const float* __restrict__ bqc, float* __restrict__ Ut, float* __restrict__ ab)
{
    __shared__ __attribute__((aligned(16))) float wk[D_];
    for (int i = threadIdx.x; i < D_; i += 256) wk[i] = Wkc[i];
    __syncthreads();
    int idx = blockIdx.x * 256 + threadIdx.x;
    int h = idx / D_, d = idx - h * D_;
    const float4* row = (const float4*)(Wqc + (size_t)d * D_ + h * 64);
    const float4* wkv = (const float4*)(wk + h * 64);
    float a0 = 0.f, a1 = 0.f, a2 = 0.f, a3 = 0.f;
#pragma unroll
    for (int j = 0; j < 16; j += 4) {
        float4 r0 = row[j], r1 = row[j + 1], r2 = row[j + 2], r3 = row[j + 3];
        float4 c0 = wkv[j], c1 = wkv[j + 1], c2 = wkv[j + 2], c3 = wkv[j + 3];
        a0 += r0.x * c0.x + r0.y * c0.y + r0.z * c0.z + r0.w * c0.w;
        a1 += r1.x * c1.x + r1.y * c1.y + r1.z * c1.z + r1.w * c1.w;
        a2 += r2.x * c2.x + r2.y * c2.y + r2.z * c2.z + r2.w * c2.w;
        a3 += r3.x * c3.x + r3.y * c3.y + r3.z * c3.z + r3.w * c3.w;
    }
    Ut[idx] = (a0 + a1) + (a2 + a3);
    if (idx < H_) {
        const float4* bq4 = (const float4*)(bqc + idx * 64);
        const float4* wk4 = (const float4*)(wk + idx * 64);
        float s = 0.f;
#pragma unroll
        for (int j = 0; j < 16; ++j) {
            float4 bb = bq4[j], cc = wk4[j];
            s += bb.x * cc.x + bb.y * cc.y + bb.z * cc.z + bb.w * cc.w;
        }
        ab[idx] = s;
    }
}

__global__ __launch_bounds__(256) void precompute_mix(
    const float* __restrict__ Wvc, const float* __restrict__ Woc,
    float* __restrict__ Wmix)
{
    __shared__ float wv[D_];
    for (int i = threadIdx.x; i < D_; i += 256) wv[i] = Wvc[i];
    __syncthreads();
    int idx = blockIdx.x * 256 + threadIdx.x;
    int h = idx / D_, n = idx - h * D_;
    float acc[8] = {};
#pragma unroll
    for (int j = 0; j < 64; ++j)
        acc[j & 7] += wv[h * 64 + j] * Woc[(size_t)(h * 64 + j) * D_ + n];
    Wmix[idx] = ((acc[0] + acc[1]) + (acc[2] + acc[3]))
              + ((acc[4] + acc[5]) + (acc[6] + acc[7]));
}

__global__ __launch_bounds__(256) void precompute_bias2(
    const float* __restrict__ Woc, const float* __restrict__ bvc,
    const float* __restrict__ boc, float* __restrict__ bias2)
{
    int tx = threadIdx.x & 63, ty = threadIdx.x >> 6;
    int n = blockIdx.x * 64 + tx;
    int d0 = ty * 192;
    float a = 0.f;
#pragma unroll 8
    for (int d = 0; d < 192; ++d)
        a += bvc[d0 + d] * Woc[(size_t)(d0 + d) * D_ + n];
    __shared__ float red[4][64];
    red[ty][tx] = a;
    __syncthreads();
    if (ty == 0)
        bias2[n] = boc[n] + red[0][tx] + red[1][tx] + red[2][tx] + red[3][tx];
}

// ---------------------------------------------------------------------------
// Fused mid: x1=LN(cur_bf16+oproj_bf16); alpha; mu; x2=LN(x1+bias2+mu@Wmix)
// -> bf16 (in-place over cur_bf: rows read early, written late, block-local)
// ---------------------------------------------------------------------------
__global__ __launch_bounds__(256) void fused_mid(
    const u16* __restrict__ curb, const u16* __restrict__ oprojb,
    const float* __restrict__ g1, const float* __restrict__ b1,
    const float* __restrict__ Ut, const float* __restrict__ ab,
    const float* __restrict__ cvec,
    const float* __restrict__ Wmix, const float* __restrict__ bias2,
    const float* __restrict__ g2, const float* __restrict__ b2,
    __hip_bfloat16* __restrict__ x2b)
{
    const int w = threadIdx.x >> 6, lane = threadIdx.x & 63;
    const int row0 = blockIdx.x * 8 + w * 2;
    const int b = blockIdx.x >> 9;

    __shared__ float4 cvs[64];
    __shared__ float xp[4][64][28];
    __shared__ float muls[4][24];

    if (threadIdx.x < 64)
        cvs[threadIdx.x] = ((const float4*)(cvec + b * C_))[threadIdx.x];

    float4 x1[2][3];
#pragma unroll
    for (int rr = 0; rr < 2; ++rr) {
        const ushort4* pa = (const ushort4*)(curb + (size_t)(row0 + rr) * D_);
        const ushort4* pb = (const ushort4*)(oprojb + (size_t)(row0 + rr) * D_);
        float s = 0.f;
#pragma unroll
        for (int i = 0; i < 3; ++i) {
            ushort4 au = pa[i * 64 + lane];
            ushort4 ou = pb[i * 64 + lane];
            float4 v;
            v.x = bfu2f(au.x) + bfu2f(ou.x); v.y = bfu2f(au.y) + bfu2f(ou.y);
            v.z = bfu2f(au.z) + bfu2f(ou.z); v.w = bfu2f(au.w) + bfu2f(ou.w);
            x1[rr][i] = v;
            s += v.x + v.y + v.z + v.w;
        }
#pragma unroll
        for (int off = 1; off < 64; off <<= 1) s += __shfl_xor(s, off, 64);
        float mean = s * (1.0f / 768.0f);
        float sq = 0.f;
#pragma unroll
        for (int i = 0; i < 3; ++i) {
            x1[rr][i].x -= mean; x1[rr][i].y -= mean;
            x1[rr][i].z -= mean; x1[rr][i].w -= mean;
            sq += x1[rr][i].x * x1[rr][i].x + x1[rr][i].y * x1[rr][i].y
                + x1[rr][i].z * x1[rr][i].z + x1[rr][i].w * x1[rr][i].w;
        }
#pragma unroll
        for (int off = 1; off < 64; off <<= 1) sq += __shfl_xor(sq, off, 64);
        float rs = rsqrtf(sq * (1.0f / 768.0f) + 1e-5f);
#pragma unroll
        for (int i = 0; i < 3; ++i) {
            float4 gg = ((const float4*)g1)[i * 64 + lane];
            float4 bb = ((const float4*)b1)[i * 64 + lane];
            x1[rr][i].x = x1[rr][i].x * rs * gg.x + bb.x;
            x1[rr][i].y = x1[rr][i].y * rs * gg.y + bb.y;
            x1[rr][i].z = x1[rr][i].z * rs * gg.z + bb.z;
            x1[rr][i].w = x1[rr][i].w * rs * gg.w + bb.w;
        }
    }

    float acc[24];
#pragma unroll
    for (int j = 0; j < 24; ++j) acc[j] = 0.f;
#pragma unroll
    for (int i = 0; i < 3; ++i) {
#pragma unroll
        for (int h = 0; h < 12; ++h) {
            float4 u = ((const float4*)(Ut + (size_t)h * D_))[i * 64 + lane];
#pragma unroll
            for (int rr = 0; rr < 2; ++rr)
                acc[rr * 12 + h] += x1[rr][i].x * u.x + x1[rr][i].y * u.y
                                  + x1[rr][i].z * u.z + x1[rr][i].w * u.w;
        }
    }
#pragma unroll
    for (int j4 = 0; j4 < 6; ++j4)
        *(float4*)&xp[w][lane][j4 * 4] = *(float4*)&acc[j4 * 4];
    __syncthreads();

    if (lane < 48) {
        int j = lane >> 1, half = lane & 1;
        float ssum = 0.f;
#pragma unroll
        for (int k = 0; k < 32; ++k) ssum += xp[w][half * 32 + k][j];
        ssum += __shfl_xor(ssum, 1, 64);
        float a = 0.125f * (ssum + ab[j % 12]);
        float z = 0.f, ms = 0.f;
#pragma unroll
        for (int it = 0; it < 32; ++it) {
            float4 c = cvs[half * 32 + it];
            float e0 = __expf(a * c.x), e1 = __expf(a * c.y),
                  e2 = __expf(a * c.z), e3 = __expf(a * c.w);
            z += e0 + e1 + e2 + e3;
            ms += e0 * c.x + e1 * c.y + e2 * c.z + e3 * c.w;
        }
        z += __shfl_xor(z, 1, 64);
        ms += __shfl_xor(ms, 1, 64);
        if (half == 0) muls[w][j] = ms / z;
    }
    __syncthreads();

    float4 t2[2][3];
#pragma unroll
    for (int i = 0; i < 3; ++i) {
        float4 bv = ((const float4*)bias2)[i * 64 + lane];
        float4 o0 = bv, o1 = bv;
#pragma unroll
        for (int h = 0; h < 12; ++h) {
            float4 wm = ((const float4*)(Wmix + (size_t)h * D_))[i * 64 + lane];
            float m0 = muls[w][h], m1 = muls[w][12 + h];
            o0.x += m0 * wm.x; o0.y += m0 * wm.y; o0.z += m0 * wm.z; o0.w += m0 * wm.w;
            o1.x += m1 * wm.x; o1.y += m1 * wm.y; o1.z += m1 * wm.z; o1.w += m1 * wm.w;
        }
        t2[0][i].x = x1[0][i].x + o0.x; t2[0][i].y = x1[0][i].y + o0.y;
        t2[0][i].z = x1[0][i].z + o0.z; t2[0][i].w = x1[0][i].w + o0.w;
        t2[1][i].x = x1[1][i].x + o1.x; t2[1][i].y = x1[1][i].y + o1.y;
        t2[1][i].z = x1[1][i].z + o1.z; t2[1][i].w = x1[1][i].w + o1.w;
    }

#pragma unroll
    for (int rr = 0; rr < 2; ++rr) {
        float s = 0.f;
#pragma unroll
        for (int i = 0; i < 3; ++i)
            s += t2[rr][i].x + t2[rr][i].y + t2[rr][i].z + t2[rr][i].w;
#pragma unroll
        for (int off = 1; off < 64; off <<= 1) s += __shfl_xor(s, off, 64);
        float mean = s * (1.0f / 768.0f);
        float sq = 0.f;
#pragma unroll
        for (int i = 0; i < 3; ++i) {
            t2[rr][i].x -= mean; t2[rr][i].y -= mean;
            t2[rr][i].z -= mean; t2[rr][i].w -= mean;
            sq += t2[rr][i].x * t2[rr][i].x + t2[rr][i].y * t2[rr][i].y
                + t2[rr][i].z * t2[rr][i].z + t2[rr][i].w * t2[rr][i].w;
        }
#pragma unroll
        for (int off = 1; off < 64; off <<= 1) sq += __shfl_xor(sq, off, 64);
        float rs = rsqrtf(sq * (1.0f / 768.0f) + 1e-5f);
        size_t base = (size_t)(row0 + rr) * D_;
#pragma unroll
        for (int i = 0; i < 3; ++i) {
            float4 gg = ((const float4*)g2)[i * 64 + lane];
            float4 bb = ((const float4*)b2)[i * 64 + lane];
            float vx = t2[rr][i].x * rs * gg.x + bb.x;
            float vy = t2[rr][i].y * rs * gg.y + bb.y;
            float vz = t2[rr][i].z * rs * gg.z + bb.z;
            float vw = t2[rr][i].w * rs * gg.w + bb.w;
            __hip_bfloat16 pk[4] = {
                __float2bfloat16(vx), __float2bfloat16(vy),
                __float2bfloat16(vz), __float2bfloat16(vw)};
            *(uint2*)(x2b + base + i * 256 + lane * 4) = *(const uint2*)pk;
        }
    }
}

// ---------------------------------------------------------------------------
extern "C" void kernel_launch(void* const* d_in, const int* in_sizes, int n_in,
                              void* d_out, int out_size, void* d_ws, size_t ws_size,
                              hipStream_t stream) {
    const float* cur   = (const float*)d_in[0];
    const float* prev  = (const float*)d_in[1];
    const float* cvec  = (const float*)d_in[2];
    const int*   ridx  = (const int*)d_in[3];
    const float* Wq  = (const float*)d_in[4];
    const float* bq  = (const float*)d_in[5];
    const float* Wk  = (const float*)d_in[6];
    const float* bk  = (const float*)d_in[7];
    const float* Wv  = (const float*)d_in[8];
    const float* bv  = (const float*)d_in[9];
    const float* Wo  = (const float*)d_in[10];
    const float* bo  = (const float*)d_in[11];
    const float* g1  = (const float*)d_in[12];
    const float* b1  = (const float*)d_in[13];
    const float* Wqc = (const float*)d_in[14];
    const float* bqc = (const float*)d_in[15];
    const float* Wkc = (const float*)d_in[16];
    const float* bkc = (const float*)d_in[17];  (void)bkc;
    const float* Wvc = (const float*)d_in[18];
    const float* bvc = (const float*)d_in[19];
    const float* Woc = (const float*)d_in[20];
    const float* boc = (const float*)d_in[21];
    const float* g2  = (const float*)d_in[22];
    const float* b2  = (const float*)d_in[23];
    const float* W1  = (const float*)d_in[24];
    const float* bf1 = (const float*)d_in[25];
    const float* W2  = (const float*)d_in[26];
    const float* bf2 = (const float*)d_in[27];
    const float* g3  = (const float*)d_in[28];
    const float* b3  = (const float*)d_in[29];
    float* outp = (float*)d_out;
    (void)ws_size; (void)in_sizes; (void)n_in; (void)out_size;

    const int M = B_ * S_;                       // 16384
    const size_t NBSD = (size_t)M * D_;          // 12,582,912
    const size_t NSEL = (size_t)B_ * 128 * D_;   // 393,216

    __hip_bfloat16* hidb  = (__hip_bfloat16*)d_ws;          // M x FF (attn_out, then hid)
    __hip_bfloat16* bf0   = hidb + (size_t)M * FF_;         // cur_bf -> x2
    __hip_bfloat16* tmpb  = bf0 + NBSD;                     // q -> oproj -> ff
    __hip_bfloat16* Pselb = tmpb + NBSD;
    __hip_bfloat16* kselb = Pselb + NSEL;
    __hip_bfloat16* vselb = kselb + NSEL;
    __hip_bfloat16* Wqt   = vselb + NSEL;
    __hip_bfloat16* Wot   = Wqt + (size_t)D_ * D_;
    __hip_bfloat16* Wkt   = Wot + (size_t)D_ * D_;
    __hip_bfloat16* Wvt   = Wkt + (size_t)D_ * D_;
    __hip_bfloat16* W1t   = Wvt + (size_t)D_ * D_;          // FF x D
    __hip_bfloat16* W2t   = W1t + (size_t)D_ * FF_;         // D x FF
    float* Ub    = (float*)(W2t + (size_t)FF_ * D_);
    float* abv   = Ub + (size_t)D_ * H_;
    float* Wmix  = abv + 16;
    float* bias2 = Wmix + (size_t)H_ * D_;
    int*   selb  = (int*)(bias2 + D_);

    // 1) gather (bf16) + transposes + convert + class-attn precomputes
    gather_kernel<<<B_ * 128, 256, 0, stream>>>(prev, ridx, Pselb, selb);
    transp_all<<<6912, 256, 0, stream>>>(Wq, Wo, Wk, Wv, W1, W2,
                                         Wqt, Wot, Wkt, Wvt, W1t, W2t);
    conv_bf16<<<(int)(NBSD / 8 + 255) / 256, 256, 0, stream>>>(cur, bf0, (int)(NBSD / 8));
    precompute_U<<<36, 256, 0, stream>>>(Wqc, Wkc, bqc, Ub, abv);
    precompute_mix<<<36, 256, 0, stream>>>(Wvc, Woc, Wmix);
    precompute_bias2<<<12, 256, 0, stream>>>(Woc, bvc, boc, bias2);

    // 2) ksel/vsel projections (M=512 -> 24 blocks)
    {
        dim3 g(D_ / 128, (B_ * 128) / 128);
        gemm128<<<g, 512, 0, stream>>>((const u16*)Pselb, (const u16*)Wkt, bk,
                                       (u16*)kselb, B_ * 128, D_, D_, 1);
        gemm128<<<g, 512, 0, stream>>>((const u16*)Pselb, (const u16*)Wvt, bv,
                                       (u16*)vselb, B_ * 128, D_, D_, 1);
    }

    // 3) q = cur_bf @ Wq + bq -> tmpb (bf16)   [768 blocks, 2/CU resident]
    gemm128<<<dim3(D_ / 128, M / 128), 512, 0, stream>>>(
        (const u16*)bf0, (const u16*)Wqt, bq, (u16*)tmpb, M, D_, D_, 1);

    // 4) MFMA sparse attention -> hidb (bf16; cur_bf preserved in bf0)
    attn3_kernel<<<dim3(S_ / 256, B_ * H_), 256, 0, stream>>>(
        (const u16*)tmpb, (const u16*)kselb, (const u16*)vselb, selb, (u16*)hidb);

    // 5) oproj = attn_out @ Wo + bo -> tmpb (bf16; q dead)
    gemm128<<<dim3(D_ / 128, M / 128), 512, 0, stream>>>(
        (const u16*)hidb, (const u16*)Wot, bo, (u16*)tmpb, M, D_, D_, 1);

    // 6) fused mid: x1, class-attn, x2 -> bf0 (in-place over cur_bf)
    fused_mid<<<M / 8, 256, 0, stream>>>(
        (const u16*)bf0, (const u16*)tmpb, g1, b1, Ub, abv, cvec, Wmix, bias2,
        g2, b2, bf0);

    // 7) FF: hid = relu(x2@W1+bf1) -> hidb (3072 blocks); ff -> tmpb (768)
    gemm128<<<dim3(FF_ / 128, M / 128), 512, 0, stream>>>(
        (const u16*)bf0, (const u16*)W1t, bf1, (u16*)hidb, M, FF_, D_, 1 | 2);
    gemm128<<<dim3(D_ / 128, M / 128), 512, 0, stream>>>(
        (const u16*)hidb, (const u16*)W2t, bf2, (u16*)tmpb, M, D_, FF_, 1);

    // 8) out = LN(x2 + ff)
    addln_bb<<<M, 192, 0, stream>>>((const u16*)bf0, (const u16*)tmpb, g3, b3, outp);
}